// Round 1
// baseline (1435.219 us; speedup 1.0000x reference)
//
#include <hip/hip_runtime.h>
#include <hip/hip_bf16.h>
#include <cstdint>
#include <cstddef>
#include <math.h>

// Match numpy f32 per-op rounding: no FMA contraction, no reassociation.
// (fmaf() below is explicit and unaffected by the pragma.)
#pragma clang fp contract(off)

#define A_N 8732
#define C_N 91
#define CM1 90
#define B_N 32
#define TOPK 400
#define MAXDET 200
#define NT 512                              /* threads in k_topknms */
#define BBOX_CLIPF 4.135166556742356f       /* log(1000/16) cast to f32 */

// Dual-path input load (reference is float32; sniff is insurance).
__device__ __forceinline__ float ldin(const void* p, size_t i, int isbf16) {
    if (isbf16) return __bfloat162float(((const __hip_bfloat16*)p)[i]);
    return ((const float*)p)[i];
}

// numpy SIMD f32 exp — bit-faithful (PROVEN bit-exact in round 10, absmax 0.0).
// DO NOT alter any constant or association.
__device__ __forceinline__ float np_expf(float x) {
    float q = rintf(x * 1.442695040f);
    float r = fmaf(q, -0.693359375f, x);
    r = fmaf(q, 2.12194440e-4f, r);
    float p = 1.9875691500E-4f;
    p = fmaf(p, r, 1.3981999507E-3f);
    p = fmaf(p, r, 8.3334519073E-3f);
    p = fmaf(p, r, 4.1665795894E-2f);
    p = fmaf(p, r, 1.6666665459E-1f);
    p = fmaf(p, r, 5.0000001201E-1f);
    p = fmaf(p, r, 1.0f);
    p = fmaf(p, r, 1.0f);
    return ldexpf(p, (int)q);
}

// ---------------------------------------------------------------- dtype sniff
__global__ void k_sniff(const unsigned* __restrict__ words, int* __restrict__ flag) {
    __shared__ int cnt_s;
    if (threadIdx.x == 0) cnt_s = 0;
    __syncthreads();
    int local = 0;
    for (int i = threadIdx.x; i < 4096; i += 256) {
        unsigned w = words[i];
        unsigned e = (w >> 7) & 0xFFu;
        if (e >= 100u && e <= 140u) local++;
    }
    atomicAdd(&cnt_s, local);
    __syncthreads();
    if (threadIdx.x == 0) flag[0] = (cnt_s > 2048) ? 1 : 0;
}

// ---------------------------------------------------------------- softmax stats
// denom = numpy pairwise_sum over the 91 f32 exp terms (PROVEN bit-exact r10).
// NEW: when scT != nullptr, also emit masked score bits TRANSPOSED to
// scT[(b*90 + c-1)*A + a] so k_topknms_pre reads them fully coalesced.
// Expressions for e, sc, and the 0.01f mask are byte-identical to the ones
// previously evaluated inside k_topknms — bit-exactness preserved.
__global__ void k_stats(const void* __restrict__ logits,
                        const int* __restrict__ flag,
                        float* __restrict__ amax,
                        float* __restrict__ denom,
                        unsigned* __restrict__ scT) {
    int i = blockIdx.x * blockDim.x + threadIdx.x;
    if (i >= B_N * A_N) return;
    int bf = flag[0];
    size_t base = (size_t)i * C_N;
    float m = -INFINITY;
    for (int c = 0; c < C_N; ++c) m = fmaxf(m, ldin(logits, base + c, bf));
    float r[8];
    for (int j = 0; j < 8; ++j) r[j] = np_expf(ldin(logits, base + j, bf) - m);
    for (int c = 8; c < 88; c += 8)
        for (int j = 0; j < 8; ++j) r[j] += np_expf(ldin(logits, base + c + j, bf) - m);
    float res = ((r[0] + r[1]) + (r[2] + r[3])) + ((r[4] + r[5]) + (r[6] + r[7]));
    res += np_expf(ldin(logits, base + 88, bf) - m);
    res += np_expf(ldin(logits, base + 89, bf) - m);
    res += np_expf(ldin(logits, base + 90, bf) - m);
    amax[i]  = m;
    denom[i] = res;

    if (scT) {
        int b = i / A_N;
        int a = i - b * A_N;
        unsigned* srow = scT + (size_t)b * CM1 * A_N + a;
        // Re-read logits (L1/L2-hot: this thread just touched its 364B row)
        // and recompute e exactly as k_topknms used to. Writes are coalesced:
        // for fixed c, consecutive lanes write consecutive anchors.
        for (int c = 1; c < C_N; ++c) {
            float e  = np_expf(ldin(logits, base + c, bf) - m);
            float sc = e / res;
            srow[(size_t)(c - 1) * A_N] = (sc > 0.01f) ? __float_as_uint(sc) : 0u;
        }
    }
}

// ---------------------------------------------------------------- box decode (PROVEN bit-exact r10)
// f32 path now uses float4 loads/stores (identical arithmetic; rel/anchors/
// boxes rows are all 16B-aligned).
__global__ void k_decode(const void* __restrict__ rel,
                         const void* __restrict__ anchors,
                         const int* __restrict__ flag,
                         float* __restrict__ boxes) {
    int i = blockIdx.x * blockDim.x + threadIdx.x;
    if (i >= B_N * A_N) return;
    int bf = flag[0];
    int a = i % A_N;
    float ax1, ay1, ax2, ay2, r0, r1, r2, r3;
    if (!bf) {
        float4 av = ((const float4*)anchors)[a];
        float4 rv = ((const float4*)rel)[i];
        ax1 = av.x; ay1 = av.y; ax2 = av.z; ay2 = av.w;
        r0 = rv.x; r1 = rv.y; r2 = rv.z; r3 = rv.w;
    } else {
        ax1 = ldin(anchors, (size_t)a * 4 + 0, bf);
        ay1 = ldin(anchors, (size_t)a * 4 + 1, bf);
        ax2 = ldin(anchors, (size_t)a * 4 + 2, bf);
        ay2 = ldin(anchors, (size_t)a * 4 + 3, bf);
        r0 = ldin(rel, (size_t)i * 4 + 0, bf);
        r1 = ldin(rel, (size_t)i * 4 + 1, bf);
        r2 = ldin(rel, (size_t)i * 4 + 2, bf);
        r3 = ldin(rel, (size_t)i * 4 + 3, bf);
    }
    float wa = ax2 - ax1, ha = ay2 - ay1;
    float cxa = ax1 + 0.5f * wa, cya = ay1 + 0.5f * ha;
    float dx = r0 / 10.0f, dy = r1 / 10.0f;
    float dw = fminf(r2 / 5.0f, BBOX_CLIPF);
    float dh = fminf(r3 / 5.0f, BBOX_CLIPF);
    float cx = dx * wa + cxa, cy = dy * ha + cya;
    float w = np_expf(dw) * wa, h = np_expf(dh) * ha;
    float4 o;
    o.x = fminf(fmaxf(cx - 0.5f * w, 0.0f), 300.0f);
    o.y = fminf(fmaxf(cy - 0.5f * h, 0.0f), 300.0f);
    o.z = fminf(fmaxf(cx + 0.5f * w, 0.0f), 300.0f);
    o.w = fminf(fmaxf(cy + 0.5f * h, 0.0f), 300.0f);
    ((float4*)boxes)[i] = o;
}

// ---------------------------------------------------------------- fused top-400 + per-class NMS
// NEW primary variant: reads precomputed masked score bits (scT, transposed)
// with a fully-coalesced uint4 stream instead of 8732 strided 4B gathers of
// logits. Nonzero count is fused into the copy. All phases from the radix
// select onward are VERBATIM from the proven kernel.
__global__ __launch_bounds__(NT) void k_topknms_pre(const unsigned* __restrict__ scT,
                                                    const float* __restrict__ boxes,
                                                    unsigned long long* __restrict__ kkey,
                                                    int* __restrict__ kcnt) {
    __shared__ __align__(16) union {
        unsigned sbits[A_N];                 // 34928 B (phase 1: scores)
        unsigned long long msk[TOPK * 7];    // 22400 B (phase 2: NMS bitmask)
    } su;
    __shared__ unsigned long long wlist[512];
    __shared__ float bx1[TOPK], by1[TOPK], bx2[TOPK], by2[TOPK], bar[TOPK];
    __shared__ int wred[NT / 64];
    __shared__ unsigned bcast_p;
    __shared__ int bcast_rem;
    __shared__ int eqlist[64];
    __shared__ int eqn;
    __shared__ int bcast_athr;
    __shared__ int nsel;

    int bc = blockIdx.x;
    int b  = bc / CM1;
    int cm = bc % CM1;                       // class row 0..89 (logit col cm+1)
    int t  = threadIdx.x;

    // coalesced copy of precomputed masked score bits + fused nonzero count
    // (scT row bc is exactly this block's class column; 8732 = 4*2183 words)
    const uint4* src = (const uint4*)(scT + (size_t)bc * A_N);
    uint4* dst = (uint4*)su.sbits;
    int c0 = 0;
    for (int k = t; k < A_N / 4; k += NT) {
        uint4 v = src[k];
        dst[k] = v;
        c0 += (v.x != 0u) + (v.y != 0u) + (v.z != 0u) + (v.w != 0u);
    }
    if (t == 0) { eqn = 0; nsel = 0; }
    for (int o = 32; o; o >>= 1) c0 += __shfl_down(c0, o);
    if ((t & 63) == 0) wred[t >> 6] = c0;
    __syncthreads();
    if (t == 0) {
        int tot = 0;
        for (int wv = 0; wv < NT / 64; ++wv) tot += wred[wv];
        bcast_rem = tot;
    }
    __syncthreads();
    int nreal = bcast_rem;
    __syncthreads();

    unsigned sstar = 0u;
    int teq = 0;
    if (nreal >= TOPK) {
        // MSB-first bit-serial radix select of the 400th largest (proven r10).
        unsigned p = 0x3C000000u;
        int rem = TOPK;
        for (int bit = 25; bit >= 0; --bit) {
            unsigned q = p | (1u << bit);
            int cnt = 0;
            for (int a = t; a < A_N; a += NT) cnt += ((su.sbits[a] >> bit) == (q >> bit));
            for (int o = 32; o; o >>= 1) cnt += __shfl_down(cnt, o);
            if ((t & 63) == 0) wred[t >> 6] = cnt;
            __syncthreads();
            if (t == 0) {
                int tot = 0;
                for (int wv = 0; wv < NT / 64; ++wv) tot += wred[wv];
                if (tot >= rem) { bcast_p = q; bcast_rem = rem; }
                else            { bcast_p = p; bcast_rem = rem - tot; }
            }
            __syncthreads();
            p = bcast_p; rem = bcast_rem;
            __syncthreads();
        }
        sstar = p;
        teq = rem;                           // ==sstar ties to take (smallest anchors)
        for (int a = t; a < A_N; a += NT) {
            if (su.sbits[a] == sstar) {
                int slot = atomicAdd(&eqn, 1);
                if (slot < 64) eqlist[slot] = a;
            }
        }
        __syncthreads();
        if (t == 0) {
            int n = eqn < 64 ? eqn : 64;
            for (int i = 1; i < n; ++i) {
                int v = eqlist[i], j = i - 1;
                while (j >= 0 && eqlist[j] > v) { eqlist[j + 1] = eqlist[j]; --j; }
                eqlist[j + 1] = v;
            }
            int tq = teq < n ? teq : n;
            bcast_athr = (tq > 0) ? eqlist[tq - 1] : -1;
        }
        __syncthreads();
    }
    int athr = (nreal >= TOPK) ? bcast_athr : -1;
    __syncthreads();

    for (int a = t; a < A_N; a += NT) {
        unsigned v = su.sbits[a];
        bool sel;
        if (nreal >= TOPK)
            sel = (v > sstar) || (v == sstar && a <= athr);
        else
            sel = (v != 0u);
        if (sel) {
            int slot = atomicAdd(&nsel, 1);
            if (slot < 512)
                wlist[slot] = ((unsigned long long)v << 32) | (unsigned)(~(unsigned)a);
        }
    }
    __syncthreads();
    int ns = nsel < 512 ? nsel : 512;
    if (t < 512 && t >= ns) wlist[t] = 0ull;
    __syncthreads();

    // bitonic sort 512 desc (score desc, anchor asc via ~a) — proven r10
    for (int k = 2; k <= 512; k <<= 1) {
        for (int j = k >> 1; j > 0; j >>= 1) {
            int ixj = t ^ j;
            if (ixj > t) {
                unsigned long long u = wlist[t], v = wlist[ixj];
                bool desc = ((t & k) == 0);
                if (desc ? (u < v) : (u > v)) { wlist[t] = v; wlist[ixj] = u; }
            }
            __syncthreads();
        }
    }

    // ---- per-class NMS on the sorted top-400 (IoU bits identical to r10) ----
    int m = ns < TOPK ? ns : TOPK;
    float offc = (float)(cm + 1) * 301.0f;
    if (t < m) {
        unsigned aidx = ~(unsigned)(wlist[t] & 0xFFFFFFFFull);
        const float* bp = boxes + ((size_t)b * A_N + aidx) * 4;
        float x1 = bp[0] + offc, y1 = bp[1] + offc;   // same expr as r10 suppression
        float x2 = bp[2] + offc, y2 = bp[3] + offc;
        bx1[t] = x1; by1[t] = y1; bx2[t] = x2; by2[t] = y2;
        bar[t] = (x2 - x1) * (y2 - y1);
    }
    __syncthreads();   // last read of su.sbits was above; safe to reuse union

    if (t < m) {
        unsigned long long w[7] = {0, 0, 0, 0, 0, 0, 0};
        float x1 = bx1[t], y1 = by1[t], x2 = bx2[t], y2 = by2[t], a1 = bar[t];
        for (int j = t + 1; j < m; ++j) {
            float lx = fmaxf(x1, bx1[j]), ly = fmaxf(y1, by1[j]);
            float rx = fminf(x2, bx2[j]), ry = fminf(y2, by2[j]);
            float ww = fmaxf(rx - lx, 0.0f), hh = fmaxf(ry - ly, 0.0f);
            float inter = ww * hh;
            float iou = inter / (a1 + bar[j] - inter + 1e-9f);
            if (iou > 0.45f) w[j >> 6] |= 1ull << (j & 63);
        }
        for (int k2 = 0; k2 < 7; ++k2) su.msk[t * 7 + k2] = w[k2];
    }
    __syncthreads();

    if (t == 0) {
        unsigned long long sup[7] = {0, 0, 0, 0, 0, 0, 0};
        int cnt = 0;
        for (int i = 0; i < m; ++i) {
            if (!((sup[i >> 6] >> (i & 63)) & 1ull)) {
                unsigned long long wv = wlist[i];
                unsigned sb = (unsigned)(wv >> 32);
                unsigned a  = ~(unsigned)wv;              // anchor, <16384
                int flat = cm * TOPK + i;
                unsigned long long key =
                    ((unsigned long long)sb << 31) |
                    ((unsigned long long)(131071 - flat) << 14) |
                    (unsigned long long)a;
                kkey[(size_t)bc * MAXDET + cnt] = key;
                cnt++;
                if (cnt == MAXDET) break;
                const unsigned long long* r = &su.msk[i * 7];
                for (int k2 = 0; k2 < 7; ++k2) sup[k2] |= r[k2];
            }
        }
        kcnt[bc] = cnt;
    }
}

// ---------------------------------------------------------------- FALLBACK top-400 + NMS
// Verbatim proven kernel (used only if the workspace can't hold scT).
__global__ __launch_bounds__(NT) void k_topknms(const void* __restrict__ logits,
                                                const int* __restrict__ flag,
                                                const float* __restrict__ amax,
                                                const float* __restrict__ denom,
                                                const float* __restrict__ boxes,
                                                unsigned long long* __restrict__ kkey,
                                                int* __restrict__ kcnt) {
    __shared__ union {
        unsigned sbits[A_N];                 // 34928 B (phase 1: scores)
        unsigned long long msk[TOPK * 7];    // 22400 B (phase 2: NMS bitmask)
    } su;
    __shared__ unsigned long long wlist[512];
    __shared__ float bx1[TOPK], by1[TOPK], bx2[TOPK], by2[TOPK], bar[TOPK];
    __shared__ int wred[NT / 64];
    __shared__ unsigned bcast_p;
    __shared__ int bcast_rem;
    __shared__ int eqlist[64];
    __shared__ int eqn;
    __shared__ int bcast_athr;
    __shared__ int nsel;

    int bc = blockIdx.x;
    int b  = bc / CM1;
    int cm = bc % CM1;                       // class row 0..89 (logit col cm+1)
    int bf = flag[0];
    int t  = threadIdx.x;

    // masked score bits (np exp / np pairwise denom — bit-exact r10 expressions)
    for (int a = t; a < A_N; a += NT) {
        size_t base = (size_t)b * A_N + a;
        float e  = np_expf(ldin(logits, base * C_N + (cm + 1), bf) - amax[base]);
        float sc = e / denom[base];
        su.sbits[a] = (sc > 0.01f) ? __float_as_uint(sc) : 0u;
    }
    if (t == 0) { eqn = 0; nsel = 0; }
    __syncthreads();

    // count of real (above-threshold) entries
    {
        int c0 = 0;
        for (int a = t; a < A_N; a += NT) c0 += (su.sbits[a] != 0u);
        for (int o = 32; o; o >>= 1) c0 += __shfl_down(c0, o);
        if ((t & 63) == 0) wred[t >> 6] = c0;
        __syncthreads();
        if (t == 0) {
            int tot = 0;
            for (int wv = 0; wv < NT / 64; ++wv) tot += wred[wv];
            bcast_rem = tot;
        }
        __syncthreads();
    }
    int nreal = bcast_rem;
    __syncthreads();

    unsigned sstar = 0u;
    int teq = 0;
    if (nreal >= TOPK) {
        unsigned p = 0x3C000000u;
        int rem = TOPK;
        for (int bit = 25; bit >= 0; --bit) {
            unsigned q = p | (1u << bit);
            int cnt = 0;
            for (int a = t; a < A_N; a += NT) cnt += ((su.sbits[a] >> bit) == (q >> bit));
            for (int o = 32; o; o >>= 1) cnt += __shfl_down(cnt, o);
            if ((t & 63) == 0) wred[t >> 6] = cnt;
            __syncthreads();
            if (t == 0) {
                int tot = 0;
                for (int wv = 0; wv < NT / 64; ++wv) tot += wred[wv];
                if (tot >= rem) { bcast_p = q; bcast_rem = rem; }
                else            { bcast_p = p; bcast_rem = rem - tot; }
            }
            __syncthreads();
            p = bcast_p; rem = bcast_rem;
            __syncthreads();
        }
        sstar = p;
        teq = rem;
        for (int a = t; a < A_N; a += NT) {
            if (su.sbits[a] == sstar) {
                int slot = atomicAdd(&eqn, 1);
                if (slot < 64) eqlist[slot] = a;
            }
        }
        __syncthreads();
        if (t == 0) {
            int n = eqn < 64 ? eqn : 64;
            for (int i = 1; i < n; ++i) {
                int v = eqlist[i], j = i - 1;
                while (j >= 0 && eqlist[j] > v) { eqlist[j + 1] = eqlist[j]; --j; }
                eqlist[j + 1] = v;
            }
            int tq = teq < n ? teq : n;
            bcast_athr = (tq > 0) ? eqlist[tq - 1] : -1;
        }
        __syncthreads();
    }
    int athr = (nreal >= TOPK) ? bcast_athr : -1;
    __syncthreads();

    for (int a = t; a < A_N; a += NT) {
        unsigned v = su.sbits[a];
        bool sel;
        if (nreal >= TOPK)
            sel = (v > sstar) || (v == sstar && a <= athr);
        else
            sel = (v != 0u);
        if (sel) {
            int slot = atomicAdd(&nsel, 1);
            if (slot < 512)
                wlist[slot] = ((unsigned long long)v << 32) | (unsigned)(~(unsigned)a);
        }
    }
    __syncthreads();
    int ns = nsel < 512 ? nsel : 512;
    if (t < 512 && t >= ns) wlist[t] = 0ull;
    __syncthreads();

    for (int k = 2; k <= 512; k <<= 1) {
        for (int j = k >> 1; j > 0; j >>= 1) {
            int ixj = t ^ j;
            if (ixj > t) {
                unsigned long long u = wlist[t], v = wlist[ixj];
                bool desc = ((t & k) == 0);
                if (desc ? (u < v) : (u > v)) { wlist[t] = v; wlist[ixj] = u; }
            }
            __syncthreads();
        }
    }

    int m = ns < TOPK ? ns : TOPK;
    float offc = (float)(cm + 1) * 301.0f;
    if (t < m) {
        unsigned aidx = ~(unsigned)(wlist[t] & 0xFFFFFFFFull);
        const float* bp = boxes + ((size_t)b * A_N + aidx) * 4;
        float x1 = bp[0] + offc, y1 = bp[1] + offc;
        float x2 = bp[2] + offc, y2 = bp[3] + offc;
        bx1[t] = x1; by1[t] = y1; bx2[t] = x2; by2[t] = y2;
        bar[t] = (x2 - x1) * (y2 - y1);
    }
    __syncthreads();

    if (t < m) {
        unsigned long long w[7] = {0, 0, 0, 0, 0, 0, 0};
        float x1 = bx1[t], y1 = by1[t], x2 = bx2[t], y2 = by2[t], a1 = bar[t];
        for (int j = t + 1; j < m; ++j) {
            float lx = fmaxf(x1, bx1[j]), ly = fmaxf(y1, by1[j]);
            float rx = fminf(x2, bx2[j]), ry = fminf(y2, by2[j]);
            float ww = fmaxf(rx - lx, 0.0f), hh = fmaxf(ry - ly, 0.0f);
            float inter = ww * hh;
            float iou = inter / (a1 + bar[j] - inter + 1e-9f);
            if (iou > 0.45f) w[j >> 6] |= 1ull << (j & 63);
        }
        for (int k2 = 0; k2 < 7; ++k2) su.msk[t * 7 + k2] = w[k2];
    }
    __syncthreads();

    if (t == 0) {
        unsigned long long sup[7] = {0, 0, 0, 0, 0, 0, 0};
        int cnt = 0;
        for (int i = 0; i < m; ++i) {
            if (!((sup[i >> 6] >> (i & 63)) & 1ull)) {
                unsigned long long wv = wlist[i];
                unsigned sb = (unsigned)(wv >> 32);
                unsigned a  = ~(unsigned)wv;
                int flat = cm * TOPK + i;
                unsigned long long key =
                    ((unsigned long long)sb << 31) |
                    ((unsigned long long)(131071 - flat) << 14) |
                    (unsigned long long)a;
                kkey[(size_t)bc * MAXDET + cnt] = key;
                cnt++;
                if (cnt == MAXDET) break;
                const unsigned long long* r = &su.msk[i * 7];
                for (int k2 = 0; k2 < 7; ++k2) sup[k2] |= r[k2];
            }
        }
        kcnt[bc] = cnt;
    }
}

// ---------------------------------------------------------------- 90-way merge, 1 wave/image
__global__ __launch_bounds__(64) void k_merge(const unsigned long long* __restrict__ kkey,
                                              const int* __restrict__ kcnt,
                                              const float* __restrict__ boxes,
                                              float* __restrict__ out) {
    int b = blockIdx.x;
    int t = threadIdx.x;
    const float* bx = boxes + (size_t)b * A_N * 4;
    float* ob = out + (size_t)b * MAXDET * 4;
    float* os = out + (size_t)B_N * MAXDET * 4 + (size_t)b * MAXDET;
    float* ol = out + (size_t)B_N * MAXDET * 5 + (size_t)b * MAXDET;

    int cls0 = t, cls1 = t + 64;
    int n0 = (cls0 < CM1) ? kcnt[b * CM1 + cls0] : 0;
    int n1 = (cls1 < CM1) ? kcnt[b * CM1 + cls1] : 0;
    const unsigned long long* l0 = kkey + (size_t)(b * CM1 + cls0) * MAXDET;
    const unsigned long long* l1 = kkey + (size_t)(b * CM1 + cls1) * MAXDET;
    int p0 = 0, p1 = 0;
    unsigned long long h0 = (n0 > 0) ? l0[0] : 0ull;
    unsigned long long h1 = (n1 > 0) ? l1[0] : 0ull;
    unsigned long long x0 = (n0 > 1) ? l0[1] : 0ull;   // prefetched next
    unsigned long long x1n = (n1 > 1) ? l1[1] : 0ull;

    for (int slot = 0; slot < MAXDET; ++slot) {
        unsigned long long m = h0 > h1 ? h0 : h1;
        for (int o = 32; o; o >>= 1) {
            unsigned long long v = __shfl_down(m, o);
            if (v > m) m = v;
        }
        m = __shfl(m, 0);                    // broadcast winner key
        if (m == 0ull) {
            if (t == 0) {
                ob[slot * 4 + 0] = 0.0f; ob[slot * 4 + 1] = 0.0f;
                ob[slot * 4 + 2] = 0.0f; ob[slot * 4 + 3] = 0.0f;
                os[slot] = 0.0f; ol[slot] = 0.0f;
            }
        } else {
            if (h0 == m) {                   // unique winner (keys unique)
                int a = (int)(m & 0x3FFFull);
                const float* bp = bx + (size_t)a * 4;
                ob[slot * 4 + 0] = bp[0]; ob[slot * 4 + 1] = bp[1];
                ob[slot * 4 + 2] = bp[2]; ob[slot * 4 + 3] = bp[3];
                os[slot] = __uint_as_float((unsigned)(m >> 31));
                ol[slot] = (float)(cls0 + 1);
                p0++; h0 = x0;
                x0 = (p0 + 1 < n0) ? l0[p0 + 1] : 0ull;
            } else if (h1 == m) {
                int a = (int)(m & 0x3FFFull);
                const float* bp = bx + (size_t)a * 4;
                ob[slot * 4 + 0] = bp[0]; ob[slot * 4 + 1] = bp[1];
                ob[slot * 4 + 2] = bp[2]; ob[slot * 4 + 3] = bp[3];
                os[slot] = __uint_as_float((unsigned)(m >> 31));
                ol[slot] = (float)(cls1 + 1);
                p1++; h1 = x1n;
                x1n = (p1 + 1 < n1) ? l1[p1 + 1] : 0ull;
            }
        }
    }
}

// ---------------------------------------------------------------- host launcher
extern "C" void kernel_launch(void* const* d_in, const int* in_sizes, int n_in,
                              void* d_out, int out_size, void* d_ws, size_t ws_size,
                              hipStream_t stream) {
    const void* logits  = d_in[0];   // [32, 8732, 91] f32
    const void* rel     = d_in[1];   // [32, 8732, 4]
    const void* anchors = d_in[2];   // [8732, 4]
    float* out = (float*)d_out;      // boxes|scores|labels flat, f32

    char* ws = (char*)d_ws;
    size_t off = 0;
    auto alloc = [&](size_t bytes) -> void* {
        void* p = ws + off;
        off = (off + bytes + 255) & ~(size_t)255;
        return p;
    };
    float* boxes  = (float*)alloc((size_t)B_N * A_N * 4 * sizeof(float));
    float* amax   = (float*)alloc((size_t)B_N * A_N * sizeof(float));
    float* denom  = (float*)alloc((size_t)B_N * A_N * sizeof(float));
    int*   flag   = (int*)alloc(256);
    unsigned long long* kkey = (unsigned long long*)alloc((size_t)B_N * CM1 * MAXDET * sizeof(unsigned long long));
    int* kcnt     = (int*)alloc((size_t)B_N * CM1 * sizeof(int));

    // transposed masked-score buffer: [B][90][A] u32 — ~96 MiB. Only used
    // if the workspace can hold it; else fall back to the proven path.
    size_t scT_bytes = (size_t)B_N * CM1 * A_N * sizeof(unsigned);
    unsigned* scT = nullptr;
    if (off + scT_bytes <= ws_size) scT = (unsigned*)alloc(scT_bytes);

    int gridBA = (B_N * A_N + 255) / 256;

    k_sniff<<<1, 256, 0, stream>>>((const unsigned*)logits, flag);
    k_stats<<<gridBA, 256, 0, stream>>>(logits, flag, amax, denom, scT);
    k_decode<<<gridBA, 256, 0, stream>>>(rel, anchors, flag, boxes);
    if (scT)
        k_topknms_pre<<<B_N * CM1, NT, 0, stream>>>(scT, boxes, kkey, kcnt);
    else
        k_topknms<<<B_N * CM1, NT, 0, stream>>>(logits, flag, amax, denom, boxes, kkey, kcnt);
    k_merge<<<B_N, 64, 0, stream>>>(kkey, kcnt, boxes, out);
}

// Round 2
// 957.137 us; speedup vs baseline: 1.4995x; 1.4995x over previous
//
#include <hip/hip_runtime.h>
#include <hip/hip_bf16.h>
#include <cstdint>
#include <cstddef>
#include <math.h>

// Match numpy f32 per-op rounding: no FMA contraction, no reassociation.
// (fmaf() below is explicit and unaffected by the pragma.)
#pragma clang fp contract(off)

#define A_N 8732
#define C_N 91
#define CM1 90
#define B_N 32
#define TOPK 400
#define MAXDET 200
#define NT 512                              /* threads in k_topknms */
#define BBOX_CLIPF 4.135166556742356f       /* log(1000/16) cast to f32 */

// 16B vector of floats with only 4B alignment guarantee (rows are 91 floats,
// so row bases are 4B- but not 16B-aligned). gfx950 global loads support
// dword-aligned dwordx4.
typedef float f4u __attribute__((ext_vector_type(4), aligned(4)));

// Dual-path input load (reference is float32; sniff is insurance).
__device__ __forceinline__ float ldin(const void* p, size_t i, int isbf16) {
    if (isbf16) return __bfloat162float(((const __hip_bfloat16*)p)[i]);
    return ((const float*)p)[i];
}

// numpy SIMD f32 exp — bit-faithful (PROVEN bit-exact in round 10, absmax 0.0).
// DO NOT alter any constant or association.
__device__ __forceinline__ float np_expf(float x) {
    float q = rintf(x * 1.442695040f);
    float r = fmaf(q, -0.693359375f, x);
    r = fmaf(q, 2.12194440e-4f, r);
    float p = 1.9875691500E-4f;
    p = fmaf(p, r, 1.3981999507E-3f);
    p = fmaf(p, r, 8.3334519073E-3f);
    p = fmaf(p, r, 4.1665795894E-2f);
    p = fmaf(p, r, 1.6666665459E-1f);
    p = fmaf(p, r, 5.0000001201E-1f);
    p = fmaf(p, r, 1.0f);
    p = fmaf(p, r, 1.0f);
    return ldexpf(p, (int)q);
}

// ---------------------------------------------------------------- dtype sniff
__global__ void k_sniff(const unsigned* __restrict__ words, int* __restrict__ flag) {
    __shared__ int cnt_s;
    if (threadIdx.x == 0) cnt_s = 0;
    __syncthreads();
    int local = 0;
    for (int i = threadIdx.x; i < 4096; i += 256) {
        unsigned w = words[i];
        unsigned e = (w >> 7) & 0xFFu;
        if (e >= 100u && e <= 140u) local++;
    }
    atomicAdd(&cnt_s, local);
    __syncthreads();
    if (threadIdx.x == 0) flag[0] = (cnt_s > 2048) ? 1 : 0;
}

// ---------------------------------------------------------------- softmax stats
// 2 passes, dwordx4 loads (4x fewer TA line-lookups than scalar strided).
// Pass A: max (sequential fmaxf chain, order identical to reference).
// Pass B: np_expf terms accumulated into the exact numpy pairwise r[8] chains,
// and RAW exp bits stored transposed to scT[(b*90+c-1)*A + a]. Division by
// denom is folded into the consumer (same e/denom expression, bit-exact).
__global__ void k_stats(const void* __restrict__ logits,
                        const int* __restrict__ flag,
                        float* __restrict__ amax,
                        float* __restrict__ denom,
                        unsigned* __restrict__ scT) {
    int i = blockIdx.x * blockDim.x + threadIdx.x;
    if (i >= B_N * A_N) return;
    int bf = flag[0];
    size_t base = (size_t)i * C_N;
    int bb = i / A_N, aa = i - bb * A_N;
    unsigned* sbase = scT ? (scT + (size_t)bb * CM1 * A_N + aa) : (unsigned*)0;

    if (!bf) {
        const float* lp = (const float*)logits + base;
        float m = -INFINITY;
        #pragma unroll
        for (int k = 0; k < 22; ++k) {
            f4u v = *(const f4u*)(lp + 4 * k);
            m = fmaxf(m, v.x); m = fmaxf(m, v.y); m = fmaxf(m, v.z); m = fmaxf(m, v.w);
        }
        m = fmaxf(m, lp[88]); m = fmaxf(m, lp[89]); m = fmaxf(m, lp[90]);

        float r[8];
        #pragma unroll
        for (int k = 0; k < 11; ++k) {
            f4u v0 = *(const f4u*)(lp + 8 * k);
            f4u v1 = *(const f4u*)(lp + 8 * k + 4);
            float e0 = np_expf(v0.x - m), e1 = np_expf(v0.y - m);
            float e2 = np_expf(v0.z - m), e3 = np_expf(v0.w - m);
            float e4 = np_expf(v1.x - m), e5 = np_expf(v1.y - m);
            float e6 = np_expf(v1.z - m), e7 = np_expf(v1.w - m);
            if (k == 0) {
                r[0] = e0; r[1] = e1; r[2] = e2; r[3] = e3;
                r[4] = e4; r[5] = e5; r[6] = e6; r[7] = e7;
                if (sbase) {
                    sbase[(size_t)0 * A_N] = __float_as_uint(e1);
                    sbase[(size_t)1 * A_N] = __float_as_uint(e2);
                    sbase[(size_t)2 * A_N] = __float_as_uint(e3);
                    sbase[(size_t)3 * A_N] = __float_as_uint(e4);
                    sbase[(size_t)4 * A_N] = __float_as_uint(e5);
                    sbase[(size_t)5 * A_N] = __float_as_uint(e6);
                    sbase[(size_t)6 * A_N] = __float_as_uint(e7);
                }
            } else {
                r[0] += e0; r[1] += e1; r[2] += e2; r[3] += e3;
                r[4] += e4; r[5] += e5; r[6] += e6; r[7] += e7;
                if (sbase) {
                    size_t o = (size_t)(8 * k - 1) * A_N;
                    sbase[o]                  = __float_as_uint(e0);
                    sbase[o + (size_t)1 * A_N] = __float_as_uint(e1);
                    sbase[o + (size_t)2 * A_N] = __float_as_uint(e2);
                    sbase[o + (size_t)3 * A_N] = __float_as_uint(e3);
                    sbase[o + (size_t)4 * A_N] = __float_as_uint(e4);
                    sbase[o + (size_t)5 * A_N] = __float_as_uint(e5);
                    sbase[o + (size_t)6 * A_N] = __float_as_uint(e6);
                    sbase[o + (size_t)7 * A_N] = __float_as_uint(e7);
                }
            }
        }
        float res = ((r[0] + r[1]) + (r[2] + r[3])) + ((r[4] + r[5]) + (r[6] + r[7]));
        float e88 = np_expf(lp[88] - m); res += e88;
        float e89 = np_expf(lp[89] - m); res += e89;
        float e90 = np_expf(lp[90] - m); res += e90;
        if (sbase) {
            sbase[(size_t)87 * A_N] = __float_as_uint(e88);
            sbase[(size_t)88 * A_N] = __float_as_uint(e89);
            sbase[(size_t)89 * A_N] = __float_as_uint(e90);
        }
        amax[i]  = m;
        denom[i] = res;
    } else {
        // bf16 insurance path — scalar, same structure as proven r10 code.
        float m = -INFINITY;
        for (int c = 0; c < C_N; ++c) m = fmaxf(m, ldin(logits, base + c, bf));
        float r[8];
        for (int j = 0; j < 8; ++j) r[j] = np_expf(ldin(logits, base + j, bf) - m);
        for (int c = 8; c < 88; c += 8)
            for (int j = 0; j < 8; ++j) r[j] += np_expf(ldin(logits, base + c + j, bf) - m);
        float res = ((r[0] + r[1]) + (r[2] + r[3])) + ((r[4] + r[5]) + (r[6] + r[7]));
        res += np_expf(ldin(logits, base + 88, bf) - m);
        res += np_expf(ldin(logits, base + 89, bf) - m);
        res += np_expf(ldin(logits, base + 90, bf) - m);
        amax[i]  = m;
        denom[i] = res;
        if (sbase) {
            for (int c = 1; c < C_N; ++c)
                sbase[(size_t)(c - 1) * A_N] =
                    __float_as_uint(np_expf(ldin(logits, base + c, bf) - m));
        }
    }
}

// ---------------------------------------------------------------- box decode (PROVEN bit-exact r10)
__global__ void k_decode(const void* __restrict__ rel,
                         const void* __restrict__ anchors,
                         const int* __restrict__ flag,
                         float* __restrict__ boxes) {
    int i = blockIdx.x * blockDim.x + threadIdx.x;
    if (i >= B_N * A_N) return;
    int bf = flag[0];
    int a = i % A_N;
    float ax1, ay1, ax2, ay2, r0, r1, r2, r3;
    if (!bf) {
        float4 av = ((const float4*)anchors)[a];
        float4 rv = ((const float4*)rel)[i];
        ax1 = av.x; ay1 = av.y; ax2 = av.z; ay2 = av.w;
        r0 = rv.x; r1 = rv.y; r2 = rv.z; r3 = rv.w;
    } else {
        ax1 = ldin(anchors, (size_t)a * 4 + 0, bf);
        ay1 = ldin(anchors, (size_t)a * 4 + 1, bf);
        ax2 = ldin(anchors, (size_t)a * 4 + 2, bf);
        ay2 = ldin(anchors, (size_t)a * 4 + 3, bf);
        r0 = ldin(rel, (size_t)i * 4 + 0, bf);
        r1 = ldin(rel, (size_t)i * 4 + 1, bf);
        r2 = ldin(rel, (size_t)i * 4 + 2, bf);
        r3 = ldin(rel, (size_t)i * 4 + 3, bf);
    }
    float wa = ax2 - ax1, ha = ay2 - ay1;
    float cxa = ax1 + 0.5f * wa, cya = ay1 + 0.5f * ha;
    float dx = r0 / 10.0f, dy = r1 / 10.0f;
    float dw = fminf(r2 / 5.0f, BBOX_CLIPF);
    float dh = fminf(r3 / 5.0f, BBOX_CLIPF);
    float cx = dx * wa + cxa, cy = dy * ha + cya;
    float w = np_expf(dw) * wa, h = np_expf(dh) * ha;
    float4 o;
    o.x = fminf(fmaxf(cx - 0.5f * w, 0.0f), 300.0f);
    o.y = fminf(fmaxf(cy - 0.5f * h, 0.0f), 300.0f);
    o.z = fminf(fmaxf(cx + 0.5f * w, 0.0f), 300.0f);
    o.w = fminf(fmaxf(cy + 0.5f * h, 0.0f), 300.0f);
    ((float4*)boxes)[i] = o;
}

// ---------------------------------------------------------------- fused top-400 + per-class NMS
// v3: histogram radix select (3 scans instead of 26), static-indexed NMS mask
// accumulation (no scratch), balanced NMS rows (t pairs with m-1-t), and a
// wave-parallel final suppression scan. Selection set / order / key encoding
// identical to the proven kernel.
__global__ __launch_bounds__(NT) void k_topknms_pre(const unsigned* __restrict__ scT,
                                                    const float* __restrict__ denom,
                                                    const float* __restrict__ boxes,
                                                    unsigned long long* __restrict__ kkey,
                                                    int* __restrict__ kcnt) {
    __shared__ __align__(16) union {
        unsigned sbits[A_N];                 // 34928 B (phase 1: masked scores)
        unsigned long long msk[TOPK * 7];    // 22400 B (phase 2: NMS bitmask)
    } su;
    __shared__ __align__(16) union {
        struct { float x1[TOPK], y1[TOPK], x2[TOPK], y2[TOPK], ar[TOPK]; } nb; // 8000 B (NMS)
        unsigned hist[1024];                 // 4096 B (radix-select histograms)
    } sb;
    __shared__ unsigned long long wlist[512];
    __shared__ int wred[NT / 64];
    __shared__ unsigned sel_b;
    __shared__ int sel_rem;
    __shared__ int eqlist[64];
    __shared__ int eqn;
    __shared__ int nsel;

    int bc = blockIdx.x;
    int b  = bc / CM1;
    int cm = bc % CM1;                       // class row 0..89 (logit col cm+1)
    int t  = threadIdx.x;

    // ---- phase 0: coalesced read of raw exp bits, divide by denom (same
    // e/denom expression as proven code), mask, stage to LDS, fused count.
    const uint4*  src = (const uint4*)(scT + (size_t)bc * A_N);
    const float4* dnm = (const float4*)(denom + (size_t)b * A_N);
    uint4* dst = (uint4*)su.sbits;
    int c0 = 0;
    for (int k = t; k < A_N / 4; k += NT) {
        uint4 ev = src[k];
        float4 dv = dnm[k];
        float s0 = __uint_as_float(ev.x) / dv.x;
        float s1 = __uint_as_float(ev.y) / dv.y;
        float s2 = __uint_as_float(ev.z) / dv.z;
        float s3 = __uint_as_float(ev.w) / dv.w;
        uint4 o;
        o.x = (s0 > 0.01f) ? __float_as_uint(s0) : 0u;
        o.y = (s1 > 0.01f) ? __float_as_uint(s1) : 0u;
        o.z = (s2 > 0.01f) ? __float_as_uint(s2) : 0u;
        o.w = (s3 > 0.01f) ? __float_as_uint(s3) : 0u;
        dst[k] = o;
        c0 += (o.x != 0u) + (o.y != 0u) + (o.z != 0u) + (o.w != 0u);
    }
    if (t == 0) { eqn = 0; nsel = 0; }
    for (int o = 32; o; o >>= 1) c0 += __shfl_down(c0, o);
    if ((t & 63) == 0) wred[t >> 6] = c0;
    __syncthreads();
    if (t == 0) {
        int tot = 0;
        for (int wv = 0; wv < NT / 64; ++wv) tot += wred[wv];
        sel_rem = tot;
    }
    __syncthreads();
    int nreal = sel_rem;
    __syncthreads();

    // ---- histogram radix select of the 400th largest (equivalent to the
    // proven 26-pass bit-serial select: same sstar, same tie count teq).
    // All masked scores lie in (0.01, 1.0]: bits 30..26 == 0b01111 fixed;
    // levels refine bits 25..16 / 15..6 / 5..0.
    unsigned sstar = 0u;
    int teq = 0;
    if (nreal >= TOPK) {
        unsigned prefix = 0xFu;
        // Level 1: bits 25..16
        if (t == 0) sel_rem = TOPK;
        for (int q = t; q < 1024; q += NT) sb.hist[q] = 0u;
        __syncthreads();
        for (int a = t; a < A_N; a += NT) {
            unsigned v = su.sbits[a];
            if (v) atomicAdd(&sb.hist[(v >> 16) & 0x3FFu], 1u);
        }
        __syncthreads();
        if (t < 64) {
            int rem = sel_rem;
            unsigned s = 0;
            #pragma unroll
            for (int q = 0; q < 16; ++q) s += sb.hist[16 * t + q];
            unsigned suf = s;
            for (int o = 1; o < 64; o <<= 1) {
                unsigned vv = __shfl_down(suf, o);
                if (t + o < 64) suf += vv;
            }
            unsigned cum = suf - s;          // count in buckets above this lane's
            for (int q = 15; q >= 0; --q) {  // walk own 16 buckets high->low
                unsigned h = sb.hist[16 * t + q];
                if ((int)cum < rem && rem <= (int)(cum + h)) {
                    sel_b = (unsigned)(16 * t + q);
                    sel_rem = rem - (int)cum;
                }
                cum += h;
            }
        }
        __syncthreads();
        prefix = (prefix << 10) | sel_b;

        // Level 2: bits 15..6
        for (int q = t; q < 1024; q += NT) sb.hist[q] = 0u;
        __syncthreads();
        for (int a = t; a < A_N; a += NT) {
            unsigned v = su.sbits[a];
            if ((v >> 16) == prefix) atomicAdd(&sb.hist[(v >> 6) & 0x3FFu], 1u);
        }
        __syncthreads();
        if (t < 64) {
            int rem = sel_rem;
            unsigned s = 0;
            #pragma unroll
            for (int q = 0; q < 16; ++q) s += sb.hist[16 * t + q];
            unsigned suf = s;
            for (int o = 1; o < 64; o <<= 1) {
                unsigned vv = __shfl_down(suf, o);
                if (t + o < 64) suf += vv;
            }
            unsigned cum = suf - s;
            for (int q = 15; q >= 0; --q) {
                unsigned h = sb.hist[16 * t + q];
                if ((int)cum < rem && rem <= (int)(cum + h)) {
                    sel_b = (unsigned)(16 * t + q);
                    sel_rem = rem - (int)cum;
                }
                cum += h;
            }
        }
        __syncthreads();
        prefix = (prefix << 10) | sel_b;

        // Level 3: bits 5..0 (64 buckets, serial walk by t==0)
        if (t < 64) sb.hist[t] = 0u;
        __syncthreads();
        for (int a = t; a < A_N; a += NT) {
            unsigned v = su.sbits[a];
            if ((v >> 6) == prefix) atomicAdd(&sb.hist[v & 0x3Fu], 1u);
        }
        __syncthreads();
        if (t == 0) {
            int rem = sel_rem;
            unsigned cum = 0;
            for (int bq = 63; bq >= 0; --bq) {
                unsigned h = sb.hist[bq];
                if ((int)cum < rem && rem <= (int)(cum + h)) {
                    sel_b = (unsigned)bq;
                    sel_rem = rem - (int)cum;
                    break;
                }
                cum += h;
            }
        }
        __syncthreads();
        sstar = (prefix << 6) | sel_b;
        teq = sel_rem;                       // ties at sstar to take
    }

    // ---- combined selection scan: strictly-greater -> wlist, ties -> eqlist.
    for (int a = t; a < A_N; a += NT) {
        unsigned v = su.sbits[a];
        if (nreal >= TOPK) {
            if (v > sstar) {
                int slot = atomicAdd(&nsel, 1);
                if (slot < 512)
                    wlist[slot] = ((unsigned long long)v << 32) | (unsigned)(~(unsigned)a);
            } else if (v == sstar) {
                int s2 = atomicAdd(&eqn, 1);
                if (s2 < 64) eqlist[s2] = a;
            }
        } else if (v != 0u) {
            int slot = atomicAdd(&nsel, 1);
            if (slot < 512)
                wlist[slot] = ((unsigned long long)v << 32) | (unsigned)(~(unsigned)a);
        }
    }
    __syncthreads();
    if (t == 0 && nreal >= TOPK) {
        int n = eqn < 64 ? eqn : 64;         // same 64-cap as proven kernel
        for (int i2 = 1; i2 < n; ++i2) {     // sort ties by anchor asc
            int v2 = eqlist[i2], j2 = i2 - 1;
            while (j2 >= 0 && eqlist[j2] > v2) { eqlist[j2 + 1] = eqlist[j2]; --j2; }
            eqlist[j2 + 1] = v2;
        }
        int tq = teq < n ? teq : n;
        int bse = nsel;
        for (int q2 = 0; q2 < tq; ++q2) {    // take tq smallest-anchor ties
            int slot = bse + q2;
            if (slot < 512)
                wlist[slot] = ((unsigned long long)sstar << 32) |
                              (unsigned)(~(unsigned)eqlist[q2]);
        }
        nsel = bse + tq;
    }
    __syncthreads();
    int ns = nsel < 512 ? nsel : 512;
    if (t >= ns) wlist[t] = 0ull;
    __syncthreads();

    // bitonic sort 512 desc (score desc, anchor asc via ~a) — proven r10
    for (int k = 2; k <= 512; k <<= 1) {
        for (int j = k >> 1; j > 0; j >>= 1) {
            int ixj = t ^ j;
            if (ixj > t) {
                unsigned long long u = wlist[t], v = wlist[ixj];
                bool desc = ((t & k) == 0);
                if (desc ? (u < v) : (u > v)) { wlist[t] = v; wlist[ixj] = u; }
            }
            __syncthreads();
        }
    }

    // ---- per-class NMS on the sorted top-400 (IoU bits identical to r10) ----
    int m = ns < TOPK ? ns : TOPK;
    float offc = (float)(cm + 1) * 301.0f;
    if (t < m) {
        unsigned aidx = ~(unsigned)(wlist[t] & 0xFFFFFFFFull);
        const float* bp = boxes + ((size_t)b * A_N + aidx) * 4;
        float x1 = bp[0] + offc, y1 = bp[1] + offc;   // same expr as r10
        float x2 = bp[2] + offc, y2 = bp[3] + offc;
        sb.nb.x1[t] = x1; sb.nb.y1[t] = y1; sb.nb.x2[t] = x2; sb.nb.y2[t] = y2;
        sb.nb.ar[t] = (x2 - x1) * (y2 - y1);
    }
    __syncthreads();   // su.sbits dead; safe to reuse union as msk

    // balanced rows: thread t computes rows t and m-1-t (each thread m-1 IoUs).
    // Mask words accumulated in a register (static index) — no scratch.
    int half = (m + 1) >> 1;
    if (t < half) {
        for (int rr = 0; rr < 2; ++rr) {
            int i2 = rr ? (m - 1 - t) : t;
            if (rr && i2 == t) break;
            float x1 = sb.nb.x1[i2], y1 = sb.nb.y1[i2];
            float x2 = sb.nb.x2[i2], y2 = sb.nb.y2[i2], a1 = sb.nb.ar[i2];
            #pragma unroll
            for (int jw = 0; jw < 7; ++jw) {
                unsigned long long acc = 0ull;
                int j0 = jw * 64; if (j0 < i2 + 1) j0 = i2 + 1;
                int j1 = jw * 64 + 64; if (j1 > m) j1 = m;
                for (int j = j0; j < j1; ++j) {
                    float lx = fmaxf(x1, sb.nb.x1[j]), ly = fmaxf(y1, sb.nb.y1[j]);
                    float rx = fminf(x2, sb.nb.x2[j]), ry = fminf(y2, sb.nb.y2[j]);
                    float ww = fmaxf(rx - lx, 0.0f), hh = fmaxf(ry - ly, 0.0f);
                    float inter = ww * hh;
                    float iou = inter / (a1 + sb.nb.ar[j] - inter + 1e-9f);
                    if (iou > 0.45f) acc |= 1ull << (j & 63);
                }
                su.msk[i2 * 7 + jw] = acc;
            }
        }
    }
    __syncthreads();

    // ---- wave-parallel greedy suppression scan (order identical to serial):
    // lane k<7 holds suppression word k in a register; decision broadcast via
    // shfl; each kept row ORs its 7-word mask in one parallel LDS read.
    if (t < 64) {
        unsigned long long supw = 0ull;
        int cnt = 0;
        for (int i2 = 0; i2 < m; ++i2) {
            unsigned long long wsup = __shfl(supw, i2 >> 6);
            if (!((wsup >> (i2 & 63)) & 1ull)) {
                if (t == 0) {
                    unsigned long long wv = wlist[i2];
                    unsigned sbts = (unsigned)(wv >> 32);
                    unsigned aa2  = ~(unsigned)wv;        // anchor, <16384
                    int flat = cm * TOPK + i2;
                    unsigned long long key =
                        ((unsigned long long)sbts << 31) |
                        ((unsigned long long)(131071 - flat) << 14) |
                        (unsigned long long)aa2;
                    kkey[(size_t)bc * MAXDET + cnt] = key;
                }
                cnt++;
                if (cnt == MAXDET) break;
                unsigned long long rmw = (t < 7) ? su.msk[i2 * 7 + t] : 0ull;
                supw |= rmw;
            }
        }
        if (t == 0) kcnt[bc] = cnt;
    }
}

// ---------------------------------------------------------------- FALLBACK top-400 + NMS
// Verbatim proven kernel (used only if the workspace can't hold scT).
__global__ __launch_bounds__(NT) void k_topknms(const void* __restrict__ logits,
                                                const int* __restrict__ flag,
                                                const float* __restrict__ amax,
                                                const float* __restrict__ denom,
                                                const float* __restrict__ boxes,
                                                unsigned long long* __restrict__ kkey,
                                                int* __restrict__ kcnt) {
    __shared__ union {
        unsigned sbits[A_N];
        unsigned long long msk[TOPK * 7];
    } su;
    __shared__ unsigned long long wlist[512];
    __shared__ float bx1[TOPK], by1[TOPK], bx2[TOPK], by2[TOPK], bar[TOPK];
    __shared__ int wred[NT / 64];
    __shared__ unsigned bcast_p;
    __shared__ int bcast_rem;
    __shared__ int eqlist[64];
    __shared__ int eqn;
    __shared__ int bcast_athr;
    __shared__ int nsel;

    int bc = blockIdx.x;
    int b  = bc / CM1;
    int cm = bc % CM1;
    int bf = flag[0];
    int t  = threadIdx.x;

    for (int a = t; a < A_N; a += NT) {
        size_t base = (size_t)b * A_N + a;
        float e  = np_expf(ldin(logits, base * C_N + (cm + 1), bf) - amax[base]);
        float sc = e / denom[base];
        su.sbits[a] = (sc > 0.01f) ? __float_as_uint(sc) : 0u;
    }
    if (t == 0) { eqn = 0; nsel = 0; }
    __syncthreads();

    {
        int c0 = 0;
        for (int a = t; a < A_N; a += NT) c0 += (su.sbits[a] != 0u);
        for (int o = 32; o; o >>= 1) c0 += __shfl_down(c0, o);
        if ((t & 63) == 0) wred[t >> 6] = c0;
        __syncthreads();
        if (t == 0) {
            int tot = 0;
            for (int wv = 0; wv < NT / 64; ++wv) tot += wred[wv];
            bcast_rem = tot;
        }
        __syncthreads();
    }
    int nreal = bcast_rem;
    __syncthreads();

    unsigned sstar = 0u;
    int teq = 0;
    if (nreal >= TOPK) {
        unsigned p = 0x3C000000u;
        int rem = TOPK;
        for (int bit = 25; bit >= 0; --bit) {
            unsigned q = p | (1u << bit);
            int cnt = 0;
            for (int a = t; a < A_N; a += NT) cnt += ((su.sbits[a] >> bit) == (q >> bit));
            for (int o = 32; o; o >>= 1) cnt += __shfl_down(cnt, o);
            if ((t & 63) == 0) wred[t >> 6] = cnt;
            __syncthreads();
            if (t == 0) {
                int tot = 0;
                for (int wv = 0; wv < NT / 64; ++wv) tot += wred[wv];
                if (tot >= rem) { bcast_p = q; bcast_rem = rem; }
                else            { bcast_p = p; bcast_rem = rem - tot; }
            }
            __syncthreads();
            p = bcast_p; rem = bcast_rem;
            __syncthreads();
        }
        sstar = p;
        teq = rem;
        for (int a = t; a < A_N; a += NT) {
            if (su.sbits[a] == sstar) {
                int slot = atomicAdd(&eqn, 1);
                if (slot < 64) eqlist[slot] = a;
            }
        }
        __syncthreads();
        if (t == 0) {
            int n = eqn < 64 ? eqn : 64;
            for (int i = 1; i < n; ++i) {
                int v = eqlist[i], j = i - 1;
                while (j >= 0 && eqlist[j] > v) { eqlist[j + 1] = eqlist[j]; --j; }
                eqlist[j + 1] = v;
            }
            int tq = teq < n ? teq : n;
            bcast_athr = (tq > 0) ? eqlist[tq - 1] : -1;
        }
        __syncthreads();
    }
    int athr = (nreal >= TOPK) ? bcast_athr : -1;
    __syncthreads();

    for (int a = t; a < A_N; a += NT) {
        unsigned v = su.sbits[a];
        bool sel;
        if (nreal >= TOPK)
            sel = (v > sstar) || (v == sstar && a <= athr);
        else
            sel = (v != 0u);
        if (sel) {
            int slot = atomicAdd(&nsel, 1);
            if (slot < 512)
                wlist[slot] = ((unsigned long long)v << 32) | (unsigned)(~(unsigned)a);
        }
    }
    __syncthreads();
    int ns = nsel < 512 ? nsel : 512;
    if (t < 512 && t >= ns) wlist[t] = 0ull;
    __syncthreads();

    for (int k = 2; k <= 512; k <<= 1) {
        for (int j = k >> 1; j > 0; j >>= 1) {
            int ixj = t ^ j;
            if (ixj > t) {
                unsigned long long u = wlist[t], v = wlist[ixj];
                bool desc = ((t & k) == 0);
                if (desc ? (u < v) : (u > v)) { wlist[t] = v; wlist[ixj] = u; }
            }
            __syncthreads();
        }
    }

    int m = ns < TOPK ? ns : TOPK;
    float offc = (float)(cm + 1) * 301.0f;
    if (t < m) {
        unsigned aidx = ~(unsigned)(wlist[t] & 0xFFFFFFFFull);
        const float* bp = boxes + ((size_t)b * A_N + aidx) * 4;
        float x1 = bp[0] + offc, y1 = bp[1] + offc;
        float x2 = bp[2] + offc, y2 = bp[3] + offc;
        bx1[t] = x1; by1[t] = y1; bx2[t] = x2; by2[t] = y2;
        bar[t] = (x2 - x1) * (y2 - y1);
    }
    __syncthreads();

    if (t < m) {
        unsigned long long w[7] = {0, 0, 0, 0, 0, 0, 0};
        float x1 = bx1[t], y1 = by1[t], x2 = bx2[t], y2 = by2[t], a1 = bar[t];
        for (int j = t + 1; j < m; ++j) {
            float lx = fmaxf(x1, bx1[j]), ly = fmaxf(y1, by1[j]);
            float rx = fminf(x2, bx2[j]), ry = fminf(y2, by2[j]);
            float ww = fmaxf(rx - lx, 0.0f), hh = fmaxf(ry - ly, 0.0f);
            float inter = ww * hh;
            float iou = inter / (a1 + bar[j] - inter + 1e-9f);
            if (iou > 0.45f) w[j >> 6] |= 1ull << (j & 63);
        }
        for (int k2 = 0; k2 < 7; ++k2) su.msk[t * 7 + k2] = w[k2];
    }
    __syncthreads();

    if (t == 0) {
        unsigned long long sup[7] = {0, 0, 0, 0, 0, 0, 0};
        int cnt = 0;
        for (int i = 0; i < m; ++i) {
            if (!((sup[i >> 6] >> (i & 63)) & 1ull)) {
                unsigned long long wv = wlist[i];
                unsigned sb2 = (unsigned)(wv >> 32);
                unsigned a  = ~(unsigned)wv;
                int flat = cm * TOPK + i;
                unsigned long long key =
                    ((unsigned long long)sb2 << 31) |
                    ((unsigned long long)(131071 - flat) << 14) |
                    (unsigned long long)a;
                kkey[(size_t)bc * MAXDET + cnt] = key;
                cnt++;
                if (cnt == MAXDET) break;
                const unsigned long long* r = &su.msk[i * 7];
                for (int k2 = 0; k2 < 7; ++k2) sup[k2] |= r[k2];
            }
        }
        kcnt[bc] = cnt;
    }
}

// ---------------------------------------------------------------- 90-way merge, 1 wave/image
__global__ __launch_bounds__(64) void k_merge(const unsigned long long* __restrict__ kkey,
                                              const int* __restrict__ kcnt,
                                              const float* __restrict__ boxes,
                                              float* __restrict__ out) {
    int b = blockIdx.x;
    int t = threadIdx.x;
    const float* bx = boxes + (size_t)b * A_N * 4;
    float* ob = out + (size_t)b * MAXDET * 4;
    float* os = out + (size_t)B_N * MAXDET * 4 + (size_t)b * MAXDET;
    float* ol = out + (size_t)B_N * MAXDET * 5 + (size_t)b * MAXDET;

    int cls0 = t, cls1 = t + 64;
    int n0 = (cls0 < CM1) ? kcnt[b * CM1 + cls0] : 0;
    int n1 = (cls1 < CM1) ? kcnt[b * CM1 + cls1] : 0;
    const unsigned long long* l0 = kkey + (size_t)(b * CM1 + cls0) * MAXDET;
    const unsigned long long* l1 = kkey + (size_t)(b * CM1 + cls1) * MAXDET;
    int p0 = 0, p1 = 0;
    unsigned long long h0 = (n0 > 0) ? l0[0] : 0ull;
    unsigned long long h1 = (n1 > 0) ? l1[0] : 0ull;
    unsigned long long x0 = (n0 > 1) ? l0[1] : 0ull;
    unsigned long long x1n = (n1 > 1) ? l1[1] : 0ull;

    for (int slot = 0; slot < MAXDET; ++slot) {
        unsigned long long m = h0 > h1 ? h0 : h1;
        for (int o = 32; o; o >>= 1) {
            unsigned long long v = __shfl_down(m, o);
            if (v > m) m = v;
        }
        m = __shfl(m, 0);
        if (m == 0ull) {
            if (t == 0) {
                ob[slot * 4 + 0] = 0.0f; ob[slot * 4 + 1] = 0.0f;
                ob[slot * 4 + 2] = 0.0f; ob[slot * 4 + 3] = 0.0f;
                os[slot] = 0.0f; ol[slot] = 0.0f;
            }
        } else {
            if (h0 == m) {
                int a = (int)(m & 0x3FFFull);
                const float* bp = bx + (size_t)a * 4;
                ob[slot * 4 + 0] = bp[0]; ob[slot * 4 + 1] = bp[1];
                ob[slot * 4 + 2] = bp[2]; ob[slot * 4 + 3] = bp[3];
                os[slot] = __uint_as_float((unsigned)(m >> 31));
                ol[slot] = (float)(cls0 + 1);
                p0++; h0 = x0;
                x0 = (p0 + 1 < n0) ? l0[p0 + 1] : 0ull;
            } else if (h1 == m) {
                int a = (int)(m & 0x3FFFull);
                const float* bp = bx + (size_t)a * 4;
                ob[slot * 4 + 0] = bp[0]; ob[slot * 4 + 1] = bp[1];
                ob[slot * 4 + 2] = bp[2]; ob[slot * 4 + 3] = bp[3];
                os[slot] = __uint_as_float((unsigned)(m >> 31));
                ol[slot] = (float)(cls1 + 1);
                p1++; h1 = x1n;
                x1n = (p1 + 1 < n1) ? l1[p1 + 1] : 0ull;
            }
        }
    }
}

// ---------------------------------------------------------------- host launcher
extern "C" void kernel_launch(void* const* d_in, const int* in_sizes, int n_in,
                              void* d_out, int out_size, void* d_ws, size_t ws_size,
                              hipStream_t stream) {
    const void* logits  = d_in[0];   // [32, 8732, 91] f32
    const void* rel     = d_in[1];   // [32, 8732, 4]
    const void* anchors = d_in[2];   // [8732, 4]
    float* out = (float*)d_out;      // boxes|scores|labels flat, f32

    char* ws = (char*)d_ws;
    size_t off = 0;
    auto alloc = [&](size_t bytes) -> void* {
        void* p = ws + off;
        off = (off + bytes + 255) & ~(size_t)255;
        return p;
    };
    float* boxes  = (float*)alloc((size_t)B_N * A_N * 4 * sizeof(float));
    float* amax   = (float*)alloc((size_t)B_N * A_N * sizeof(float));
    float* denom  = (float*)alloc((size_t)B_N * A_N * sizeof(float));
    int*   flag   = (int*)alloc(256);
    unsigned long long* kkey = (unsigned long long*)alloc((size_t)B_N * CM1 * MAXDET * sizeof(unsigned long long));
    int* kcnt     = (int*)alloc((size_t)B_N * CM1 * sizeof(int));

    // transposed raw-exp buffer: [B][90][A] u32 — ~96 MiB. Only used if the
    // workspace can hold it; else fall back to the proven path.
    size_t scT_bytes = (size_t)B_N * CM1 * A_N * sizeof(unsigned);
    unsigned* scT = nullptr;
    if (off + scT_bytes <= ws_size) scT = (unsigned*)alloc(scT_bytes);

    int gridBA = (B_N * A_N + 255) / 256;

    k_sniff<<<1, 256, 0, stream>>>((const unsigned*)logits, flag);
    k_stats<<<gridBA, 256, 0, stream>>>(logits, flag, amax, denom, scT);
    k_decode<<<gridBA, 256, 0, stream>>>(rel, anchors, flag, boxes);
    if (scT)
        k_topknms_pre<<<B_N * CM1, NT, 0, stream>>>(scT, denom, boxes, kkey, kcnt);
    else
        k_topknms<<<B_N * CM1, NT, 0, stream>>>(logits, flag, amax, denom, boxes, kkey, kcnt);
    k_merge<<<B_N, 64, 0, stream>>>(kkey, kcnt, boxes, out);
}

// Round 3
// 851.758 us; speedup vs baseline: 1.6850x; 1.1237x over previous
//
#include <hip/hip_runtime.h>
#include <hip/hip_bf16.h>
#include <cstdint>
#include <cstddef>
#include <math.h>

// Match numpy f32 per-op rounding: no FMA contraction, no reassociation.
// (fmaf() below is explicit and unaffected by the pragma.)
#pragma clang fp contract(off)

#define A_N 8732
#define C_N 91
#define CM1 90
#define B_N 32
#define TOPK 400
#define MAXDET 200
#define NT 512                              /* threads in k_topknms */
#define BBOX_CLIPF 4.135166556742356f       /* log(1000/16) cast to f32 */

// Exact predicate constant: for c = 0.45f (even mantissa),
// RN(x/y) > c  <=>  x > (c + 2^-26)*y  with the product exact in double
// (25-bit * 24-bit mantissa). Bit-equivalent to the IEEE f32 divide+compare.
#define IOU_M ((double)0.45f + 0x1p-26)

// 16B vector of floats with only 4B alignment guarantee (rows are 91 floats,
// so row bases are 4B- but not 16B-aligned). gfx950 global loads support
// dword-aligned dwordx4.
typedef float f4u __attribute__((ext_vector_type(4), aligned(4)));

// Dual-path input load (reference is float32; sniff is insurance).
__device__ __forceinline__ float ldin(const void* p, size_t i, int isbf16) {
    if (isbf16) return __bfloat162float(((const __hip_bfloat16*)p)[i]);
    return ((const float*)p)[i];
}

// numpy SIMD f32 exp — bit-faithful (PROVEN bit-exact in round 10, absmax 0.0).
// DO NOT alter any constant or association.
__device__ __forceinline__ float np_expf(float x) {
    float q = rintf(x * 1.442695040f);
    float r = fmaf(q, -0.693359375f, x);
    r = fmaf(q, 2.12194440e-4f, r);
    float p = 1.9875691500E-4f;
    p = fmaf(p, r, 1.3981999507E-3f);
    p = fmaf(p, r, 8.3334519073E-3f);
    p = fmaf(p, r, 4.1665795894E-2f);
    p = fmaf(p, r, 1.6666665459E-1f);
    p = fmaf(p, r, 5.0000001201E-1f);
    p = fmaf(p, r, 1.0f);
    p = fmaf(p, r, 1.0f);
    return ldexpf(p, (int)q);
}

// ---------------------------------------------------------------- dtype sniff
__global__ void k_sniff(const unsigned* __restrict__ words, int* __restrict__ flag) {
    __shared__ int cnt_s;
    if (threadIdx.x == 0) cnt_s = 0;
    __syncthreads();
    int local = 0;
    for (int i = threadIdx.x; i < 4096; i += 256) {
        unsigned w = words[i];
        unsigned e = (w >> 7) & 0xFFu;
        if (e >= 100u && e <= 140u) local++;
    }
    atomicAdd(&cnt_s, local);
    __syncthreads();
    if (threadIdx.x == 0) flag[0] = (cnt_s > 2048) ? 1 : 0;
}

// ---------------------------------------------------------------- softmax stats
// 2 passes, dwordx4 loads. Pass A: max (sequential fmaxf chain). Pass B:
// np_expf terms accumulated into the exact numpy pairwise r[8] chains, RAW exp
// bits stored transposed to scT[(b*90+c-1)*A + a]. Division by denom is folded
// into the consumer (same e/denom expression, bit-exact).
__global__ void k_stats(const void* __restrict__ logits,
                        const int* __restrict__ flag,
                        float* __restrict__ amax,
                        float* __restrict__ denom,
                        unsigned* __restrict__ scT) {
    int i = blockIdx.x * blockDim.x + threadIdx.x;
    if (i >= B_N * A_N) return;
    int bf = flag[0];
    size_t base = (size_t)i * C_N;
    int bb = i / A_N, aa = i - bb * A_N;
    unsigned* sbase = scT ? (scT + (size_t)bb * CM1 * A_N + aa) : (unsigned*)0;

    if (!bf) {
        const float* lp = (const float*)logits + base;
        float m = -INFINITY;
        #pragma unroll
        for (int k = 0; k < 22; ++k) {
            f4u v = *(const f4u*)(lp + 4 * k);
            m = fmaxf(m, v.x); m = fmaxf(m, v.y); m = fmaxf(m, v.z); m = fmaxf(m, v.w);
        }
        m = fmaxf(m, lp[88]); m = fmaxf(m, lp[89]); m = fmaxf(m, lp[90]);

        float r[8];
        #pragma unroll
        for (int k = 0; k < 11; ++k) {
            f4u v0 = *(const f4u*)(lp + 8 * k);
            f4u v1 = *(const f4u*)(lp + 8 * k + 4);
            float e0 = np_expf(v0.x - m), e1 = np_expf(v0.y - m);
            float e2 = np_expf(v0.z - m), e3 = np_expf(v0.w - m);
            float e4 = np_expf(v1.x - m), e5 = np_expf(v1.y - m);
            float e6 = np_expf(v1.z - m), e7 = np_expf(v1.w - m);
            if (k == 0) {
                r[0] = e0; r[1] = e1; r[2] = e2; r[3] = e3;
                r[4] = e4; r[5] = e5; r[6] = e6; r[7] = e7;
                if (sbase) {
                    sbase[(size_t)0 * A_N] = __float_as_uint(e1);
                    sbase[(size_t)1 * A_N] = __float_as_uint(e2);
                    sbase[(size_t)2 * A_N] = __float_as_uint(e3);
                    sbase[(size_t)3 * A_N] = __float_as_uint(e4);
                    sbase[(size_t)4 * A_N] = __float_as_uint(e5);
                    sbase[(size_t)5 * A_N] = __float_as_uint(e6);
                    sbase[(size_t)6 * A_N] = __float_as_uint(e7);
                }
            } else {
                r[0] += e0; r[1] += e1; r[2] += e2; r[3] += e3;
                r[4] += e4; r[5] += e5; r[6] += e6; r[7] += e7;
                if (sbase) {
                    size_t o = (size_t)(8 * k - 1) * A_N;
                    sbase[o]                  = __float_as_uint(e0);
                    sbase[o + (size_t)1 * A_N] = __float_as_uint(e1);
                    sbase[o + (size_t)2 * A_N] = __float_as_uint(e2);
                    sbase[o + (size_t)3 * A_N] = __float_as_uint(e3);
                    sbase[o + (size_t)4 * A_N] = __float_as_uint(e4);
                    sbase[o + (size_t)5 * A_N] = __float_as_uint(e5);
                    sbase[o + (size_t)6 * A_N] = __float_as_uint(e6);
                    sbase[o + (size_t)7 * A_N] = __float_as_uint(e7);
                }
            }
        }
        float res = ((r[0] + r[1]) + (r[2] + r[3])) + ((r[4] + r[5]) + (r[6] + r[7]));
        float e88 = np_expf(lp[88] - m); res += e88;
        float e89 = np_expf(lp[89] - m); res += e89;
        float e90 = np_expf(lp[90] - m); res += e90;
        if (sbase) {
            sbase[(size_t)87 * A_N] = __float_as_uint(e88);
            sbase[(size_t)88 * A_N] = __float_as_uint(e89);
            sbase[(size_t)89 * A_N] = __float_as_uint(e90);
        }
        amax[i]  = m;
        denom[i] = res;
    } else {
        // bf16 insurance path — scalar, same structure as proven r10 code.
        float m = -INFINITY;
        for (int c = 0; c < C_N; ++c) m = fmaxf(m, ldin(logits, base + c, bf));
        float r[8];
        for (int j = 0; j < 8; ++j) r[j] = np_expf(ldin(logits, base + j, bf) - m);
        for (int c = 8; c < 88; c += 8)
            for (int j = 0; j < 8; ++j) r[j] += np_expf(ldin(logits, base + c + j, bf) - m);
        float res = ((r[0] + r[1]) + (r[2] + r[3])) + ((r[4] + r[5]) + (r[6] + r[7]));
        res += np_expf(ldin(logits, base + 88, bf) - m);
        res += np_expf(ldin(logits, base + 89, bf) - m);
        res += np_expf(ldin(logits, base + 90, bf) - m);
        amax[i]  = m;
        denom[i] = res;
        if (sbase) {
            for (int c = 1; c < C_N; ++c)
                sbase[(size_t)(c - 1) * A_N] =
                    __float_as_uint(np_expf(ldin(logits, base + c, bf) - m));
        }
    }
}

// ---------------------------------------------------------------- box decode (PROVEN bit-exact r10)
__global__ void k_decode(const void* __restrict__ rel,
                         const void* __restrict__ anchors,
                         const int* __restrict__ flag,
                         float* __restrict__ boxes) {
    int i = blockIdx.x * blockDim.x + threadIdx.x;
    if (i >= B_N * A_N) return;
    int bf = flag[0];
    int a = i % A_N;
    float ax1, ay1, ax2, ay2, r0, r1, r2, r3;
    if (!bf) {
        float4 av = ((const float4*)anchors)[a];
        float4 rv = ((const float4*)rel)[i];
        ax1 = av.x; ay1 = av.y; ax2 = av.z; ay2 = av.w;
        r0 = rv.x; r1 = rv.y; r2 = rv.z; r3 = rv.w;
    } else {
        ax1 = ldin(anchors, (size_t)a * 4 + 0, bf);
        ay1 = ldin(anchors, (size_t)a * 4 + 1, bf);
        ax2 = ldin(anchors, (size_t)a * 4 + 2, bf);
        ay2 = ldin(anchors, (size_t)a * 4 + 3, bf);
        r0 = ldin(rel, (size_t)i * 4 + 0, bf);
        r1 = ldin(rel, (size_t)i * 4 + 1, bf);
        r2 = ldin(rel, (size_t)i * 4 + 2, bf);
        r3 = ldin(rel, (size_t)i * 4 + 3, bf);
    }
    float wa = ax2 - ax1, ha = ay2 - ay1;
    float cxa = ax1 + 0.5f * wa, cya = ay1 + 0.5f * ha;
    float dx = r0 / 10.0f, dy = r1 / 10.0f;
    float dw = fminf(r2 / 5.0f, BBOX_CLIPF);
    float dh = fminf(r3 / 5.0f, BBOX_CLIPF);
    float cx = dx * wa + cxa, cy = dy * ha + cya;
    float w = np_expf(dw) * wa, h = np_expf(dh) * ha;
    float4 o;
    o.x = fminf(fmaxf(cx - 0.5f * w, 0.0f), 300.0f);
    o.y = fminf(fmaxf(cy - 0.5f * h, 0.0f), 300.0f);
    o.z = fminf(fmaxf(cx + 0.5f * w, 0.0f), 300.0f);
    o.w = fminf(fmaxf(cy + 0.5f * h, 0.0f), 300.0f);
    ((float4*)boxes)[i] = o;
}

// ---------------------------------------------------------------- fused top-400 + per-class NMS
// v4: histogram select (r2-proven), register bitonic (shfl for j<=32), float4
// box tile + exact double-mul IoU predicate (no divide) over all 512 threads,
// chunked register-resident suppression scan + rank-parallel emission.
// Selection set / order / key encoding identical to the proven kernel.
__global__ __launch_bounds__(NT) void k_topknms_pre(const unsigned* __restrict__ scT,
                                                    const float* __restrict__ denom,
                                                    const float* __restrict__ boxes,
                                                    unsigned long long* __restrict__ kkey,
                                                    int* __restrict__ kcnt) {
    __shared__ __align__(16) union {
        unsigned sbits[A_N];                 // 34928 B (phase 1: masked scores)
        unsigned long long msk[TOPK * 7];    // 22400 B (phase 2: NMS bitmask)
    } su;
    __shared__ __align__(16) union {
        float4 nbq[TOPK];                    // 6400 B (NMS boxes, offset coords)
        unsigned hist[1024];                 // 4096 B (radix-select histograms)
    } sb;
    __shared__ unsigned long long wlist[512];
    __shared__ unsigned long long fsup[8];   // future-chunk suppression words
    __shared__ unsigned long long ksv[8];    // per-chunk kept bit-vectors
    __shared__ int wred[NT / 64];
    __shared__ unsigned sel_b;
    __shared__ int sel_rem;
    __shared__ int eqlist[64];
    __shared__ int eqn;
    __shared__ int nsel;

    int bc = blockIdx.x;
    int b  = bc / CM1;
    int cm = bc % CM1;                       // class row 0..89 (logit col cm+1)
    int t  = threadIdx.x;

    // ---- phase 0: coalesced read of raw exp bits, divide by denom (same
    // e/denom expression as proven code), mask, stage to LDS, fused count.
    const uint4*  src = (const uint4*)(scT + (size_t)bc * A_N);
    const float4* dnm = (const float4*)(denom + (size_t)b * A_N);
    uint4* dst = (uint4*)su.sbits;
    int c0 = 0;
    for (int k = t; k < A_N / 4; k += NT) {
        uint4 ev = src[k];
        float4 dv = dnm[k];
        float s0 = __uint_as_float(ev.x) / dv.x;
        float s1 = __uint_as_float(ev.y) / dv.y;
        float s2 = __uint_as_float(ev.z) / dv.z;
        float s3 = __uint_as_float(ev.w) / dv.w;
        uint4 o;
        o.x = (s0 > 0.01f) ? __float_as_uint(s0) : 0u;
        o.y = (s1 > 0.01f) ? __float_as_uint(s1) : 0u;
        o.z = (s2 > 0.01f) ? __float_as_uint(s2) : 0u;
        o.w = (s3 > 0.01f) ? __float_as_uint(s3) : 0u;
        dst[k] = o;
        c0 += (o.x != 0u) + (o.y != 0u) + (o.z != 0u) + (o.w != 0u);
    }
    if (t == 0) { eqn = 0; nsel = 0; }
    for (int o = 32; o; o >>= 1) c0 += __shfl_down(c0, o);
    if ((t & 63) == 0) wred[t >> 6] = c0;
    __syncthreads();
    if (t == 0) {
        int tot = 0;
        for (int wv = 0; wv < NT / 64; ++wv) tot += wred[wv];
        sel_rem = tot;
    }
    __syncthreads();
    int nreal = sel_rem;
    __syncthreads();

    // ---- histogram radix select of the 400th largest (r2-proven, identical
    // sstar/teq to the bit-serial select). Scores in (0.01, 1.0]: bits 30..26
    // == 0b01111 fixed; levels refine 25..16 / 15..6 / 5..0.
    unsigned sstar = 0u;
    int teq = 0;
    if (nreal >= TOPK) {
        unsigned prefix = 0xFu;
        // Level 1: bits 25..16
        if (t == 0) sel_rem = TOPK;
        for (int q = t; q < 1024; q += NT) sb.hist[q] = 0u;
        __syncthreads();
        for (int a = t; a < A_N; a += NT) {
            unsigned v = su.sbits[a];
            if (v) atomicAdd(&sb.hist[(v >> 16) & 0x3FFu], 1u);
        }
        __syncthreads();
        if (t < 64) {
            int rem = sel_rem;
            unsigned s = 0;
            #pragma unroll
            for (int q = 0; q < 16; ++q) s += sb.hist[16 * t + q];
            unsigned suf = s;
            for (int o = 1; o < 64; o <<= 1) {
                unsigned vv = __shfl_down(suf, o);
                if (t + o < 64) suf += vv;
            }
            unsigned cum = suf - s;          // count in buckets above this lane's
            for (int q = 15; q >= 0; --q) {  // walk own 16 buckets high->low
                unsigned h = sb.hist[16 * t + q];
                if ((int)cum < rem && rem <= (int)(cum + h)) {
                    sel_b = (unsigned)(16 * t + q);
                    sel_rem = rem - (int)cum;
                }
                cum += h;
            }
        }
        __syncthreads();
        prefix = (prefix << 10) | sel_b;

        // Level 2: bits 15..6
        for (int q = t; q < 1024; q += NT) sb.hist[q] = 0u;
        __syncthreads();
        for (int a = t; a < A_N; a += NT) {
            unsigned v = su.sbits[a];
            if ((v >> 16) == prefix) atomicAdd(&sb.hist[(v >> 6) & 0x3FFu], 1u);
        }
        __syncthreads();
        if (t < 64) {
            int rem = sel_rem;
            unsigned s = 0;
            #pragma unroll
            for (int q = 0; q < 16; ++q) s += sb.hist[16 * t + q];
            unsigned suf = s;
            for (int o = 1; o < 64; o <<= 1) {
                unsigned vv = __shfl_down(suf, o);
                if (t + o < 64) suf += vv;
            }
            unsigned cum = suf - s;
            for (int q = 15; q >= 0; --q) {
                unsigned h = sb.hist[16 * t + q];
                if ((int)cum < rem && rem <= (int)(cum + h)) {
                    sel_b = (unsigned)(16 * t + q);
                    sel_rem = rem - (int)cum;
                }
                cum += h;
            }
        }
        __syncthreads();
        prefix = (prefix << 10) | sel_b;

        // Level 3: bits 5..0
        if (t < 64) sb.hist[t] = 0u;
        __syncthreads();
        for (int a = t; a < A_N; a += NT) {
            unsigned v = su.sbits[a];
            if ((v >> 6) == prefix) atomicAdd(&sb.hist[v & 0x3Fu], 1u);
        }
        __syncthreads();
        if (t == 0) {
            int rem = sel_rem;
            unsigned cum = 0;
            for (int bq = 63; bq >= 0; --bq) {
                unsigned h = sb.hist[bq];
                if ((int)cum < rem && rem <= (int)(cum + h)) {
                    sel_b = (unsigned)bq;
                    sel_rem = rem - (int)cum;
                    break;
                }
                cum += h;
            }
        }
        __syncthreads();
        sstar = (prefix << 6) | sel_b;
        teq = sel_rem;                       // ties at sstar to take
    }

    // ---- combined selection scan: strictly-greater -> wlist, ties -> eqlist.
    for (int a = t; a < A_N; a += NT) {
        unsigned v = su.sbits[a];
        if (nreal >= TOPK) {
            if (v > sstar) {
                int slot = atomicAdd(&nsel, 1);
                if (slot < 512)
                    wlist[slot] = ((unsigned long long)v << 32) | (unsigned)(~(unsigned)a);
            } else if (v == sstar) {
                int s2 = atomicAdd(&eqn, 1);
                if (s2 < 64) eqlist[s2] = a;
            }
        } else if (v != 0u) {
            int slot = atomicAdd(&nsel, 1);
            if (slot < 512)
                wlist[slot] = ((unsigned long long)v << 32) | (unsigned)(~(unsigned)a);
        }
    }
    __syncthreads();
    if (t == 0 && nreal >= TOPK) {
        int n = eqn < 64 ? eqn : 64;         // same 64-cap as proven kernel
        for (int i2 = 1; i2 < n; ++i2) {     // sort ties by anchor asc
            int v2 = eqlist[i2], j2 = i2 - 1;
            while (j2 >= 0 && eqlist[j2] > v2) { eqlist[j2 + 1] = eqlist[j2]; --j2; }
            eqlist[j2 + 1] = v2;
        }
        int tq = teq < n ? teq : n;
        int bse = nsel;
        for (int q2 = 0; q2 < tq; ++q2) {    // take tq smallest-anchor ties
            int slot = bse + q2;
            if (slot < 512)
                wlist[slot] = ((unsigned long long)sstar << 32) |
                              (unsigned)(~(unsigned)eqlist[q2]);
        }
        nsel = bse + tq;
    }
    __syncthreads();
    int ns = nsel < 512 ? nsel : 512;
    if (t >= ns) wlist[t] = 0ull;
    __syncthreads();

    // ---- bitonic sort 512 desc, register-resident; shfl_xor for j<=32,
    // LDS exchange only for j>=64 (6 stages). Same compare-exchange network
    // as the proven loop => identical permutation.
    {
        unsigned long long u = wlist[t];
        for (int k = 2; k <= 512; k <<= 1) {
            bool up = ((t & k) == 0);
            for (int j = k >> 1; j >= 64; j >>= 1) {
                __syncthreads();
                wlist[t] = u;
                __syncthreads();
                unsigned long long v = wlist[t ^ j];
                bool takeMax = (((t & j) == 0) == up);
                u = takeMax ? (u > v ? u : v) : (u < v ? u : v);
            }
            for (int j = ((k >> 1) < 64 ? (k >> 1) : 32); j > 0; j >>= 1) {
                unsigned long long v = __shfl_xor(u, j);
                bool takeMax = (((t & j) == 0) == up);
                u = takeMax ? (u > v ? u : v) : (u < v ? u : v);
            }
        }
        __syncthreads();
        wlist[t] = u;
        __syncthreads();
    }

    // ---- per-class NMS on the sorted top-400 ----
    int m = ns < TOPK ? ns : TOPK;
    float offc = (float)(cm + 1) * 301.0f;
    if (t < m) {
        unsigned aidx = ~(unsigned)(wlist[t] & 0xFFFFFFFFull);
        const float* bp = boxes + ((size_t)b * A_N + aidx) * 4;
        float4 q;
        q.x = bp[0] + offc; q.y = bp[1] + offc;   // same exprs as proven code
        q.z = bp[2] + offc; q.w = bp[3] + offc;
        sb.nbq[t] = q;
    }
    __syncthreads();   // su.sbits dead; safe to reuse union as msk

    // IoU mask build: flattened (row, word) task grid over all 512 threads.
    // Exact double-mul predicate replaces the IEEE divide (bit-equivalent).
    for (int tau = t; tau < TOPK * 7; tau += NT) {
        int i2 = tau / 7, jw = tau - 7 * i2;
        int j0 = jw * 64; if (j0 < i2 + 1) j0 = i2 + 1;
        int j1 = jw * 64 + 64; if (j1 > m) j1 = m;
        unsigned long long acc = 0ull;
        if (j0 < j1) {
            float4 bq = sb.nbq[i2];
            float a1 = (bq.z - bq.x) * (bq.w - bq.y);   // == bar[i2] bits
            for (int j = j0; j < j1; ++j) {
                float4 cq = sb.nbq[j];
                float lx = fmaxf(bq.x, cq.x), ly = fmaxf(bq.y, cq.y);
                float rx = fminf(bq.z, cq.z), ry = fminf(bq.w, cq.w);
                float ww = fmaxf(rx - lx, 0.0f), hh = fmaxf(ry - ly, 0.0f);
                float inter = ww * hh;
                float arj = (cq.z - cq.x) * (cq.w - cq.y);   // == bar[j] bits
                float U = a1 + arj - inter + 1e-9f;           // same assoc
                if ((double)inter > IOU_M * (double)U) acc |= 1ull << (j & 63);
            }
        }
        su.msk[i2 * 7 + jw] = acc;
    }
    __syncthreads();

    // ---- chunked greedy suppression scan (wave 0), register shfl chain.
    // Decisions identical to the serial scan; rows past the 200th kept are
    // decided but never emitted (matches the cnt==MAXDET break semantics).
    if (t < 64) {
        int l = t;
        if (l < 8) fsup[l] = 0ull;
        int nch = (m + 63) >> 6;
        int total = 0;
        for (int g = 0; g < nch; ++g) {
            int jmax = m - 64 * g; if (jmax > 64) jmax = 64;
            unsigned long long w =
                (l < jmax) ? su.msk[(64 * g + l) * 7 + g] : 0ull;
            unsigned long long sup = fsup[g];
            unsigned long long kv = 0ull;
            for (int j = 0; j < jmax; ++j) {
                unsigned long long wj = __shfl(w, j);
                if (!((sup >> j) & 1ull)) { sup |= wj; kv |= 1ull << j; }
            }
            if (l == 0) ksv[g] = kv;
            for (int h = g + 1; h < nch; ++h) {
                unsigned long long v =
                    ((kv >> l) & 1ull) ? su.msk[(64 * g + l) * 7 + h] : 0ull;
                for (int o = 32; o; o >>= 1) v |= __shfl_down(v, o);
                if (l == 0) fsup[h] |= v;
            }
            total += __popcll(kv);
        }
        // rank-parallel emission (kept order == row order == serial order)
        int basek = 0;
        for (int g = 0; g < nch; ++g) {
            unsigned long long kv = ksv[g];
            int row = 64 * g + l;
            if ((kv >> l) & 1ull) {
                int rank = basek + __popcll(kv & ((1ull << l) - 1ull));
                if (rank < MAXDET) {
                    unsigned long long wv = wlist[row];
                    unsigned sbts = (unsigned)(wv >> 32);
                    unsigned aa2  = ~(unsigned)wv;        // anchor, <16384
                    int flat = cm * TOPK + row;
                    unsigned long long key =
                        ((unsigned long long)sbts << 31) |
                        ((unsigned long long)(131071 - flat) << 14) |
                        (unsigned long long)aa2;
                    kkey[(size_t)bc * MAXDET + rank] = key;
                }
            }
            basek += __popcll(kv);
        }
        if (l == 0) kcnt[bc] = total < MAXDET ? total : MAXDET;
    }
}

// ---------------------------------------------------------------- FALLBACK top-400 + NMS
// Verbatim proven kernel (used only if the workspace can't hold scT).
__global__ __launch_bounds__(NT) void k_topknms(const void* __restrict__ logits,
                                                const int* __restrict__ flag,
                                                const float* __restrict__ amax,
                                                const float* __restrict__ denom,
                                                const float* __restrict__ boxes,
                                                unsigned long long* __restrict__ kkey,
                                                int* __restrict__ kcnt) {
    __shared__ union {
        unsigned sbits[A_N];
        unsigned long long msk[TOPK * 7];
    } su;
    __shared__ unsigned long long wlist[512];
    __shared__ float bx1[TOPK], by1[TOPK], bx2[TOPK], by2[TOPK], bar[TOPK];
    __shared__ int wred[NT / 64];
    __shared__ unsigned bcast_p;
    __shared__ int bcast_rem;
    __shared__ int eqlist[64];
    __shared__ int eqn;
    __shared__ int bcast_athr;
    __shared__ int nsel;

    int bc = blockIdx.x;
    int b  = bc / CM1;
    int cm = bc % CM1;
    int bf = flag[0];
    int t  = threadIdx.x;

    for (int a = t; a < A_N; a += NT) {
        size_t base = (size_t)b * A_N + a;
        float e  = np_expf(ldin(logits, base * C_N + (cm + 1), bf) - amax[base]);
        float sc = e / denom[base];
        su.sbits[a] = (sc > 0.01f) ? __float_as_uint(sc) : 0u;
    }
    if (t == 0) { eqn = 0; nsel = 0; }
    __syncthreads();

    {
        int c0 = 0;
        for (int a = t; a < A_N; a += NT) c0 += (su.sbits[a] != 0u);
        for (int o = 32; o; o >>= 1) c0 += __shfl_down(c0, o);
        if ((t & 63) == 0) wred[t >> 6] = c0;
        __syncthreads();
        if (t == 0) {
            int tot = 0;
            for (int wv = 0; wv < NT / 64; ++wv) tot += wred[wv];
            bcast_rem = tot;
        }
        __syncthreads();
    }
    int nreal = bcast_rem;
    __syncthreads();

    unsigned sstar = 0u;
    int teq = 0;
    if (nreal >= TOPK) {
        unsigned p = 0x3C000000u;
        int rem = TOPK;
        for (int bit = 25; bit >= 0; --bit) {
            unsigned q = p | (1u << bit);
            int cnt = 0;
            for (int a = t; a < A_N; a += NT) cnt += ((su.sbits[a] >> bit) == (q >> bit));
            for (int o = 32; o; o >>= 1) cnt += __shfl_down(cnt, o);
            if ((t & 63) == 0) wred[t >> 6] = cnt;
            __syncthreads();
            if (t == 0) {
                int tot = 0;
                for (int wv = 0; wv < NT / 64; ++wv) tot += wred[wv];
                if (tot >= rem) { bcast_p = q; bcast_rem = rem; }
                else            { bcast_p = p; bcast_rem = rem - tot; }
            }
            __syncthreads();
            p = bcast_p; rem = bcast_rem;
            __syncthreads();
        }
        sstar = p;
        teq = rem;
        for (int a = t; a < A_N; a += NT) {
            if (su.sbits[a] == sstar) {
                int slot = atomicAdd(&eqn, 1);
                if (slot < 64) eqlist[slot] = a;
            }
        }
        __syncthreads();
        if (t == 0) {
            int n = eqn < 64 ? eqn : 64;
            for (int i = 1; i < n; ++i) {
                int v = eqlist[i], j = i - 1;
                while (j >= 0 && eqlist[j] > v) { eqlist[j + 1] = eqlist[j]; --j; }
                eqlist[j + 1] = v;
            }
            int tq = teq < n ? teq : n;
            bcast_athr = (tq > 0) ? eqlist[tq - 1] : -1;
        }
        __syncthreads();
    }
    int athr = (nreal >= TOPK) ? bcast_athr : -1;
    __syncthreads();

    for (int a = t; a < A_N; a += NT) {
        unsigned v = su.sbits[a];
        bool sel;
        if (nreal >= TOPK)
            sel = (v > sstar) || (v == sstar && a <= athr);
        else
            sel = (v != 0u);
        if (sel) {
            int slot = atomicAdd(&nsel, 1);
            if (slot < 512)
                wlist[slot] = ((unsigned long long)v << 32) | (unsigned)(~(unsigned)a);
        }
    }
    __syncthreads();
    int ns = nsel < 512 ? nsel : 512;
    if (t < 512 && t >= ns) wlist[t] = 0ull;
    __syncthreads();

    for (int k = 2; k <= 512; k <<= 1) {
        for (int j = k >> 1; j > 0; j >>= 1) {
            int ixj = t ^ j;
            if (ixj > t) {
                unsigned long long u = wlist[t], v = wlist[ixj];
                bool desc = ((t & k) == 0);
                if (desc ? (u < v) : (u > v)) { wlist[t] = v; wlist[ixj] = u; }
            }
            __syncthreads();
        }
    }

    int m = ns < TOPK ? ns : TOPK;
    float offc = (float)(cm + 1) * 301.0f;
    if (t < m) {
        unsigned aidx = ~(unsigned)(wlist[t] & 0xFFFFFFFFull);
        const float* bp = boxes + ((size_t)b * A_N + aidx) * 4;
        float x1 = bp[0] + offc, y1 = bp[1] + offc;
        float x2 = bp[2] + offc, y2 = bp[3] + offc;
        bx1[t] = x1; by1[t] = y1; bx2[t] = x2; by2[t] = y2;
        bar[t] = (x2 - x1) * (y2 - y1);
    }
    __syncthreads();

    if (t < m) {
        unsigned long long w[7] = {0, 0, 0, 0, 0, 0, 0};
        float x1 = bx1[t], y1 = by1[t], x2 = bx2[t], y2 = by2[t], a1 = bar[t];
        for (int j = t + 1; j < m; ++j) {
            float lx = fmaxf(x1, bx1[j]), ly = fmaxf(y1, by1[j]);
            float rx = fminf(x2, bx2[j]), ry = fminf(y2, by2[j]);
            float ww = fmaxf(rx - lx, 0.0f), hh = fmaxf(ry - ly, 0.0f);
            float inter = ww * hh;
            float iou = inter / (a1 + bar[j] - inter + 1e-9f);
            if (iou > 0.45f) w[j >> 6] |= 1ull << (j & 63);
        }
        for (int k2 = 0; k2 < 7; ++k2) su.msk[t * 7 + k2] = w[k2];
    }
    __syncthreads();

    if (t == 0) {
        unsigned long long sup[7] = {0, 0, 0, 0, 0, 0, 0};
        int cnt = 0;
        for (int i = 0; i < m; ++i) {
            if (!((sup[i >> 6] >> (i & 63)) & 1ull)) {
                unsigned long long wv = wlist[i];
                unsigned sb2 = (unsigned)(wv >> 32);
                unsigned a  = ~(unsigned)wv;
                int flat = cm * TOPK + i;
                unsigned long long key =
                    ((unsigned long long)sb2 << 31) |
                    ((unsigned long long)(131071 - flat) << 14) |
                    (unsigned long long)a;
                kkey[(size_t)bc * MAXDET + cnt] = key;
                cnt++;
                if (cnt == MAXDET) break;
                const unsigned long long* r = &su.msk[i * 7];
                for (int k2 = 0; k2 < 7; ++k2) sup[k2] |= r[k2];
            }
        }
        kcnt[bc] = cnt;
    }
}

// ---------------------------------------------------------------- 90-way merge, 1 wave/image
__global__ __launch_bounds__(64) void k_merge(const unsigned long long* __restrict__ kkey,
                                              const int* __restrict__ kcnt,
                                              const float* __restrict__ boxes,
                                              float* __restrict__ out) {
    int b = blockIdx.x;
    int t = threadIdx.x;
    const float* bx = boxes + (size_t)b * A_N * 4;
    float* ob = out + (size_t)b * MAXDET * 4;
    float* os = out + (size_t)B_N * MAXDET * 4 + (size_t)b * MAXDET;
    float* ol = out + (size_t)B_N * MAXDET * 5 + (size_t)b * MAXDET;

    int cls0 = t, cls1 = t + 64;
    int n0 = (cls0 < CM1) ? kcnt[b * CM1 + cls0] : 0;
    int n1 = (cls1 < CM1) ? kcnt[b * CM1 + cls1] : 0;
    const unsigned long long* l0 = kkey + (size_t)(b * CM1 + cls0) * MAXDET;
    const unsigned long long* l1 = kkey + (size_t)(b * CM1 + cls1) * MAXDET;
    int p0 = 0, p1 = 0;
    unsigned long long h0 = (n0 > 0) ? l0[0] : 0ull;
    unsigned long long h1 = (n1 > 0) ? l1[0] : 0ull;
    unsigned long long x0 = (n0 > 1) ? l0[1] : 0ull;
    unsigned long long x1n = (n1 > 1) ? l1[1] : 0ull;

    for (int slot = 0; slot < MAXDET; ++slot) {
        unsigned long long m = h0 > h1 ? h0 : h1;
        for (int o = 32; o; o >>= 1) {
            unsigned long long v = __shfl_down(m, o);
            if (v > m) m = v;
        }
        m = __shfl(m, 0);
        if (m == 0ull) {
            if (t == 0) {
                ob[slot * 4 + 0] = 0.0f; ob[slot * 4 + 1] = 0.0f;
                ob[slot * 4 + 2] = 0.0f; ob[slot * 4 + 3] = 0.0f;
                os[slot] = 0.0f; ol[slot] = 0.0f;
            }
        } else {
            if (h0 == m) {
                int a = (int)(m & 0x3FFFull);
                const float* bp = bx + (size_t)a * 4;
                ob[slot * 4 + 0] = bp[0]; ob[slot * 4 + 1] = bp[1];
                ob[slot * 4 + 2] = bp[2]; ob[slot * 4 + 3] = bp[3];
                os[slot] = __uint_as_float((unsigned)(m >> 31));
                ol[slot] = (float)(cls0 + 1);
                p0++; h0 = x0;
                x0 = (p0 + 1 < n0) ? l0[p0 + 1] : 0ull;
            } else if (h1 == m) {
                int a = (int)(m & 0x3FFFull);
                const float* bp = bx + (size_t)a * 4;
                ob[slot * 4 + 0] = bp[0]; ob[slot * 4 + 1] = bp[1];
                ob[slot * 4 + 2] = bp[2]; ob[slot * 4 + 3] = bp[3];
                os[slot] = __uint_as_float((unsigned)(m >> 31));
                ol[slot] = (float)(cls1 + 1);
                p1++; h1 = x1n;
                x1n = (p1 + 1 < n1) ? l1[p1 + 1] : 0ull;
            }
        }
    }
}

// ---------------------------------------------------------------- host launcher
extern "C" void kernel_launch(void* const* d_in, const int* in_sizes, int n_in,
                              void* d_out, int out_size, void* d_ws, size_t ws_size,
                              hipStream_t stream) {
    const void* logits  = d_in[0];   // [32, 8732, 91] f32
    const void* rel     = d_in[1];   // [32, 8732, 4]
    const void* anchors = d_in[2];   // [8732, 4]
    float* out = (float*)d_out;      // boxes|scores|labels flat, f32

    char* ws = (char*)d_ws;
    size_t off = 0;
    auto alloc = [&](size_t bytes) -> void* {
        void* p = ws + off;
        off = (off + bytes + 255) & ~(size_t)255;
        return p;
    };
    float* boxes  = (float*)alloc((size_t)B_N * A_N * 4 * sizeof(float));
    float* amax   = (float*)alloc((size_t)B_N * A_N * sizeof(float));
    float* denom  = (float*)alloc((size_t)B_N * A_N * sizeof(float));
    int*   flag   = (int*)alloc(256);
    unsigned long long* kkey = (unsigned long long*)alloc((size_t)B_N * CM1 * MAXDET * sizeof(unsigned long long));
    int* kcnt     = (int*)alloc((size_t)B_N * CM1 * sizeof(int));

    // transposed raw-exp buffer: [B][90][A] u32 — ~96 MiB. Only used if the
    // workspace can hold it; else fall back to the proven path.
    size_t scT_bytes = (size_t)B_N * CM1 * A_N * sizeof(unsigned);
    unsigned* scT = nullptr;
    if (off + scT_bytes <= ws_size) scT = (unsigned*)alloc(scT_bytes);

    int gridBA = (B_N * A_N + 255) / 256;

    k_sniff<<<1, 256, 0, stream>>>((const unsigned*)logits, flag);
    k_stats<<<gridBA, 256, 0, stream>>>(logits, flag, amax, denom, scT);
    k_decode<<<gridBA, 256, 0, stream>>>(rel, anchors, flag, boxes);
    if (scT)
        k_topknms_pre<<<B_N * CM1, NT, 0, stream>>>(scT, denom, boxes, kkey, kcnt);
    else
        k_topknms<<<B_N * CM1, NT, 0, stream>>>(logits, flag, amax, denom, boxes, kkey, kcnt);
    k_merge<<<B_N, 64, 0, stream>>>(kkey, kcnt, boxes, out);
}

// Round 4
// 753.798 us; speedup vs baseline: 1.9040x; 1.1300x over previous
//
#include <hip/hip_runtime.h>
#include <hip/hip_bf16.h>
#include <cstdint>
#include <cstddef>
#include <math.h>

// Match numpy f32 per-op rounding: no FMA contraction, no reassociation.
// (fmaf() below is explicit and unaffected by the pragma.)
#pragma clang fp contract(off)

#define A_N 8732
#define C_N 91
#define CM1 90
#define B_N 32
#define TOPK 400
#define MAXDET 200
#define NT 512                              /* threads in k_topknms */
#define BBOX_CLIPF 4.135166556742356f       /* log(1000/16) cast to f32 */

// Exact predicate constant: for c = 0.45f (even mantissa),
// RN(x/y) > c  <=>  x > (c + 2^-26)*y  with the product exact in double
// (25-bit * 24-bit mantissa). Bit-equivalent to the IEEE f32 divide+compare.
#define IOU_M ((double)0.45f + 0x1p-26)

// 16B vector of floats with only 4B alignment guarantee (rows are 91 floats,
// so row bases are 4B- but not 16B-aligned). gfx950 global loads support
// dword-aligned dwordx4.
typedef float f4u __attribute__((ext_vector_type(4), aligned(4)));

// Dual-path input load (reference is float32; sniff is insurance).
__device__ __forceinline__ float ldin(const void* p, size_t i, int isbf16) {
    if (isbf16) return __bfloat162float(((const __hip_bfloat16*)p)[i]);
    return ((const float*)p)[i];
}

// numpy SIMD f32 exp — bit-faithful (PROVEN bit-exact in round 10, absmax 0.0).
// DO NOT alter any constant or association.
__device__ __forceinline__ float np_expf(float x) {
    float q = rintf(x * 1.442695040f);
    float r = fmaf(q, -0.693359375f, x);
    r = fmaf(q, 2.12194440e-4f, r);
    float p = 1.9875691500E-4f;
    p = fmaf(p, r, 1.3981999507E-3f);
    p = fmaf(p, r, 8.3334519073E-3f);
    p = fmaf(p, r, 4.1665795894E-2f);
    p = fmaf(p, r, 1.6666665459E-1f);
    p = fmaf(p, r, 5.0000001201E-1f);
    p = fmaf(p, r, 1.0f);
    p = fmaf(p, r, 1.0f);
    return ldexpf(p, (int)q);
}

// ---------------------------------------------------------------- dtype sniff
__global__ void k_sniff(const unsigned* __restrict__ words, int* __restrict__ flag) {
    __shared__ int cnt_s;
    if (threadIdx.x == 0) cnt_s = 0;
    __syncthreads();
    int local = 0;
    for (int i = threadIdx.x; i < 4096; i += 256) {
        unsigned w = words[i];
        unsigned e = (w >> 7) & 0xFFu;
        if (e >= 100u && e <= 140u) local++;
    }
    atomicAdd(&cnt_s, local);
    __syncthreads();
    if (threadIdx.x == 0) flag[0] = (cnt_s > 2048) ? 1 : 0;
}

// ---------------------------------------------------------------- softmax stats
// 2 passes, dwordx4 loads. Pass A: max (sequential fmaxf chain). Pass B:
// np_expf terms accumulated into the exact numpy pairwise r[8] chains, RAW exp
// bits stored transposed to scT[(b*90+c-1)*A + a]. Division by denom is folded
// into the consumer (same e/denom expression, bit-exact).
__global__ void k_stats(const void* __restrict__ logits,
                        const int* __restrict__ flag,
                        float* __restrict__ amax,
                        float* __restrict__ denom,
                        unsigned* __restrict__ scT) {
    int i = blockIdx.x * blockDim.x + threadIdx.x;
    if (i >= B_N * A_N) return;
    int bf = flag[0];
    size_t base = (size_t)i * C_N;
    int bb = i / A_N, aa = i - bb * A_N;
    unsigned* sbase = scT ? (scT + (size_t)bb * CM1 * A_N + aa) : (unsigned*)0;

    if (!bf) {
        const float* lp = (const float*)logits + base;
        float m = -INFINITY;
        #pragma unroll
        for (int k = 0; k < 22; ++k) {
            f4u v = *(const f4u*)(lp + 4 * k);
            m = fmaxf(m, v.x); m = fmaxf(m, v.y); m = fmaxf(m, v.z); m = fmaxf(m, v.w);
        }
        m = fmaxf(m, lp[88]); m = fmaxf(m, lp[89]); m = fmaxf(m, lp[90]);

        float r[8];
        #pragma unroll
        for (int k = 0; k < 11; ++k) {
            f4u v0 = *(const f4u*)(lp + 8 * k);
            f4u v1 = *(const f4u*)(lp + 8 * k + 4);
            float e0 = np_expf(v0.x - m), e1 = np_expf(v0.y - m);
            float e2 = np_expf(v0.z - m), e3 = np_expf(v0.w - m);
            float e4 = np_expf(v1.x - m), e5 = np_expf(v1.y - m);
            float e6 = np_expf(v1.z - m), e7 = np_expf(v1.w - m);
            if (k == 0) {
                r[0] = e0; r[1] = e1; r[2] = e2; r[3] = e3;
                r[4] = e4; r[5] = e5; r[6] = e6; r[7] = e7;
                if (sbase) {
                    sbase[(size_t)0 * A_N] = __float_as_uint(e1);
                    sbase[(size_t)1 * A_N] = __float_as_uint(e2);
                    sbase[(size_t)2 * A_N] = __float_as_uint(e3);
                    sbase[(size_t)3 * A_N] = __float_as_uint(e4);
                    sbase[(size_t)4 * A_N] = __float_as_uint(e5);
                    sbase[(size_t)5 * A_N] = __float_as_uint(e6);
                    sbase[(size_t)6 * A_N] = __float_as_uint(e7);
                }
            } else {
                r[0] += e0; r[1] += e1; r[2] += e2; r[3] += e3;
                r[4] += e4; r[5] += e5; r[6] += e6; r[7] += e7;
                if (sbase) {
                    size_t o = (size_t)(8 * k - 1) * A_N;
                    sbase[o]                  = __float_as_uint(e0);
                    sbase[o + (size_t)1 * A_N] = __float_as_uint(e1);
                    sbase[o + (size_t)2 * A_N] = __float_as_uint(e2);
                    sbase[o + (size_t)3 * A_N] = __float_as_uint(e3);
                    sbase[o + (size_t)4 * A_N] = __float_as_uint(e4);
                    sbase[o + (size_t)5 * A_N] = __float_as_uint(e5);
                    sbase[o + (size_t)6 * A_N] = __float_as_uint(e6);
                    sbase[o + (size_t)7 * A_N] = __float_as_uint(e7);
                }
            }
        }
        float res = ((r[0] + r[1]) + (r[2] + r[3])) + ((r[4] + r[5]) + (r[6] + r[7]));
        float e88 = np_expf(lp[88] - m); res += e88;
        float e89 = np_expf(lp[89] - m); res += e89;
        float e90 = np_expf(lp[90] - m); res += e90;
        if (sbase) {
            sbase[(size_t)87 * A_N] = __float_as_uint(e88);
            sbase[(size_t)88 * A_N] = __float_as_uint(e89);
            sbase[(size_t)89 * A_N] = __float_as_uint(e90);
        }
        amax[i]  = m;
        denom[i] = res;
    } else {
        // bf16 insurance path — scalar, same structure as proven r10 code.
        float m = -INFINITY;
        for (int c = 0; c < C_N; ++c) m = fmaxf(m, ldin(logits, base + c, bf));
        float r[8];
        for (int j = 0; j < 8; ++j) r[j] = np_expf(ldin(logits, base + j, bf) - m);
        for (int c = 8; c < 88; c += 8)
            for (int j = 0; j < 8; ++j) r[j] += np_expf(ldin(logits, base + c + j, bf) - m);
        float res = ((r[0] + r[1]) + (r[2] + r[3])) + ((r[4] + r[5]) + (r[6] + r[7]));
        res += np_expf(ldin(logits, base + 88, bf) - m);
        res += np_expf(ldin(logits, base + 89, bf) - m);
        res += np_expf(ldin(logits, base + 90, bf) - m);
        amax[i]  = m;
        denom[i] = res;
        if (sbase) {
            for (int c = 1; c < C_N; ++c)
                sbase[(size_t)(c - 1) * A_N] =
                    __float_as_uint(np_expf(ldin(logits, base + c, bf) - m));
        }
    }
}

// ---------------------------------------------------------------- box decode (PROVEN bit-exact r10)
__global__ void k_decode(const void* __restrict__ rel,
                         const void* __restrict__ anchors,
                         const int* __restrict__ flag,
                         float* __restrict__ boxes) {
    int i = blockIdx.x * blockDim.x + threadIdx.x;
    if (i >= B_N * A_N) return;
    int bf = flag[0];
    int a = i % A_N;
    float ax1, ay1, ax2, ay2, r0, r1, r2, r3;
    if (!bf) {
        float4 av = ((const float4*)anchors)[a];
        float4 rv = ((const float4*)rel)[i];
        ax1 = av.x; ay1 = av.y; ax2 = av.z; ay2 = av.w;
        r0 = rv.x; r1 = rv.y; r2 = rv.z; r3 = rv.w;
    } else {
        ax1 = ldin(anchors, (size_t)a * 4 + 0, bf);
        ay1 = ldin(anchors, (size_t)a * 4 + 1, bf);
        ax2 = ldin(anchors, (size_t)a * 4 + 2, bf);
        ay2 = ldin(anchors, (size_t)a * 4 + 3, bf);
        r0 = ldin(rel, (size_t)i * 4 + 0, bf);
        r1 = ldin(rel, (size_t)i * 4 + 1, bf);
        r2 = ldin(rel, (size_t)i * 4 + 2, bf);
        r3 = ldin(rel, (size_t)i * 4 + 3, bf);
    }
    float wa = ax2 - ax1, ha = ay2 - ay1;
    float cxa = ax1 + 0.5f * wa, cya = ay1 + 0.5f * ha;
    float dx = r0 / 10.0f, dy = r1 / 10.0f;
    float dw = fminf(r2 / 5.0f, BBOX_CLIPF);
    float dh = fminf(r3 / 5.0f, BBOX_CLIPF);
    float cx = dx * wa + cxa, cy = dy * ha + cya;
    float w = np_expf(dw) * wa, h = np_expf(dh) * ha;
    float4 o;
    o.x = fminf(fmaxf(cx - 0.5f * w, 0.0f), 300.0f);
    o.y = fminf(fmaxf(cy - 0.5f * h, 0.0f), 300.0f);
    o.z = fminf(fmaxf(cx + 0.5f * w, 0.0f), 300.0f);
    o.w = fminf(fmaxf(cy + 0.5f * h, 0.0f), 300.0f);
    ((float4*)boxes)[i] = o;
}

// ---------------------------------------------------------------- fused top-400 + per-class NMS
// v5: jw-major IoU task grid (wave-uniform j => broadcast LDS reads, no bank
// conflicts), hoisted per-row areas, ctz-driven suppression scan (iterations
// = kept rows only). Selection set / order / key encoding identical to the
// proven kernel; IoU predicate is the r3-proven exact double-mul form.
__global__ __launch_bounds__(NT) void k_topknms_pre(const unsigned* __restrict__ scT,
                                                    const float* __restrict__ denom,
                                                    const float* __restrict__ boxes,
                                                    unsigned long long* __restrict__ kkey,
                                                    int* __restrict__ kcnt) {
    __shared__ __align__(16) union {
        unsigned sbits[A_N];                 // 34928 B (phase 1: masked scores)
        struct {
            unsigned long long msk[TOPK * 7];   // 22400 B (phase 2: NMS bitmask)
            float sar[TOPK];                    // 1600 B  (per-row areas)
        } p2;                                // 24000 B total — fits in union
    } su;
    __shared__ __align__(16) union {
        float4 nbq[TOPK];                    // 6400 B (NMS boxes, offset coords)
        unsigned hist[1024];                 // 4096 B (radix-select histograms)
    } sb;
    __shared__ unsigned long long wlist[512];
    __shared__ unsigned long long fsup[8];   // future-chunk suppression words
    __shared__ unsigned long long ksv[8];    // per-chunk kept bit-vectors
    __shared__ int wred[NT / 64];
    __shared__ unsigned sel_b;
    __shared__ int sel_rem;
    __shared__ int eqlist[64];
    __shared__ int eqn;
    __shared__ int nsel;

    int bc = blockIdx.x;
    int b  = bc / CM1;
    int cm = bc % CM1;                       // class row 0..89 (logit col cm+1)
    int t  = threadIdx.x;

    // ---- phase 0: coalesced read of raw exp bits, divide by denom (same
    // e/denom expression as proven code), mask, stage to LDS, fused count.
    const uint4*  src = (const uint4*)(scT + (size_t)bc * A_N);
    const float4* dnm = (const float4*)(denom + (size_t)b * A_N);
    uint4* dst = (uint4*)su.sbits;
    int c0 = 0;
    for (int k = t; k < A_N / 4; k += NT) {
        uint4 ev = src[k];
        float4 dv = dnm[k];
        float s0 = __uint_as_float(ev.x) / dv.x;
        float s1 = __uint_as_float(ev.y) / dv.y;
        float s2 = __uint_as_float(ev.z) / dv.z;
        float s3 = __uint_as_float(ev.w) / dv.w;
        uint4 o;
        o.x = (s0 > 0.01f) ? __float_as_uint(s0) : 0u;
        o.y = (s1 > 0.01f) ? __float_as_uint(s1) : 0u;
        o.z = (s2 > 0.01f) ? __float_as_uint(s2) : 0u;
        o.w = (s3 > 0.01f) ? __float_as_uint(s3) : 0u;
        dst[k] = o;
        c0 += (o.x != 0u) + (o.y != 0u) + (o.z != 0u) + (o.w != 0u);
    }
    if (t == 0) { eqn = 0; nsel = 0; }
    for (int o = 32; o; o >>= 1) c0 += __shfl_down(c0, o);
    if ((t & 63) == 0) wred[t >> 6] = c0;
    __syncthreads();
    if (t == 0) {
        int tot = 0;
        for (int wv = 0; wv < NT / 64; ++wv) tot += wred[wv];
        sel_rem = tot;
    }
    __syncthreads();
    int nreal = sel_rem;
    __syncthreads();

    // ---- histogram radix select of the 400th largest (r2-proven, identical
    // sstar/teq to the bit-serial select). Scores in (0.01, 1.0]: bits 30..26
    // == 0b01111 fixed; levels refine 25..16 / 15..6 / 5..0.
    unsigned sstar = 0u;
    int teq = 0;
    if (nreal >= TOPK) {
        unsigned prefix = 0xFu;
        // Level 1: bits 25..16
        if (t == 0) sel_rem = TOPK;
        for (int q = t; q < 1024; q += NT) sb.hist[q] = 0u;
        __syncthreads();
        for (int a = t; a < A_N; a += NT) {
            unsigned v = su.sbits[a];
            if (v) atomicAdd(&sb.hist[(v >> 16) & 0x3FFu], 1u);
        }
        __syncthreads();
        if (t < 64) {
            int rem = sel_rem;
            unsigned s = 0;
            #pragma unroll
            for (int q = 0; q < 16; ++q) s += sb.hist[16 * t + q];
            unsigned suf = s;
            for (int o = 1; o < 64; o <<= 1) {
                unsigned vv = __shfl_down(suf, o);
                if (t + o < 64) suf += vv;
            }
            unsigned cum = suf - s;          // count in buckets above this lane's
            for (int q = 15; q >= 0; --q) {  // walk own 16 buckets high->low
                unsigned h = sb.hist[16 * t + q];
                if ((int)cum < rem && rem <= (int)(cum + h)) {
                    sel_b = (unsigned)(16 * t + q);
                    sel_rem = rem - (int)cum;
                }
                cum += h;
            }
        }
        __syncthreads();
        prefix = (prefix << 10) | sel_b;

        // Level 2: bits 15..6
        for (int q = t; q < 1024; q += NT) sb.hist[q] = 0u;
        __syncthreads();
        for (int a = t; a < A_N; a += NT) {
            unsigned v = su.sbits[a];
            if ((v >> 16) == prefix) atomicAdd(&sb.hist[(v >> 6) & 0x3FFu], 1u);
        }
        __syncthreads();
        if (t < 64) {
            int rem = sel_rem;
            unsigned s = 0;
            #pragma unroll
            for (int q = 0; q < 16; ++q) s += sb.hist[16 * t + q];
            unsigned suf = s;
            for (int o = 1; o < 64; o <<= 1) {
                unsigned vv = __shfl_down(suf, o);
                if (t + o < 64) suf += vv;
            }
            unsigned cum = suf - s;
            for (int q = 15; q >= 0; --q) {
                unsigned h = sb.hist[16 * t + q];
                if ((int)cum < rem && rem <= (int)(cum + h)) {
                    sel_b = (unsigned)(16 * t + q);
                    sel_rem = rem - (int)cum;
                }
                cum += h;
            }
        }
        __syncthreads();
        prefix = (prefix << 10) | sel_b;

        // Level 3: bits 5..0
        if (t < 64) sb.hist[t] = 0u;
        __syncthreads();
        for (int a = t; a < A_N; a += NT) {
            unsigned v = su.sbits[a];
            if ((v >> 6) == prefix) atomicAdd(&sb.hist[v & 0x3Fu], 1u);
        }
        __syncthreads();
        if (t == 0) {
            int rem = sel_rem;
            unsigned cum = 0;
            for (int bq = 63; bq >= 0; --bq) {
                unsigned h = sb.hist[bq];
                if ((int)cum < rem && rem <= (int)(cum + h)) {
                    sel_b = (unsigned)bq;
                    sel_rem = rem - (int)cum;
                    break;
                }
                cum += h;
            }
        }
        __syncthreads();
        sstar = (prefix << 6) | sel_b;
        teq = sel_rem;                       // ties at sstar to take
    }

    // ---- combined selection scan: strictly-greater -> wlist, ties -> eqlist.
    for (int a = t; a < A_N; a += NT) {
        unsigned v = su.sbits[a];
        if (nreal >= TOPK) {
            if (v > sstar) {
                int slot = atomicAdd(&nsel, 1);
                if (slot < 512)
                    wlist[slot] = ((unsigned long long)v << 32) | (unsigned)(~(unsigned)a);
            } else if (v == sstar) {
                int s2 = atomicAdd(&eqn, 1);
                if (s2 < 64) eqlist[s2] = a;
            }
        } else if (v != 0u) {
            int slot = atomicAdd(&nsel, 1);
            if (slot < 512)
                wlist[slot] = ((unsigned long long)v << 32) | (unsigned)(~(unsigned)a);
        }
    }
    __syncthreads();
    if (t == 0 && nreal >= TOPK) {
        int n = eqn < 64 ? eqn : 64;         // same 64-cap as proven kernel
        for (int i2 = 1; i2 < n; ++i2) {     // sort ties by anchor asc
            int v2 = eqlist[i2], j2 = i2 - 1;
            while (j2 >= 0 && eqlist[j2] > v2) { eqlist[j2 + 1] = eqlist[j2]; --j2; }
            eqlist[j2 + 1] = v2;
        }
        int tq = teq < n ? teq : n;
        int bse = nsel;
        for (int q2 = 0; q2 < tq; ++q2) {    // take tq smallest-anchor ties
            int slot = bse + q2;
            if (slot < 512)
                wlist[slot] = ((unsigned long long)sstar << 32) |
                              (unsigned)(~(unsigned)eqlist[q2]);
        }
        nsel = bse + tq;
    }
    __syncthreads();
    int ns = nsel < 512 ? nsel : 512;
    if (t >= ns) wlist[t] = 0ull;
    __syncthreads();

    // ---- bitonic sort 512 desc, register-resident; shfl_xor for j<=32,
    // LDS exchange only for j>=64 (6 stages). Same compare-exchange network
    // as the proven loop => identical permutation.
    {
        unsigned long long u = wlist[t];
        for (int k = 2; k <= 512; k <<= 1) {
            bool up = ((t & k) == 0);
            for (int j = k >> 1; j >= 64; j >>= 1) {
                __syncthreads();
                wlist[t] = u;
                __syncthreads();
                unsigned long long v = wlist[t ^ j];
                bool takeMax = (((t & j) == 0) == up);
                u = takeMax ? (u > v ? u : v) : (u < v ? u : v);
            }
            for (int j = ((k >> 1) < 64 ? (k >> 1) : 32); j > 0; j >>= 1) {
                unsigned long long v = __shfl_xor(u, j);
                bool takeMax = (((t & j) == 0) == up);
                u = takeMax ? (u > v ? u : v) : (u < v ? u : v);
            }
        }
        __syncthreads();
        wlist[t] = u;
        __syncthreads();
    }

    // ---- per-class NMS on the sorted top-400 ----
    int m = ns < TOPK ? ns : TOPK;
    float offc = (float)(cm + 1) * 301.0f;
    if (t < m) {
        unsigned aidx = ~(unsigned)(wlist[t] & 0xFFFFFFFFull);
        const float* bp = boxes + ((size_t)b * A_N + aidx) * 4;
        float4 q;
        q.x = bp[0] + offc; q.y = bp[1] + offc;   // same exprs as proven code
        q.z = bp[2] + offc; q.w = bp[3] + offc;
        sb.nbq[t] = q;
        su.p2.sar[t] = (q.z - q.x) * (q.w - q.y); // == bar[t] bits (sbits dead)
    }
    __syncthreads();

    // IoU mask build: jw-major task grid — lanes of a wave share the word jw
    // and walk the SAME j (broadcast LDS reads, no bank conflicts). Exact
    // double-mul predicate (r3-proven bit-equivalent to divide+compare).
    for (int tau = t; tau < 7 * TOPK; tau += NT) {
        int jw = tau / TOPK;                 // word index 0..6 (wave-uniform-ish)
        int i2 = tau - jw * TOPK;            // row 0..399 (consecutive per lane)
        int j0u = jw * 64;
        int j1 = j0u + 64; if (j1 > m) j1 = m;
        unsigned long long acc = 0ull;
        if (i2 + 1 < m && j1 > i2 + 1) {
            float4 bq = sb.nbq[i2];
            float a1 = su.p2.sar[i2];
            for (int j = j0u; j < j1; ++j) {
                float4 cq = sb.nbq[j];       // wave-uniform j => broadcast
                float lx = fmaxf(bq.x, cq.x), ly = fmaxf(bq.y, cq.y);
                float rx = fminf(bq.z, cq.z), ry = fminf(bq.w, cq.w);
                float ww = fmaxf(rx - lx, 0.0f), hh = fmaxf(ry - ly, 0.0f);
                float inter = ww * hh;
                float U = a1 + su.p2.sar[j] - inter + 1e-9f;   // same assoc
                if (j > i2 && (double)inter > IOU_M * (double)U)
                    acc |= 1ull << (j & 63);
            }
        }
        su.p2.msk[i2 * 7 + jw] = acc;
    }
    __syncthreads();

    // ---- chunked greedy suppression scan (wave 0): ctz-driven — iterations
    // = kept rows only. Keep decisions identical to the serial scan; rows past
    // the 200th kept are decided but never emitted (cnt==MAXDET semantics).
    if (t < 64) {
        int l = t;
        if (l < 8) fsup[l] = 0ull;
        int nch = (m + 63) >> 6;
        int total = 0;
        for (int g = 0; g < nch; ++g) {
            int jmax = m - 64 * g; if (jmax > 64) jmax = 64;
            unsigned long long w =
                (l < jmax) ? su.p2.msk[(64 * g + l) * 7 + g] : 0ull;
            unsigned long long sup = fsup[g];
            unsigned long long kv = 0ull;
            unsigned long long rem =
                ((jmax == 64) ? ~0ull : ((1ull << jmax) - 1ull)) & ~sup;
            while (rem) {
                int j = __builtin_ctzll(rem);      // next non-suppressed row
                unsigned long long wj = __shfl(w, j);
                kv |= 1ull << j;
                sup |= wj;
                rem &= ~(sup | (1ull << j));
            }
            if (l == 0) ksv[g] = kv;
            for (int h = g + 1; h < nch; ++h) {
                unsigned long long v =
                    ((kv >> l) & 1ull) ? su.p2.msk[(64 * g + l) * 7 + h] : 0ull;
                for (int o = 32; o; o >>= 1) v |= __shfl_down(v, o);
                if (l == 0) fsup[h] |= v;
            }
            total += __popcll(kv);
        }
        // rank-parallel emission (kept order == row order == serial order)
        int basek = 0;
        for (int g = 0; g < nch; ++g) {
            unsigned long long kv = ksv[g];
            int row = 64 * g + l;
            if ((kv >> l) & 1ull) {
                int rank = basek + __popcll(kv & ((1ull << l) - 1ull));
                if (rank < MAXDET) {
                    unsigned long long wv = wlist[row];
                    unsigned sbts = (unsigned)(wv >> 32);
                    unsigned aa2  = ~(unsigned)wv;        // anchor, <16384
                    int flat = cm * TOPK + row;
                    unsigned long long key =
                        ((unsigned long long)sbts << 31) |
                        ((unsigned long long)(131071 - flat) << 14) |
                        (unsigned long long)aa2;
                    kkey[(size_t)bc * MAXDET + rank] = key;
                }
            }
            basek += __popcll(kv);
        }
        if (l == 0) kcnt[bc] = total < MAXDET ? total : MAXDET;
    }
}

// ---------------------------------------------------------------- FALLBACK top-400 + NMS
// Verbatim proven kernel (used only if the workspace can't hold scT).
__global__ __launch_bounds__(NT) void k_topknms(const void* __restrict__ logits,
                                                const int* __restrict__ flag,
                                                const float* __restrict__ amax,
                                                const float* __restrict__ denom,
                                                const float* __restrict__ boxes,
                                                unsigned long long* __restrict__ kkey,
                                                int* __restrict__ kcnt) {
    __shared__ union {
        unsigned sbits[A_N];
        unsigned long long msk[TOPK * 7];
    } su;
    __shared__ unsigned long long wlist[512];
    __shared__ float bx1[TOPK], by1[TOPK], bx2[TOPK], by2[TOPK], bar[TOPK];
    __shared__ int wred[NT / 64];
    __shared__ unsigned bcast_p;
    __shared__ int bcast_rem;
    __shared__ int eqlist[64];
    __shared__ int eqn;
    __shared__ int bcast_athr;
    __shared__ int nsel;

    int bc = blockIdx.x;
    int b  = bc / CM1;
    int cm = bc % CM1;
    int bf = flag[0];
    int t  = threadIdx.x;

    for (int a = t; a < A_N; a += NT) {
        size_t base = (size_t)b * A_N + a;
        float e  = np_expf(ldin(logits, base * C_N + (cm + 1), bf) - amax[base]);
        float sc = e / denom[base];
        su.sbits[a] = (sc > 0.01f) ? __float_as_uint(sc) : 0u;
    }
    if (t == 0) { eqn = 0; nsel = 0; }
    __syncthreads();

    {
        int c0 = 0;
        for (int a = t; a < A_N; a += NT) c0 += (su.sbits[a] != 0u);
        for (int o = 32; o; o >>= 1) c0 += __shfl_down(c0, o);
        if ((t & 63) == 0) wred[t >> 6] = c0;
        __syncthreads();
        if (t == 0) {
            int tot = 0;
            for (int wv = 0; wv < NT / 64; ++wv) tot += wred[wv];
            bcast_rem = tot;
        }
        __syncthreads();
    }
    int nreal = bcast_rem;
    __syncthreads();

    unsigned sstar = 0u;
    int teq = 0;
    if (nreal >= TOPK) {
        unsigned p = 0x3C000000u;
        int rem = TOPK;
        for (int bit = 25; bit >= 0; --bit) {
            unsigned q = p | (1u << bit);
            int cnt = 0;
            for (int a = t; a < A_N; a += NT) cnt += ((su.sbits[a] >> bit) == (q >> bit));
            for (int o = 32; o; o >>= 1) cnt += __shfl_down(cnt, o);
            if ((t & 63) == 0) wred[t >> 6] = cnt;
            __syncthreads();
            if (t == 0) {
                int tot = 0;
                for (int wv = 0; wv < NT / 64; ++wv) tot += wred[wv];
                if (tot >= rem) { bcast_p = q; bcast_rem = rem; }
                else            { bcast_p = p; bcast_rem = rem - tot; }
            }
            __syncthreads();
            p = bcast_p; rem = bcast_rem;
            __syncthreads();
        }
        sstar = p;
        teq = rem;
        for (int a = t; a < A_N; a += NT) {
            if (su.sbits[a] == sstar) {
                int slot = atomicAdd(&eqn, 1);
                if (slot < 64) eqlist[slot] = a;
            }
        }
        __syncthreads();
        if (t == 0) {
            int n = eqn < 64 ? eqn : 64;
            for (int i = 1; i < n; ++i) {
                int v = eqlist[i], j = i - 1;
                while (j >= 0 && eqlist[j] > v) { eqlist[j + 1] = eqlist[j]; --j; }
                eqlist[j + 1] = v;
            }
            int tq = teq < n ? teq : n;
            bcast_athr = (tq > 0) ? eqlist[tq - 1] : -1;
        }
        __syncthreads();
    }
    int athr = (nreal >= TOPK) ? bcast_athr : -1;
    __syncthreads();

    for (int a = t; a < A_N; a += NT) {
        unsigned v = su.sbits[a];
        bool sel;
        if (nreal >= TOPK)
            sel = (v > sstar) || (v == sstar && a <= athr);
        else
            sel = (v != 0u);
        if (sel) {
            int slot = atomicAdd(&nsel, 1);
            if (slot < 512)
                wlist[slot] = ((unsigned long long)v << 32) | (unsigned)(~(unsigned)a);
        }
    }
    __syncthreads();
    int ns = nsel < 512 ? nsel : 512;
    if (t < 512 && t >= ns) wlist[t] = 0ull;
    __syncthreads();

    for (int k = 2; k <= 512; k <<= 1) {
        for (int j = k >> 1; j > 0; j >>= 1) {
            int ixj = t ^ j;
            if (ixj > t) {
                unsigned long long u = wlist[t], v = wlist[ixj];
                bool desc = ((t & k) == 0);
                if (desc ? (u < v) : (u > v)) { wlist[t] = v; wlist[ixj] = u; }
            }
            __syncthreads();
        }
    }

    int m = ns < TOPK ? ns : TOPK;
    float offc = (float)(cm + 1) * 301.0f;
    if (t < m) {
        unsigned aidx = ~(unsigned)(wlist[t] & 0xFFFFFFFFull);
        const float* bp = boxes + ((size_t)b * A_N + aidx) * 4;
        float x1 = bp[0] + offc, y1 = bp[1] + offc;
        float x2 = bp[2] + offc, y2 = bp[3] + offc;
        bx1[t] = x1; by1[t] = y1; bx2[t] = x2; by2[t] = y2;
        bar[t] = (x2 - x1) * (y2 - y1);
    }
    __syncthreads();

    if (t < m) {
        unsigned long long w[7] = {0, 0, 0, 0, 0, 0, 0};
        float x1 = bx1[t], y1 = by1[t], x2 = bx2[t], y2 = by2[t], a1 = bar[t];
        for (int j = t + 1; j < m; ++j) {
            float lx = fmaxf(x1, bx1[j]), ly = fmaxf(y1, by1[j]);
            float rx = fminf(x2, bx2[j]), ry = fminf(y2, by2[j]);
            float ww = fmaxf(rx - lx, 0.0f), hh = fmaxf(ry - ly, 0.0f);
            float inter = ww * hh;
            float iou = inter / (a1 + bar[j] - inter + 1e-9f);
            if (iou > 0.45f) w[j >> 6] |= 1ull << (j & 63);
        }
        for (int k2 = 0; k2 < 7; ++k2) su.msk[t * 7 + k2] = w[k2];
    }
    __syncthreads();

    if (t == 0) {
        unsigned long long sup[7] = {0, 0, 0, 0, 0, 0, 0};
        int cnt = 0;
        for (int i = 0; i < m; ++i) {
            if (!((sup[i >> 6] >> (i & 63)) & 1ull)) {
                unsigned long long wv = wlist[i];
                unsigned sb2 = (unsigned)(wv >> 32);
                unsigned a  = ~(unsigned)wv;
                int flat = cm * TOPK + i;
                unsigned long long key =
                    ((unsigned long long)sb2 << 31) |
                    ((unsigned long long)(131071 - flat) << 14) |
                    (unsigned long long)a;
                kkey[(size_t)bc * MAXDET + cnt] = key;
                cnt++;
                if (cnt == MAXDET) break;
                const unsigned long long* r = &su.msk[i * 7];
                for (int k2 = 0; k2 < 7; ++k2) sup[k2] |= r[k2];
            }
        }
        kcnt[bc] = cnt;
    }
}

// ---------------------------------------------------------------- 90-way merge, 1 wave/image
__global__ __launch_bounds__(64) void k_merge(const unsigned long long* __restrict__ kkey,
                                              const int* __restrict__ kcnt,
                                              const float* __restrict__ boxes,
                                              float* __restrict__ out) {
    int b = blockIdx.x;
    int t = threadIdx.x;
    const float* bx = boxes + (size_t)b * A_N * 4;
    float* ob = out + (size_t)b * MAXDET * 4;
    float* os = out + (size_t)B_N * MAXDET * 4 + (size_t)b * MAXDET;
    float* ol = out + (size_t)B_N * MAXDET * 5 + (size_t)b * MAXDET;

    int cls0 = t, cls1 = t + 64;
    int n0 = (cls0 < CM1) ? kcnt[b * CM1 + cls0] : 0;
    int n1 = (cls1 < CM1) ? kcnt[b * CM1 + cls1] : 0;
    const unsigned long long* l0 = kkey + (size_t)(b * CM1 + cls0) * MAXDET;
    const unsigned long long* l1 = kkey + (size_t)(b * CM1 + cls1) * MAXDET;
    int p0 = 0, p1 = 0;
    unsigned long long h0 = (n0 > 0) ? l0[0] : 0ull;
    unsigned long long h1 = (n1 > 0) ? l1[0] : 0ull;
    unsigned long long x0 = (n0 > 1) ? l0[1] : 0ull;
    unsigned long long x1n = (n1 > 1) ? l1[1] : 0ull;

    for (int slot = 0; slot < MAXDET; ++slot) {
        unsigned long long m = h0 > h1 ? h0 : h1;
        for (int o = 32; o; o >>= 1) {
            unsigned long long v = __shfl_down(m, o);
            if (v > m) m = v;
        }
        m = __shfl(m, 0);
        if (m == 0ull) {
            if (t == 0) {
                ob[slot * 4 + 0] = 0.0f; ob[slot * 4 + 1] = 0.0f;
                ob[slot * 4 + 2] = 0.0f; ob[slot * 4 + 3] = 0.0f;
                os[slot] = 0.0f; ol[slot] = 0.0f;
            }
        } else {
            if (h0 == m) {
                int a = (int)(m & 0x3FFFull);
                const float* bp = bx + (size_t)a * 4;
                ob[slot * 4 + 0] = bp[0]; ob[slot * 4 + 1] = bp[1];
                ob[slot * 4 + 2] = bp[2]; ob[slot * 4 + 3] = bp[3];
                os[slot] = __uint_as_float((unsigned)(m >> 31));
                ol[slot] = (float)(cls0 + 1);
                p0++; h0 = x0;
                x0 = (p0 + 1 < n0) ? l0[p0 + 1] : 0ull;
            } else if (h1 == m) {
                int a = (int)(m & 0x3FFFull);
                const float* bp = bx + (size_t)a * 4;
                ob[slot * 4 + 0] = bp[0]; ob[slot * 4 + 1] = bp[1];
                ob[slot * 4 + 2] = bp[2]; ob[slot * 4 + 3] = bp[3];
                os[slot] = __uint_as_float((unsigned)(m >> 31));
                ol[slot] = (float)(cls1 + 1);
                p1++; h1 = x1n;
                x1n = (p1 + 1 < n1) ? l1[p1 + 1] : 0ull;
            }
        }
    }
}

// ---------------------------------------------------------------- host launcher
extern "C" void kernel_launch(void* const* d_in, const int* in_sizes, int n_in,
                              void* d_out, int out_size, void* d_ws, size_t ws_size,
                              hipStream_t stream) {
    const void* logits  = d_in[0];   // [32, 8732, 91] f32
    const void* rel     = d_in[1];   // [32, 8732, 4]
    const void* anchors = d_in[2];   // [8732, 4]
    float* out = (float*)d_out;      // boxes|scores|labels flat, f32

    char* ws = (char*)d_ws;
    size_t off = 0;
    auto alloc = [&](size_t bytes) -> void* {
        void* p = ws + off;
        off = (off + bytes + 255) & ~(size_t)255;
        return p;
    };
    float* boxes  = (float*)alloc((size_t)B_N * A_N * 4 * sizeof(float));
    float* amax   = (float*)alloc((size_t)B_N * A_N * sizeof(float));
    float* denom  = (float*)alloc((size_t)B_N * A_N * sizeof(float));
    int*   flag   = (int*)alloc(256);
    unsigned long long* kkey = (unsigned long long*)alloc((size_t)B_N * CM1 * MAXDET * sizeof(unsigned long long));
    int* kcnt     = (int*)alloc((size_t)B_N * CM1 * sizeof(int));

    // transposed raw-exp buffer: [B][90][A] u32 — ~96 MiB. Only used if the
    // workspace can hold it; else fall back to the proven path.
    size_t scT_bytes = (size_t)B_N * CM1 * A_N * sizeof(unsigned);
    unsigned* scT = nullptr;
    if (off + scT_bytes <= ws_size) scT = (unsigned*)alloc(scT_bytes);

    int gridBA = (B_N * A_N + 255) / 256;

    k_sniff<<<1, 256, 0, stream>>>((const unsigned*)logits, flag);
    k_stats<<<gridBA, 256, 0, stream>>>(logits, flag, amax, denom, scT);
    k_decode<<<gridBA, 256, 0, stream>>>(rel, anchors, flag, boxes);
    if (scT)
        k_topknms_pre<<<B_N * CM1, NT, 0, stream>>>(scT, denom, boxes, kkey, kcnt);
    else
        k_topknms<<<B_N * CM1, NT, 0, stream>>>(logits, flag, amax, denom, boxes, kkey, kcnt);
    k_merge<<<B_N, 64, 0, stream>>>(kkey, kcnt, boxes, out);
}

// Round 5
// 704.584 us; speedup vs baseline: 2.0370x; 1.0698x over previous
//
#include <hip/hip_runtime.h>
#include <hip/hip_bf16.h>
#include <cstdint>
#include <cstddef>
#include <math.h>

// Match numpy f32 per-op rounding: no FMA contraction, no reassociation.
// (fmaf() below is explicit and unaffected by the pragma.)
#pragma clang fp contract(off)

#define A_N 8732
#define C_N 91
#define CM1 90
#define B_N 32
#define TOPK 400
#define MAXDET 200
#define NT 512                              /* threads in k_topknms */
#define BBOX_CLIPF 4.135166556742356f       /* log(1000/16) cast to f32 */

// Exact predicate constant: for c = 0.45f (even mantissa),
// RN(x/y) > c  <=>  x > (c + 2^-26)*y  with the product exact in double
// (25-bit * 24-bit mantissa). Bit-equivalent to the IEEE f32 divide+compare.
#define IOU_M ((double)0.45f + 0x1p-26)

// 16B vector of floats with only 4B alignment guarantee (rows are 91 floats,
// so row bases are 4B- but not 16B-aligned).
typedef float f4u __attribute__((ext_vector_type(4), aligned(4)));

// Dual-path input load (reference is float32; sniff is insurance).
__device__ __forceinline__ float ldin(const void* p, size_t i, int isbf16) {
    if (isbf16) return __bfloat162float(((const __hip_bfloat16*)p)[i]);
    return ((const float*)p)[i];
}

// numpy SIMD f32 exp — bit-faithful (PROVEN bit-exact, absmax 0.0).
// DO NOT alter any constant or association.
__device__ __forceinline__ float np_expf(float x) {
    float q = rintf(x * 1.442695040f);
    float r = fmaf(q, -0.693359375f, x);
    r = fmaf(q, 2.12194440e-4f, r);
    float p = 1.9875691500E-4f;
    p = fmaf(p, r, 1.3981999507E-3f);
    p = fmaf(p, r, 8.3334519073E-3f);
    p = fmaf(p, r, 4.1665795894E-2f);
    p = fmaf(p, r, 1.6666665459E-1f);
    p = fmaf(p, r, 5.0000001201E-1f);
    p = fmaf(p, r, 1.0f);
    p = fmaf(p, r, 1.0f);
    return ldexpf(p, (int)q);
}

// ---------------------------------------------------------------- dtype sniff
__global__ void k_sniff(const unsigned* __restrict__ words, int* __restrict__ flag) {
    __shared__ int cnt_s;
    if (threadIdx.x == 0) cnt_s = 0;
    __syncthreads();
    int local = 0;
    for (int i = threadIdx.x; i < 4096; i += 256) {
        unsigned w = words[i];
        unsigned e = (w >> 7) & 0xFFu;
        if (e >= 100u && e <= 140u) local++;
    }
    atomicAdd(&cnt_s, local);
    __syncthreads();
    if (threadIdx.x == 0) flag[0] = (cnt_s > 2048) ? 1 : 0;
}

// ---------------------------------------------------------------- softmax stats
// 2 passes, dwordx4 loads. Pass A: max (sequential fmaxf chain). Pass B:
// np_expf terms accumulated into the exact numpy pairwise r[8] chains, RAW exp
// bits stored transposed to scT[(b*90+c-1)*A + a]. Division by denom is folded
// into the consumer (same e/denom expression, bit-exact).
__global__ void k_stats(const void* __restrict__ logits,
                        const int* __restrict__ flag,
                        float* __restrict__ amax,
                        float* __restrict__ denom,
                        unsigned* __restrict__ scT) {
    int i = blockIdx.x * blockDim.x + threadIdx.x;
    if (i >= B_N * A_N) return;
    int bf = flag[0];
    size_t base = (size_t)i * C_N;
    int bb = i / A_N, aa = i - bb * A_N;
    unsigned* sbase = scT ? (scT + (size_t)bb * CM1 * A_N + aa) : (unsigned*)0;

    if (!bf) {
        const float* lp = (const float*)logits + base;
        float m = -INFINITY;
        #pragma unroll
        for (int k = 0; k < 22; ++k) {
            f4u v = *(const f4u*)(lp + 4 * k);
            m = fmaxf(m, v.x); m = fmaxf(m, v.y); m = fmaxf(m, v.z); m = fmaxf(m, v.w);
        }
        m = fmaxf(m, lp[88]); m = fmaxf(m, lp[89]); m = fmaxf(m, lp[90]);

        float r[8];
        #pragma unroll
        for (int k = 0; k < 11; ++k) {
            f4u v0 = *(const f4u*)(lp + 8 * k);
            f4u v1 = *(const f4u*)(lp + 8 * k + 4);
            float e0 = np_expf(v0.x - m), e1 = np_expf(v0.y - m);
            float e2 = np_expf(v0.z - m), e3 = np_expf(v0.w - m);
            float e4 = np_expf(v1.x - m), e5 = np_expf(v1.y - m);
            float e6 = np_expf(v1.z - m), e7 = np_expf(v1.w - m);
            if (k == 0) {
                r[0] = e0; r[1] = e1; r[2] = e2; r[3] = e3;
                r[4] = e4; r[5] = e5; r[6] = e6; r[7] = e7;
                if (sbase) {
                    sbase[(size_t)0 * A_N] = __float_as_uint(e1);
                    sbase[(size_t)1 * A_N] = __float_as_uint(e2);
                    sbase[(size_t)2 * A_N] = __float_as_uint(e3);
                    sbase[(size_t)3 * A_N] = __float_as_uint(e4);
                    sbase[(size_t)4 * A_N] = __float_as_uint(e5);
                    sbase[(size_t)5 * A_N] = __float_as_uint(e6);
                    sbase[(size_t)6 * A_N] = __float_as_uint(e7);
                }
            } else {
                r[0] += e0; r[1] += e1; r[2] += e2; r[3] += e3;
                r[4] += e4; r[5] += e5; r[6] += e6; r[7] += e7;
                if (sbase) {
                    size_t o = (size_t)(8 * k - 1) * A_N;
                    sbase[o]                  = __float_as_uint(e0);
                    sbase[o + (size_t)1 * A_N] = __float_as_uint(e1);
                    sbase[o + (size_t)2 * A_N] = __float_as_uint(e2);
                    sbase[o + (size_t)3 * A_N] = __float_as_uint(e3);
                    sbase[o + (size_t)4 * A_N] = __float_as_uint(e4);
                    sbase[o + (size_t)5 * A_N] = __float_as_uint(e5);
                    sbase[o + (size_t)6 * A_N] = __float_as_uint(e6);
                    sbase[o + (size_t)7 * A_N] = __float_as_uint(e7);
                }
            }
        }
        float res = ((r[0] + r[1]) + (r[2] + r[3])) + ((r[4] + r[5]) + (r[6] + r[7]));
        float e88 = np_expf(lp[88] - m); res += e88;
        float e89 = np_expf(lp[89] - m); res += e89;
        float e90 = np_expf(lp[90] - m); res += e90;
        if (sbase) {
            sbase[(size_t)87 * A_N] = __float_as_uint(e88);
            sbase[(size_t)88 * A_N] = __float_as_uint(e89);
            sbase[(size_t)89 * A_N] = __float_as_uint(e90);
        }
        amax[i]  = m;
        denom[i] = res;
    } else {
        // bf16 insurance path — scalar, same structure as proven code.
        float m = -INFINITY;
        for (int c = 0; c < C_N; ++c) m = fmaxf(m, ldin(logits, base + c, bf));
        float r[8];
        for (int j = 0; j < 8; ++j) r[j] = np_expf(ldin(logits, base + j, bf) - m);
        for (int c = 8; c < 88; c += 8)
            for (int j = 0; j < 8; ++j) r[j] += np_expf(ldin(logits, base + c + j, bf) - m);
        float res = ((r[0] + r[1]) + (r[2] + r[3])) + ((r[4] + r[5]) + (r[6] + r[7]));
        res += np_expf(ldin(logits, base + 88, bf) - m);
        res += np_expf(ldin(logits, base + 89, bf) - m);
        res += np_expf(ldin(logits, base + 90, bf) - m);
        amax[i]  = m;
        denom[i] = res;
        if (sbase) {
            for (int c = 1; c < C_N; ++c)
                sbase[(size_t)(c - 1) * A_N] =
                    __float_as_uint(np_expf(ldin(logits, base + c, bf) - m));
        }
    }
}

// ---------------------------------------------------------------- box decode (PROVEN bit-exact)
__global__ void k_decode(const void* __restrict__ rel,
                         const void* __restrict__ anchors,
                         const int* __restrict__ flag,
                         float* __restrict__ boxes) {
    int i = blockIdx.x * blockDim.x + threadIdx.x;
    if (i >= B_N * A_N) return;
    int bf = flag[0];
    int a = i % A_N;
    float ax1, ay1, ax2, ay2, r0, r1, r2, r3;
    if (!bf) {
        float4 av = ((const float4*)anchors)[a];
        float4 rv = ((const float4*)rel)[i];
        ax1 = av.x; ay1 = av.y; ax2 = av.z; ay2 = av.w;
        r0 = rv.x; r1 = rv.y; r2 = rv.z; r3 = rv.w;
    } else {
        ax1 = ldin(anchors, (size_t)a * 4 + 0, bf);
        ay1 = ldin(anchors, (size_t)a * 4 + 1, bf);
        ax2 = ldin(anchors, (size_t)a * 4 + 2, bf);
        ay2 = ldin(anchors, (size_t)a * 4 + 3, bf);
        r0 = ldin(rel, (size_t)i * 4 + 0, bf);
        r1 = ldin(rel, (size_t)i * 4 + 1, bf);
        r2 = ldin(rel, (size_t)i * 4 + 2, bf);
        r3 = ldin(rel, (size_t)i * 4 + 3, bf);
    }
    float wa = ax2 - ax1, ha = ay2 - ay1;
    float cxa = ax1 + 0.5f * wa, cya = ay1 + 0.5f * ha;
    float dx = r0 / 10.0f, dy = r1 / 10.0f;
    float dw = fminf(r2 / 5.0f, BBOX_CLIPF);
    float dh = fminf(r3 / 5.0f, BBOX_CLIPF);
    float cx = dx * wa + cxa, cy = dy * ha + cya;
    float w = np_expf(dw) * wa, h = np_expf(dh) * ha;
    float4 o;
    o.x = fminf(fmaxf(cx - 0.5f * w, 0.0f), 300.0f);
    o.y = fminf(fmaxf(cy - 0.5f * h, 0.0f), 300.0f);
    o.z = fminf(fmaxf(cx + 0.5f * w, 0.0f), 300.0f);
    o.w = fminf(fmaxf(cy + 0.5f * h, 0.0f), 300.0f);
    ((float4*)boxes)[i] = o;
}

// ---------------------------------------------------------------- fused top-400 + per-class NMS
// v6: masked score bits live in GLOBAL (scT row, overwritten in place) instead
// of a 35KB LDS stage -> LDS 46.6->~35KB -> 4 blocks/CU (full 32-wave occ).
// Histogram level 1 + nreal count fused into phase 0 (one fewer full pass).
// All selection / order / key semantics identical to the proven kernel.
__global__ __launch_bounds__(NT) void k_topknms_pre(unsigned* __restrict__ scT,
                                                    const float* __restrict__ denom,
                                                    const float* __restrict__ boxes,
                                                    unsigned long long* __restrict__ kkey,
                                                    int* __restrict__ kcnt) {
    __shared__ __align__(16) union {
        struct {
            unsigned long long msk[TOPK * 7];   // 22400 B (NMS bitmask)
            float sar[TOPK];                    // 1600 B  (per-row areas)
        } p2;                                // 24000 B
        unsigned hist[1024];                 // 4096 B (radix-select histograms)
    } su;
    __shared__ __align__(16) float4 nbq[TOPK];  // 6400 B (NMS boxes, offset)
    __shared__ unsigned long long wlist[512];   // 4096 B
    __shared__ unsigned long long fsup[8];
    __shared__ unsigned long long ksv[8];
    __shared__ unsigned sel_b;
    __shared__ int sel_rem;
    __shared__ int nreal_s;
    __shared__ int eqlist[64];
    __shared__ int eqn;
    __shared__ int nsel;

    int bc = blockIdx.x;
    int b  = bc / CM1;
    int cm = bc % CM1;                       // class row 0..89 (logit col cm+1)
    int t  = threadIdx.x;

    unsigned* srow = scT + (size_t)bc * A_N;
    uint4* srow4 = (uint4*)srow;
    const float4* dnm = (const float4*)(denom + (size_t)b * A_N);

    // ---- phase 0: read raw exp bits, divide by denom (same e/denom
    // expression as proven code), mask, write masked bits back IN PLACE,
    // and build the level-1 histogram (bits 25..16) in the same pass.
    if (t == 0) { eqn = 0; nsel = 0; }
    for (int q = t; q < 1024; q += NT) su.hist[q] = 0u;
    __syncthreads();
    for (int k = t; k < A_N / 4; k += NT) {
        uint4 ev = srow4[k];
        float4 dv = dnm[k];
        float s0 = __uint_as_float(ev.x) / dv.x;
        float s1 = __uint_as_float(ev.y) / dv.y;
        float s2 = __uint_as_float(ev.z) / dv.z;
        float s3 = __uint_as_float(ev.w) / dv.w;
        uint4 o;
        o.x = (s0 > 0.01f) ? __float_as_uint(s0) : 0u;
        o.y = (s1 > 0.01f) ? __float_as_uint(s1) : 0u;
        o.z = (s2 > 0.01f) ? __float_as_uint(s2) : 0u;
        o.w = (s3 > 0.01f) ? __float_as_uint(s3) : 0u;
        srow4[k] = o;
        if (o.x) atomicAdd(&su.hist[(o.x >> 16) & 0x3FFu], 1u);
        if (o.y) atomicAdd(&su.hist[(o.y >> 16) & 0x3FFu], 1u);
        if (o.z) atomicAdd(&su.hist[(o.z >> 16) & 0x3FFu], 1u);
        if (o.w) atomicAdd(&su.hist[(o.w >> 16) & 0x3FFu], 1u);
    }
    __syncthreads();

    // ---- level-1 scan: suffix sums give BOTH nreal (total) and the
    // 400th-largest bucket (valid iff nreal >= TOPK).
    if (t < 64) {
        unsigned s = 0;
        #pragma unroll
        for (int q = 0; q < 16; ++q) s += su.hist[16 * t + q];
        unsigned suf = s;
        for (int o = 1; o < 64; o <<= 1) {
            unsigned vv = __shfl_down(suf, o);
            if (t + o < 64) suf += vv;
        }
        if (t == 0) nreal_s = (int)suf;      // total nonzero
        unsigned cum = suf - s;              // count in buckets above lane's
        for (int q = 15; q >= 0; --q) {
            unsigned h = su.hist[16 * t + q];
            if ((int)cum < TOPK && TOPK <= (int)(cum + h)) {
                sel_b = (unsigned)(16 * t + q);
                sel_rem = TOPK - (int)cum;
            }
            cum += h;
        }
    }
    __syncthreads();
    int nreal = nreal_s;

    unsigned sstar = 0u;
    int teq = 0;
    if (nreal >= TOPK) {                     // block-uniform branch
        unsigned prefix = (0xFu << 10) | sel_b;

        // Level 2: bits 15..6
        for (int q = t; q < 1024; q += NT) su.hist[q] = 0u;
        __syncthreads();
        for (int a = t; a < A_N; a += NT) {
            unsigned v = srow[a];
            if ((v >> 16) == prefix) atomicAdd(&su.hist[(v >> 6) & 0x3FFu], 1u);
        }
        __syncthreads();
        if (t < 64) {
            int rem = sel_rem;
            unsigned s = 0;
            #pragma unroll
            for (int q = 0; q < 16; ++q) s += su.hist[16 * t + q];
            unsigned suf = s;
            for (int o = 1; o < 64; o <<= 1) {
                unsigned vv = __shfl_down(suf, o);
                if (t + o < 64) suf += vv;
            }
            unsigned cum = suf - s;
            for (int q = 15; q >= 0; --q) {
                unsigned h = su.hist[16 * t + q];
                if ((int)cum < rem && rem <= (int)(cum + h)) {
                    sel_b = (unsigned)(16 * t + q);
                    sel_rem = rem - (int)cum;
                }
                cum += h;
            }
        }
        __syncthreads();
        prefix = (prefix << 10) | sel_b;

        // Level 3: bits 5..0
        if (t < 64) su.hist[t] = 0u;
        __syncthreads();
        for (int a = t; a < A_N; a += NT) {
            unsigned v = srow[a];
            if ((v >> 6) == prefix) atomicAdd(&su.hist[v & 0x3Fu], 1u);
        }
        __syncthreads();
        if (t == 0) {
            int rem = sel_rem;
            unsigned cum = 0;
            for (int bq = 63; bq >= 0; --bq) {
                unsigned h = su.hist[bq];
                if ((int)cum < rem && rem <= (int)(cum + h)) {
                    sel_b = (unsigned)bq;
                    sel_rem = rem - (int)cum;
                    break;
                }
                cum += h;
            }
        }
        __syncthreads();
        sstar = (prefix << 6) | sel_b;
        teq = sel_rem;                       // ties at sstar to take
    }

    // ---- combined selection scan: strictly-greater -> wlist, ties -> eqlist.
    for (int a = t; a < A_N; a += NT) {
        unsigned v = srow[a];
        if (nreal >= TOPK) {
            if (v > sstar) {
                int slot = atomicAdd(&nsel, 1);
                if (slot < 512)
                    wlist[slot] = ((unsigned long long)v << 32) | (unsigned)(~(unsigned)a);
            } else if (v == sstar) {
                int s2 = atomicAdd(&eqn, 1);
                if (s2 < 64) eqlist[s2] = a;
            }
        } else if (v != 0u) {
            int slot = atomicAdd(&nsel, 1);
            if (slot < 512)
                wlist[slot] = ((unsigned long long)v << 32) | (unsigned)(~(unsigned)a);
        }
    }
    __syncthreads();
    if (t == 0 && nreal >= TOPK) {
        int n = eqn < 64 ? eqn : 64;         // same 64-cap as proven kernel
        for (int i2 = 1; i2 < n; ++i2) {     // sort ties by anchor asc
            int v2 = eqlist[i2], j2 = i2 - 1;
            while (j2 >= 0 && eqlist[j2] > v2) { eqlist[j2 + 1] = eqlist[j2]; --j2; }
            eqlist[j2 + 1] = v2;
        }
        int tq = teq < n ? teq : n;
        int bse = nsel;
        for (int q2 = 0; q2 < tq; ++q2) {    // take tq smallest-anchor ties
            int slot = bse + q2;
            if (slot < 512)
                wlist[slot] = ((unsigned long long)sstar << 32) |
                              (unsigned)(~(unsigned)eqlist[q2]);
        }
        nsel = bse + tq;
    }
    __syncthreads();
    int ns = nsel < 512 ? nsel : 512;
    if (t >= ns) wlist[t] = 0ull;
    __syncthreads();

    // ---- bitonic sort 512 desc, register-resident; shfl_xor for j<=32,
    // LDS exchange only for j>=64. Same compare-exchange network as the
    // proven loop => identical permutation.
    {
        unsigned long long u = wlist[t];
        for (int k = 2; k <= 512; k <<= 1) {
            bool up = ((t & k) == 0);
            for (int j = k >> 1; j >= 64; j >>= 1) {
                __syncthreads();
                wlist[t] = u;
                __syncthreads();
                unsigned long long v = wlist[t ^ j];
                bool takeMax = (((t & j) == 0) == up);
                u = takeMax ? (u > v ? u : v) : (u < v ? u : v);
            }
            for (int j = ((k >> 1) < 64 ? (k >> 1) : 32); j > 0; j >>= 1) {
                unsigned long long v = __shfl_xor(u, j);
                bool takeMax = (((t & j) == 0) == up);
                u = takeMax ? (u > v ? u : v) : (u < v ? u : v);
            }
        }
        __syncthreads();
        wlist[t] = u;
        __syncthreads();
    }

    // ---- per-class NMS on the sorted top-400 ----
    int m = ns < TOPK ? ns : TOPK;
    float offc = (float)(cm + 1) * 301.0f;
    if (t < m) {
        unsigned aidx = ~(unsigned)(wlist[t] & 0xFFFFFFFFull);
        const float* bp = boxes + ((size_t)b * A_N + aidx) * 4;
        float4 q;
        q.x = bp[0] + offc; q.y = bp[1] + offc;   // same exprs as proven code
        q.z = bp[2] + offc; q.w = bp[3] + offc;
        nbq[t] = q;
        su.p2.sar[t] = (q.z - q.x) * (q.w - q.y); // == bar[t] bits (hist dead)
    }
    __syncthreads();

    // IoU mask build: jw-major task grid — lanes of a wave share the word jw
    // and walk the SAME j (broadcast LDS reads, no bank conflicts). Exact
    // double-mul predicate (proven bit-equivalent to divide+compare).
    for (int tau = t; tau < 7 * TOPK; tau += NT) {
        int jw = tau / TOPK;                 // word index 0..6
        int i2 = tau - jw * TOPK;            // row 0..399
        int j0u = jw * 64;
        int j1 = j0u + 64; if (j1 > m) j1 = m;
        unsigned long long acc = 0ull;
        if (i2 + 1 < m && j1 > i2 + 1) {
            float4 bq = nbq[i2];
            float a1 = su.p2.sar[i2];
            for (int j = j0u; j < j1; ++j) {
                float4 cq = nbq[j];          // wave-uniform j => broadcast
                float lx = fmaxf(bq.x, cq.x), ly = fmaxf(bq.y, cq.y);
                float rx = fminf(bq.z, cq.z), ry = fminf(bq.w, cq.w);
                float ww = fmaxf(rx - lx, 0.0f), hh = fmaxf(ry - ly, 0.0f);
                float inter = ww * hh;
                float U = a1 + su.p2.sar[j] - inter + 1e-9f;   // same assoc
                if (j > i2 && (double)inter > IOU_M * (double)U)
                    acc |= 1ull << (j & 63);
            }
        }
        su.p2.msk[i2 * 7 + jw] = acc;
    }
    __syncthreads();

    // ---- chunked greedy suppression scan (wave 0): ctz-driven — iterations
    // = kept rows only. Keep decisions identical to the serial scan; rows past
    // the 200th kept are decided but never emitted (cnt==MAXDET semantics).
    if (t < 64) {
        int l = t;
        if (l < 8) fsup[l] = 0ull;
        int nch = (m + 63) >> 6;
        int total = 0;
        for (int g = 0; g < nch; ++g) {
            int jmax = m - 64 * g; if (jmax > 64) jmax = 64;
            unsigned long long w =
                (l < jmax) ? su.p2.msk[(64 * g + l) * 7 + g] : 0ull;
            unsigned long long sup = fsup[g];
            unsigned long long kv = 0ull;
            unsigned long long rem =
                ((jmax == 64) ? ~0ull : ((1ull << jmax) - 1ull)) & ~sup;
            while (rem) {
                int j = __builtin_ctzll(rem);      // next non-suppressed row
                unsigned long long wj = __shfl(w, j);
                kv |= 1ull << j;
                sup |= wj;
                rem &= ~(sup | (1ull << j));
            }
            if (l == 0) ksv[g] = kv;
            for (int h = g + 1; h < nch; ++h) {
                unsigned long long v =
                    ((kv >> l) & 1ull) ? su.p2.msk[(64 * g + l) * 7 + h] : 0ull;
                for (int o = 32; o; o >>= 1) v |= __shfl_down(v, o);
                if (l == 0) fsup[h] |= v;
            }
            total += __popcll(kv);
        }
        // rank-parallel emission (kept order == row order == serial order)
        int basek = 0;
        for (int g = 0; g < nch; ++g) {
            unsigned long long kv = ksv[g];
            int row = 64 * g + l;
            if ((kv >> l) & 1ull) {
                int rank = basek + __popcll(kv & ((1ull << l) - 1ull));
                if (rank < MAXDET) {
                    unsigned long long wv = wlist[row];
                    unsigned sbts = (unsigned)(wv >> 32);
                    unsigned aa2  = ~(unsigned)wv;        // anchor, <16384
                    int flat = cm * TOPK + row;
                    unsigned long long key =
                        ((unsigned long long)sbts << 31) |
                        ((unsigned long long)(131071 - flat) << 14) |
                        (unsigned long long)aa2;
                    kkey[(size_t)bc * MAXDET + rank] = key;
                }
            }
            basek += __popcll(kv);
        }
        if (l == 0) kcnt[bc] = total < MAXDET ? total : MAXDET;
    }
}

// ---------------------------------------------------------------- FALLBACK top-400 + NMS
// Verbatim proven kernel (used only if the workspace can't hold scT).
__global__ __launch_bounds__(NT) void k_topknms(const void* __restrict__ logits,
                                                const int* __restrict__ flag,
                                                const float* __restrict__ amax,
                                                const float* __restrict__ denom,
                                                const float* __restrict__ boxes,
                                                unsigned long long* __restrict__ kkey,
                                                int* __restrict__ kcnt) {
    __shared__ union {
        unsigned sbits[A_N];
        unsigned long long msk[TOPK * 7];
    } su;
    __shared__ unsigned long long wlist[512];
    __shared__ float bx1[TOPK], by1[TOPK], bx2[TOPK], by2[TOPK], bar[TOPK];
    __shared__ int wred[NT / 64];
    __shared__ unsigned bcast_p;
    __shared__ int bcast_rem;
    __shared__ int eqlist[64];
    __shared__ int eqn;
    __shared__ int bcast_athr;
    __shared__ int nsel;

    int bc = blockIdx.x;
    int b  = bc / CM1;
    int cm = bc % CM1;
    int bf = flag[0];
    int t  = threadIdx.x;

    for (int a = t; a < A_N; a += NT) {
        size_t base = (size_t)b * A_N + a;
        float e  = np_expf(ldin(logits, base * C_N + (cm + 1), bf) - amax[base]);
        float sc = e / denom[base];
        su.sbits[a] = (sc > 0.01f) ? __float_as_uint(sc) : 0u;
    }
    if (t == 0) { eqn = 0; nsel = 0; }
    __syncthreads();

    {
        int c0 = 0;
        for (int a = t; a < A_N; a += NT) c0 += (su.sbits[a] != 0u);
        for (int o = 32; o; o >>= 1) c0 += __shfl_down(c0, o);
        if ((t & 63) == 0) wred[t >> 6] = c0;
        __syncthreads();
        if (t == 0) {
            int tot = 0;
            for (int wv = 0; wv < NT / 64; ++wv) tot += wred[wv];
            bcast_rem = tot;
        }
        __syncthreads();
    }
    int nreal = bcast_rem;
    __syncthreads();

    unsigned sstar = 0u;
    int teq = 0;
    if (nreal >= TOPK) {
        unsigned p = 0x3C000000u;
        int rem = TOPK;
        for (int bit = 25; bit >= 0; --bit) {
            unsigned q = p | (1u << bit);
            int cnt = 0;
            for (int a = t; a < A_N; a += NT) cnt += ((su.sbits[a] >> bit) == (q >> bit));
            for (int o = 32; o; o >>= 1) cnt += __shfl_down(cnt, o);
            if ((t & 63) == 0) wred[t >> 6] = cnt;
            __syncthreads();
            if (t == 0) {
                int tot = 0;
                for (int wv = 0; wv < NT / 64; ++wv) tot += wred[wv];
                if (tot >= rem) { bcast_p = q; bcast_rem = rem; }
                else            { bcast_p = p; bcast_rem = rem - tot; }
            }
            __syncthreads();
            p = bcast_p; rem = bcast_rem;
            __syncthreads();
        }
        sstar = p;
        teq = rem;
        for (int a = t; a < A_N; a += NT) {
            if (su.sbits[a] == sstar) {
                int slot = atomicAdd(&eqn, 1);
                if (slot < 64) eqlist[slot] = a;
            }
        }
        __syncthreads();
        if (t == 0) {
            int n = eqn < 64 ? eqn : 64;
            for (int i = 1; i < n; ++i) {
                int v = eqlist[i], j = i - 1;
                while (j >= 0 && eqlist[j] > v) { eqlist[j + 1] = eqlist[j]; --j; }
                eqlist[j + 1] = v;
            }
            int tq = teq < n ? teq : n;
            bcast_athr = (tq > 0) ? eqlist[tq - 1] : -1;
        }
        __syncthreads();
    }
    int athr = (nreal >= TOPK) ? bcast_athr : -1;
    __syncthreads();

    for (int a = t; a < A_N; a += NT) {
        unsigned v = su.sbits[a];
        bool sel;
        if (nreal >= TOPK)
            sel = (v > sstar) || (v == sstar && a <= athr);
        else
            sel = (v != 0u);
        if (sel) {
            int slot = atomicAdd(&nsel, 1);
            if (slot < 512)
                wlist[slot] = ((unsigned long long)v << 32) | (unsigned)(~(unsigned)a);
        }
    }
    __syncthreads();
    int ns = nsel < 512 ? nsel : 512;
    if (t < 512 && t >= ns) wlist[t] = 0ull;
    __syncthreads();

    for (int k = 2; k <= 512; k <<= 1) {
        for (int j = k >> 1; j > 0; j >>= 1) {
            int ixj = t ^ j;
            if (ixj > t) {
                unsigned long long u = wlist[t], v = wlist[ixj];
                bool desc = ((t & k) == 0);
                if (desc ? (u < v) : (u > v)) { wlist[t] = v; wlist[ixj] = u; }
            }
            __syncthreads();
        }
    }

    int m = ns < TOPK ? ns : TOPK;
    float offc = (float)(cm + 1) * 301.0f;
    if (t < m) {
        unsigned aidx = ~(unsigned)(wlist[t] & 0xFFFFFFFFull);
        const float* bp = boxes + ((size_t)b * A_N + aidx) * 4;
        float x1 = bp[0] + offc, y1 = bp[1] + offc;
        float x2 = bp[2] + offc, y2 = bp[3] + offc;
        bx1[t] = x1; by1[t] = y1; bx2[t] = x2; by2[t] = y2;
        bar[t] = (x2 - x1) * (y2 - y1);
    }
    __syncthreads();

    if (t < m) {
        unsigned long long w[7] = {0, 0, 0, 0, 0, 0, 0};
        float x1 = bx1[t], y1 = by1[t], x2 = bx2[t], y2 = by2[t], a1 = bar[t];
        for (int j = t + 1; j < m; ++j) {
            float lx = fmaxf(x1, bx1[j]), ly = fmaxf(y1, by1[j]);
            float rx = fminf(x2, bx2[j]), ry = fminf(y2, by2[j]);
            float ww = fmaxf(rx - lx, 0.0f), hh = fmaxf(ry - ly, 0.0f);
            float inter = ww * hh;
            float iou = inter / (a1 + bar[j] - inter + 1e-9f);
            if (iou > 0.45f) w[j >> 6] |= 1ull << (j & 63);
        }
        for (int k2 = 0; k2 < 7; ++k2) su.msk[t * 7 + k2] = w[k2];
    }
    __syncthreads();

    if (t == 0) {
        unsigned long long sup[7] = {0, 0, 0, 0, 0, 0, 0};
        int cnt = 0;
        for (int i = 0; i < m; ++i) {
            if (!((sup[i >> 6] >> (i & 63)) & 1ull)) {
                unsigned long long wv = wlist[i];
                unsigned sb2 = (unsigned)(wv >> 32);
                unsigned a  = ~(unsigned)wv;
                int flat = cm * TOPK + i;
                unsigned long long key =
                    ((unsigned long long)sb2 << 31) |
                    ((unsigned long long)(131071 - flat) << 14) |
                    (unsigned long long)a;
                kkey[(size_t)bc * MAXDET + cnt] = key;
                cnt++;
                if (cnt == MAXDET) break;
                const unsigned long long* r = &su.msk[i * 7];
                for (int k2 = 0; k2 < 7; ++k2) sup[k2] |= r[k2];
            }
        }
        kcnt[bc] = cnt;
    }
}

// ---------------------------------------------------------------- parallel per-image top-200
// v2: replaces the serial 200-step 90-way merge. Keys are globally unique and
// each class list is sorted desc, so the merged output == the top-200 keys of
// the union in descending order. Generic 64-bit radix select of the 200th
// largest (7 levels, 10+10+10+10+10+10+2 bits), gather (count(>=T) == 200
// exactly, by uniqueness), bitonic sort 256 desc, emit. Bit-identical output.
__global__ __launch_bounds__(256) void k_merge(const unsigned long long* __restrict__ kkey,
                                               const int* __restrict__ kcnt,
                                               const float* __restrict__ boxes,
                                               float* __restrict__ out) {
    __shared__ unsigned hist[1024];
    __shared__ unsigned long long wl[256];
    __shared__ int kc[CM1];
    __shared__ int tot_s;
    __shared__ unsigned selb_s;
    __shared__ int selrem_s;
    __shared__ int gcnt;

    int b = blockIdx.x;
    int t = threadIdx.x;
    const unsigned long long* keys = kkey + (size_t)b * (CM1 * MAXDET);
    const float* bx = boxes + (size_t)b * A_N * 4;
    float* ob = out + (size_t)b * MAXDET * 4;
    float* os = out + (size_t)B_N * MAXDET * 4 + (size_t)b * MAXDET;
    float* ol = out + (size_t)B_N * MAXDET * 5 + (size_t)b * MAXDET;

    if (t < CM1) kc[t] = kcnt[b * CM1 + t];
    if (t == 0) { tot_s = 0; gcnt = 0; }
    __syncthreads();

    // total kept
    {
        int c0 = 0;
        for (int idx = t; idx < CM1 * MAXDET; idx += 256) {
            int c = idx / MAXDET;
            if (idx - c * MAXDET < kc[c]) c0++;
        }
        for (int o = 32; o; o >>= 1) c0 += __shfl_down(c0, o);
        if ((t & 63) == 0) atomicAdd(&tot_s, c0);
    }
    __syncthreads();
    int total = tot_s;

    unsigned long long T = 0ull;             // threshold key (take keys >= T)
    if (total > MAXDET) {
        unsigned long long prefix = 0ull;
        if (t == 0) selrem_s = MAXDET;
        __syncthreads();
        const int sh[7] = {52, 42, 32, 22, 12, 2, 0};
        const int wd[7] = {10, 10, 10, 10, 10, 10, 2};
        for (int l = 0; l < 7; ++l) {
            int shift = sh[l], width = wd[l];
            int nb = 1 << width;
            for (int q = t; q < nb; q += 256) hist[q] = 0u;
            __syncthreads();
            for (int idx = t; idx < CM1 * MAXDET; idx += 256) {
                int c = idx / MAXDET;
                if (idx - c * MAXDET < kc[c]) {
                    unsigned long long key = keys[idx];
                    if ((key >> (shift + width)) == prefix)
                        atomicAdd(&hist[(unsigned)(key >> shift) & (unsigned)(nb - 1)], 1u);
                }
            }
            __syncthreads();
            if (nb >= 64) {
                if (t < 64) {
                    int rem = selrem_s;
                    int per = nb / 64;
                    unsigned s = 0;
                    for (int q = 0; q < per; ++q) s += hist[per * t + q];
                    unsigned suf = s;
                    for (int o = 1; o < 64; o <<= 1) {
                        unsigned vv = __shfl_down(suf, o);
                        if (t + o < 64) suf += vv;
                    }
                    unsigned cum = suf - s;
                    for (int q = per - 1; q >= 0; --q) {
                        unsigned h = hist[per * t + q];
                        if ((int)cum < rem && rem <= (int)(cum + h)) {
                            selb_s = (unsigned)(per * t + q);
                            selrem_s = rem - (int)cum;
                        }
                        cum += h;
                    }
                }
            } else if (t == 0) {
                int rem = selrem_s;
                unsigned cum = 0;
                for (int bq = nb - 1; bq >= 0; --bq) {
                    unsigned h = hist[bq];
                    if ((int)cum < rem && rem <= (int)(cum + h)) {
                        selb_s = (unsigned)bq;
                        selrem_s = rem - (int)cum;
                        break;
                    }
                    cum += h;
                }
            }
            __syncthreads();
            prefix = (prefix << width) | (unsigned long long)selb_s;
            __syncthreads();
        }
        T = prefix;                          // exact 200th-largest key
    }

    wl[t] = 0ull;
    __syncthreads();
    for (int idx = t; idx < CM1 * MAXDET; idx += 256) {
        int c = idx / MAXDET;
        if (idx - c * MAXDET < kc[c]) {
            unsigned long long key = keys[idx];
            if (key >= T) {
                int s = atomicAdd(&gcnt, 1);
                if (s < 256) wl[s] = key;
            }
        }
    }
    __syncthreads();

    // bitonic sort 256 desc in LDS
    for (int k = 2; k <= 256; k <<= 1) {
        for (int j = k >> 1; j > 0; j >>= 1) {
            int ixj = t ^ j;
            if (ixj > t) {
                unsigned long long u = wl[t], v = wl[ixj];
                bool desc = ((t & k) == 0);
                if (desc ? (u < v) : (u > v)) { wl[t] = v; wl[ixj] = u; }
            }
            __syncthreads();
        }
    }

    if (t < MAXDET) {
        unsigned long long key = wl[t];
        if (key == 0ull) {
            ob[t * 4 + 0] = 0.0f; ob[t * 4 + 1] = 0.0f;
            ob[t * 4 + 2] = 0.0f; ob[t * 4 + 3] = 0.0f;
            os[t] = 0.0f; ol[t] = 0.0f;
        } else {
            int a = (int)(key & 0x3FFFull);
            int flat = 131071 - (int)((key >> 14) & 0x1FFFFull);
            int cmv = flat / TOPK;
            const float* bp = bx + (size_t)a * 4;
            ob[t * 4 + 0] = bp[0]; ob[t * 4 + 1] = bp[1];
            ob[t * 4 + 2] = bp[2]; ob[t * 4 + 3] = bp[3];
            os[t] = __uint_as_float((unsigned)(key >> 31));
            ol[t] = (float)(cmv + 1);
        }
    }
}

// ---------------------------------------------------------------- host launcher
extern "C" void kernel_launch(void* const* d_in, const int* in_sizes, int n_in,
                              void* d_out, int out_size, void* d_ws, size_t ws_size,
                              hipStream_t stream) {
    const void* logits  = d_in[0];   // [32, 8732, 91] f32
    const void* rel     = d_in[1];   // [32, 8732, 4]
    const void* anchors = d_in[2];   // [8732, 4]
    float* out = (float*)d_out;      // boxes|scores|labels flat, f32

    char* ws = (char*)d_ws;
    size_t off = 0;
    auto alloc = [&](size_t bytes) -> void* {
        void* p = ws + off;
        off = (off + bytes + 255) & ~(size_t)255;
        return p;
    };
    float* boxes  = (float*)alloc((size_t)B_N * A_N * 4 * sizeof(float));
    float* amax   = (float*)alloc((size_t)B_N * A_N * sizeof(float));
    float* denom  = (float*)alloc((size_t)B_N * A_N * sizeof(float));
    int*   flag   = (int*)alloc(256);
    unsigned long long* kkey = (unsigned long long*)alloc((size_t)B_N * CM1 * MAXDET * sizeof(unsigned long long));
    int* kcnt     = (int*)alloc((size_t)B_N * CM1 * sizeof(int));

    // transposed raw-exp buffer: [B][90][A] u32 — ~96 MiB. Only used if the
    // workspace can hold it; else fall back to the proven path. Overwritten
    // in place with masked score bits by k_topknms_pre (safe: k_stats
    // rewrites it every launch before the consumer reads it).
    size_t scT_bytes = (size_t)B_N * CM1 * A_N * sizeof(unsigned);
    unsigned* scT = nullptr;
    if (off + scT_bytes <= ws_size) scT = (unsigned*)alloc(scT_bytes);

    int gridBA = (B_N * A_N + 255) / 256;

    k_sniff<<<1, 256, 0, stream>>>((const unsigned*)logits, flag);
    k_stats<<<gridBA, 256, 0, stream>>>(logits, flag, amax, denom, scT);
    k_decode<<<gridBA, 256, 0, stream>>>(rel, anchors, flag, boxes);
    if (scT)
        k_topknms_pre<<<B_N * CM1, NT, 0, stream>>>(scT, denom, boxes, kkey, kcnt);
    else
        k_topknms<<<B_N * CM1, NT, 0, stream>>>(logits, flag, amax, denom, boxes, kkey, kcnt);
    k_merge<<<B_N, 256, 0, stream>>>(kkey, kcnt, boxes, out);
}

// Round 6
// 652.627 us; speedup vs baseline: 2.1991x; 1.0796x over previous
//
#include <hip/hip_runtime.h>
#include <hip/hip_bf16.h>
#include <cstdint>
#include <cstddef>
#include <math.h>

// Match numpy f32 per-op rounding: no FMA contraction, no reassociation.
// (fmaf() below is explicit and unaffected by the pragma.)
#pragma clang fp contract(off)

#define A_N 8732
#define C_N 91
#define CM1 90
#define B_N 32
#define TOPK 400
#define MAXDET 200
#define NT 512                              /* threads in k_topknms */
#define CCAP 1024                           /* candidate-list capacity */
#define BBOX_CLIPF 4.135166556742356f       /* log(1000/16) cast to f32 */

// Exact predicate constant: for c = 0.45f (even mantissa),
// RN(x/y) > c  <=>  x > (c + 2^-26)*y  with the product exact in double
// (25-bit * 24-bit mantissa). Bit-equivalent to the IEEE f32 divide+compare.
#define IOU_M ((double)0.45f + 0x1p-26)

// 16B vector of floats with only 4B alignment guarantee (rows are 91 floats,
// so row bases are 4B- but not 16B-aligned).
typedef float f4u __attribute__((ext_vector_type(4), aligned(4)));

// Dual-path input load (reference is float32; sniff is insurance).
__device__ __forceinline__ float ldin(const void* p, size_t i, int isbf16) {
    if (isbf16) return __bfloat162float(((const __hip_bfloat16*)p)[i]);
    return ((const float*)p)[i];
}

// numpy SIMD f32 exp — bit-faithful (PROVEN bit-exact, absmax 0.0).
// DO NOT alter any constant or association.
__device__ __forceinline__ float np_expf(float x) {
    float q = rintf(x * 1.442695040f);
    float r = fmaf(q, -0.693359375f, x);
    r = fmaf(q, 2.12194440e-4f, r);
    float p = 1.9875691500E-4f;
    p = fmaf(p, r, 1.3981999507E-3f);
    p = fmaf(p, r, 8.3334519073E-3f);
    p = fmaf(p, r, 4.1665795894E-2f);
    p = fmaf(p, r, 1.6666665459E-1f);
    p = fmaf(p, r, 5.0000001201E-1f);
    p = fmaf(p, r, 1.0f);
    p = fmaf(p, r, 1.0f);
    return ldexpf(p, (int)q);
}

// ---------------------------------------------------------------- dtype sniff
__global__ void k_sniff(const unsigned* __restrict__ words, int* __restrict__ flag) {
    __shared__ int cnt_s;
    if (threadIdx.x == 0) cnt_s = 0;
    __syncthreads();
    int local = 0;
    for (int i = threadIdx.x; i < 4096; i += 256) {
        unsigned w = words[i];
        unsigned e = (w >> 7) & 0xFFu;
        if (e >= 100u && e <= 140u) local++;
    }
    atomicAdd(&cnt_s, local);
    __syncthreads();
    if (threadIdx.x == 0) flag[0] = (cnt_s > 2048) ? 1 : 0;
}

// ---------------------------------------------------------------- softmax stats + box decode (fused)
// Stats: 2 passes, dwordx4 loads; np_expf terms accumulated into the exact
// numpy pairwise r[8] chains, RAW exp bits stored transposed to
// scT[(b*90+c-1)*A + a]. Decode: PROVEN bit-exact expressions, same thread
// mapping (i over B*A) — fused to save a dispatch.
__global__ void k_stats(const void* __restrict__ logits,
                        const void* __restrict__ rel,
                        const void* __restrict__ anchors,
                        const int* __restrict__ flag,
                        float* __restrict__ amax,
                        float* __restrict__ denom,
                        float* __restrict__ boxes,
                        unsigned* __restrict__ scT) {
    int i = blockIdx.x * blockDim.x + threadIdx.x;
    if (i >= B_N * A_N) return;
    int bf = flag[0];
    size_t base = (size_t)i * C_N;
    int bb = i / A_N, aa = i - bb * A_N;
    unsigned* sbase = scT ? (scT + (size_t)bb * CM1 * A_N + aa) : (unsigned*)0;

    if (!bf) {
        const float* lp = (const float*)logits + base;
        float m = -INFINITY;
        #pragma unroll
        for (int k = 0; k < 22; ++k) {
            f4u v = *(const f4u*)(lp + 4 * k);
            m = fmaxf(m, v.x); m = fmaxf(m, v.y); m = fmaxf(m, v.z); m = fmaxf(m, v.w);
        }
        m = fmaxf(m, lp[88]); m = fmaxf(m, lp[89]); m = fmaxf(m, lp[90]);

        float r[8];
        #pragma unroll
        for (int k = 0; k < 11; ++k) {
            f4u v0 = *(const f4u*)(lp + 8 * k);
            f4u v1 = *(const f4u*)(lp + 8 * k + 4);
            float e0 = np_expf(v0.x - m), e1 = np_expf(v0.y - m);
            float e2 = np_expf(v0.z - m), e3 = np_expf(v0.w - m);
            float e4 = np_expf(v1.x - m), e5 = np_expf(v1.y - m);
            float e6 = np_expf(v1.z - m), e7 = np_expf(v1.w - m);
            if (k == 0) {
                r[0] = e0; r[1] = e1; r[2] = e2; r[3] = e3;
                r[4] = e4; r[5] = e5; r[6] = e6; r[7] = e7;
                if (sbase) {
                    sbase[(size_t)0 * A_N] = __float_as_uint(e1);
                    sbase[(size_t)1 * A_N] = __float_as_uint(e2);
                    sbase[(size_t)2 * A_N] = __float_as_uint(e3);
                    sbase[(size_t)3 * A_N] = __float_as_uint(e4);
                    sbase[(size_t)4 * A_N] = __float_as_uint(e5);
                    sbase[(size_t)5 * A_N] = __float_as_uint(e6);
                    sbase[(size_t)6 * A_N] = __float_as_uint(e7);
                }
            } else {
                r[0] += e0; r[1] += e1; r[2] += e2; r[3] += e3;
                r[4] += e4; r[5] += e5; r[6] += e6; r[7] += e7;
                if (sbase) {
                    size_t o = (size_t)(8 * k - 1) * A_N;
                    sbase[o]                  = __float_as_uint(e0);
                    sbase[o + (size_t)1 * A_N] = __float_as_uint(e1);
                    sbase[o + (size_t)2 * A_N] = __float_as_uint(e2);
                    sbase[o + (size_t)3 * A_N] = __float_as_uint(e3);
                    sbase[o + (size_t)4 * A_N] = __float_as_uint(e4);
                    sbase[o + (size_t)5 * A_N] = __float_as_uint(e5);
                    sbase[o + (size_t)6 * A_N] = __float_as_uint(e6);
                    sbase[o + (size_t)7 * A_N] = __float_as_uint(e7);
                }
            }
        }
        float res = ((r[0] + r[1]) + (r[2] + r[3])) + ((r[4] + r[5]) + (r[6] + r[7]));
        float e88 = np_expf(lp[88] - m); res += e88;
        float e89 = np_expf(lp[89] - m); res += e89;
        float e90 = np_expf(lp[90] - m); res += e90;
        if (sbase) {
            sbase[(size_t)87 * A_N] = __float_as_uint(e88);
            sbase[(size_t)88 * A_N] = __float_as_uint(e89);
            sbase[(size_t)89 * A_N] = __float_as_uint(e90);
        }
        amax[i]  = m;
        denom[i] = res;
    } else {
        float m = -INFINITY;
        for (int c = 0; c < C_N; ++c) m = fmaxf(m, ldin(logits, base + c, bf));
        float r[8];
        for (int j = 0; j < 8; ++j) r[j] = np_expf(ldin(logits, base + j, bf) - m);
        for (int c = 8; c < 88; c += 8)
            for (int j = 0; j < 8; ++j) r[j] += np_expf(ldin(logits, base + c + j, bf) - m);
        float res = ((r[0] + r[1]) + (r[2] + r[3])) + ((r[4] + r[5]) + (r[6] + r[7]));
        res += np_expf(ldin(logits, base + 88, bf) - m);
        res += np_expf(ldin(logits, base + 89, bf) - m);
        res += np_expf(ldin(logits, base + 90, bf) - m);
        amax[i]  = m;
        denom[i] = res;
        if (sbase) {
            for (int c = 1; c < C_N; ++c)
                sbase[(size_t)(c - 1) * A_N] =
                    __float_as_uint(np_expf(ldin(logits, base + c, bf) - m));
        }
    }

    // ---- fused box decode (PROVEN bit-exact expressions) ----
    {
        int a = aa;
        float ax1, ay1, ax2, ay2, r0, r1, r2, r3;
        if (!bf) {
            float4 av = ((const float4*)anchors)[a];
            float4 rv = ((const float4*)rel)[i];
            ax1 = av.x; ay1 = av.y; ax2 = av.z; ay2 = av.w;
            r0 = rv.x; r1 = rv.y; r2 = rv.z; r3 = rv.w;
        } else {
            ax1 = ldin(anchors, (size_t)a * 4 + 0, bf);
            ay1 = ldin(anchors, (size_t)a * 4 + 1, bf);
            ax2 = ldin(anchors, (size_t)a * 4 + 2, bf);
            ay2 = ldin(anchors, (size_t)a * 4 + 3, bf);
            r0 = ldin(rel, (size_t)i * 4 + 0, bf);
            r1 = ldin(rel, (size_t)i * 4 + 1, bf);
            r2 = ldin(rel, (size_t)i * 4 + 2, bf);
            r3 = ldin(rel, (size_t)i * 4 + 3, bf);
        }
        float wa = ax2 - ax1, ha = ay2 - ay1;
        float cxa = ax1 + 0.5f * wa, cya = ay1 + 0.5f * ha;
        float dx = r0 / 10.0f, dy = r1 / 10.0f;
        float dw = fminf(r2 / 5.0f, BBOX_CLIPF);
        float dh = fminf(r3 / 5.0f, BBOX_CLIPF);
        float cx = dx * wa + cxa, cy = dy * ha + cya;
        float w = np_expf(dw) * wa, h = np_expf(dh) * ha;
        float4 o;
        o.x = fminf(fmaxf(cx - 0.5f * w, 0.0f), 300.0f);
        o.y = fminf(fmaxf(cy - 0.5f * h, 0.0f), 300.0f);
        o.z = fminf(fmaxf(cx + 0.5f * w, 0.0f), 300.0f);
        o.w = fminf(fmaxf(cy + 0.5f * h, 0.0f), 300.0f);
        ((float4*)boxes)[i] = o;
    }
}

// ---------------------------------------------------------------- fused top-400 + per-class NMS
// v7: NO scT writeback (2 read passes, candidate-list select in LDS with
// proven global-pass fallback), on-demand ballot NMS (no 22KB mask array,
// early stop at 200 kept). Selection set / order / key encoding identical
// to the proven kernel; IoU predicate is the proven exact double-mul form.
__global__ __launch_bounds__(NT) void k_topknms_pre(const unsigned* __restrict__ scT,
                                                    const float* __restrict__ denom,
                                                    const float* __restrict__ boxes,
                                                    unsigned long long* __restrict__ kkey,
                                                    int* __restrict__ kcnt) {
    __shared__ __align__(16) float4 nbq[TOPK];      // 6400 B
    __shared__ float sar[TOPK];                     // 1600 B
    __shared__ unsigned long long wlist[512];       // 4096 B
    __shared__ unsigned long long cand[CCAP];       // 8192 B
    __shared__ unsigned hist[1024];                 // 4096 B
    __shared__ unsigned long long fsup[8];
    __shared__ unsigned long long ksv[8];
    __shared__ unsigned sel_b;
    __shared__ int sel_rem;
    __shared__ int nreal_s;
    __shared__ int eqlist[64];
    __shared__ int eqn, nsel, candn, total_s;

    int bc = blockIdx.x;
    int b  = bc / CM1;
    int cm = bc % CM1;                       // class row 0..89 (logit col cm+1)
    int t  = threadIdx.x;

    const unsigned* srow = scT + (size_t)bc * A_N;
    const uint4* srow4 = (const uint4*)srow;
    const float4* dnm = (const float4*)(denom + (size_t)b * A_N);
    const float* dsc = denom + (size_t)b * A_N;

    // ---- phase 0: read raw exp, divide (same e/denom expression), mask,
    // build level-1 histogram (bits 25..16). No writes to global.
    if (t == 0) { eqn = 0; nsel = 0; candn = 0; total_s = 0; }
    for (int q = t; q < 1024; q += NT) hist[q] = 0u;
    __syncthreads();
    for (int k = t; k < A_N / 4; k += NT) {
        uint4 ev = srow4[k];
        float4 dv = dnm[k];
        float s0 = __uint_as_float(ev.x) / dv.x;
        float s1 = __uint_as_float(ev.y) / dv.y;
        float s2 = __uint_as_float(ev.z) / dv.z;
        float s3 = __uint_as_float(ev.w) / dv.w;
        unsigned v0 = (s0 > 0.01f) ? __float_as_uint(s0) : 0u;
        unsigned v1 = (s1 > 0.01f) ? __float_as_uint(s1) : 0u;
        unsigned v2 = (s2 > 0.01f) ? __float_as_uint(s2) : 0u;
        unsigned v3 = (s3 > 0.01f) ? __float_as_uint(s3) : 0u;
        if (v0) atomicAdd(&hist[(v0 >> 16) & 0x3FFu], 1u);
        if (v1) atomicAdd(&hist[(v1 >> 16) & 0x3FFu], 1u);
        if (v2) atomicAdd(&hist[(v2 >> 16) & 0x3FFu], 1u);
        if (v3) atomicAdd(&hist[(v3 >> 16) & 0x3FFu], 1u);
    }
    __syncthreads();

    // ---- level-1 scan: suffix sums give BOTH nreal and the 400th bucket.
    if (t < 64) {
        unsigned s = 0;
        #pragma unroll
        for (int q = 0; q < 16; ++q) s += hist[16 * t + q];
        unsigned suf = s;
        for (int o = 1; o < 64; o <<= 1) {
            unsigned vv = __shfl_down(suf, o);
            if (t + o < 64) suf += vv;
        }
        if (t == 0) nreal_s = (int)suf;
        unsigned cum = suf - s;
        for (int q = 15; q >= 0; --q) {
            unsigned h = hist[16 * t + q];
            if ((int)cum < TOPK && TOPK <= (int)(cum + h)) {
                sel_b = (unsigned)(16 * t + q);
                sel_rem = TOPK - (int)cum;
            }
            cum += h;
        }
    }
    __syncthreads();
    int nreal = nreal_s;
    bool sel_path = (nreal >= TOPK);         // block-uniform
    unsigned selL1 = sel_b;                  // valid iff sel_path
    unsigned prefix1 = (0xFu << 10) | selL1;
    __syncthreads();

    // ---- pass B: recompute v (bit-identical), classify.
    //   sel_path: bucket>selL1 -> wlist (<400 such); bucket==selL1 -> cand
    //             list + level-2 histogram (bits 15..6) in the same pass.
    //   else:     all nonzero -> wlist (nreal<400).
    if (sel_path) { for (int q = t; q < 1024; q += NT) hist[q] = 0u; }
    __syncthreads();
    for (int k = t; k < A_N / 4; k += NT) {
        uint4 ev = srow4[k];
        float4 dv = dnm[k];
        float ss[4];
        ss[0] = __uint_as_float(ev.x) / dv.x;
        ss[1] = __uint_as_float(ev.y) / dv.y;
        ss[2] = __uint_as_float(ev.z) / dv.z;
        ss[3] = __uint_as_float(ev.w) / dv.w;
        #pragma unroll
        for (int c = 0; c < 4; ++c) {
            unsigned v = (ss[c] > 0.01f) ? __float_as_uint(ss[c]) : 0u;
            if (!v) continue;
            unsigned a = (unsigned)(4 * k + c);
            if (sel_path) {
                unsigned bkt = (v >> 16) & 0x3FFu;
                if (bkt > selL1) {
                    int slot = atomicAdd(&nsel, 1);
                    if (slot < 512)
                        wlist[slot] = ((unsigned long long)v << 32) | (unsigned)(~a);
                } else if (bkt == selL1) {
                    int s2 = atomicAdd(&candn, 1);
                    if (s2 < CCAP)
                        cand[s2] = ((unsigned long long)v << 32) | (unsigned)(~a);
                    atomicAdd(&hist[(v >> 6) & 0x3FFu], 1u);
                }
            } else {
                int slot = atomicAdd(&nsel, 1);
                if (slot < 512)
                    wlist[slot] = ((unsigned long long)v << 32) | (unsigned)(~a);
            }
        }
    }
    __syncthreads();

    unsigned sstar = 0u;
    int teq = 0;
    if (sel_path) {
        bool ovf = (candn > CCAP);           // block-uniform
        // ---- level-2 scan (hist2 built in pass B — complete even on ovf).
        if (t < 64) {
            int rem = sel_rem;
            unsigned s = 0;
            #pragma unroll
            for (int q = 0; q < 16; ++q) s += hist[16 * t + q];
            unsigned suf = s;
            for (int o = 1; o < 64; o <<= 1) {
                unsigned vv = __shfl_down(suf, o);
                if (t + o < 64) suf += vv;
            }
            unsigned cum = suf - s;
            for (int q = 15; q >= 0; --q) {
                unsigned h = hist[16 * t + q];
                if ((int)cum < rem && rem <= (int)(cum + h)) {
                    sel_b = (unsigned)(16 * t + q);
                    sel_rem = rem - (int)cum;
                }
                cum += h;
            }
        }
        __syncthreads();
        unsigned prefix2 = (prefix1 << 10) | sel_b;

        // ---- level-3 (bits 5..0)
        if (t < 64) hist[t] = 0u;
        __syncthreads();
        if (!ovf) {
            int cn = candn < CCAP ? candn : CCAP;
            for (int q = t; q < cn; q += NT) {
                unsigned v = (unsigned)(cand[q] >> 32);
                if ((v >> 6) == prefix2) atomicAdd(&hist[v & 0x3Fu], 1u);
            }
        } else {
            for (int a = t; a < A_N; a += NT) {
                float s = __uint_as_float(srow[a]) / dsc[a];
                unsigned v = (s > 0.01f) ? __float_as_uint(s) : 0u;
                if (v && (v >> 6) == prefix2) atomicAdd(&hist[v & 0x3Fu], 1u);
            }
        }
        __syncthreads();
        if (t == 0) {
            int rem = sel_rem;
            unsigned cum = 0;
            for (int bq = 63; bq >= 0; --bq) {
                unsigned h = hist[bq];
                if ((int)cum < rem && rem <= (int)(cum + h)) {
                    sel_b = (unsigned)bq;
                    sel_rem = rem - (int)cum;
                    break;
                }
                cum += h;
            }
        }
        __syncthreads();
        sstar = (prefix2 << 6) | sel_b;
        teq = sel_rem;

        // ---- remaining selection: v>sstar within the selL1 bucket -> wlist;
        // ties -> eqlist. (bucket>selL1 already pushed in pass B.)
        if (!ovf) {
            int cn = candn < CCAP ? candn : CCAP;
            for (int q = t; q < cn; q += NT) {
                unsigned long long cv = cand[q];
                unsigned v = (unsigned)(cv >> 32);
                if (v > sstar) {
                    int slot = atomicAdd(&nsel, 1);
                    if (slot < 512) wlist[slot] = cv;
                } else if (v == sstar) {
                    int s2 = atomicAdd(&eqn, 1);
                    if (s2 < 64) eqlist[s2] = (int)(~(unsigned)cv);
                }
            }
        } else {
            for (int a = t; a < A_N; a += NT) {
                float s = __uint_as_float(srow[a]) / dsc[a];
                unsigned v = (s > 0.01f) ? __float_as_uint(s) : 0u;
                if (!v) continue;
                if ((v >> 16) == prefix1) {
                    if (v > sstar) {
                        int slot = atomicAdd(&nsel, 1);
                        if (slot < 512)
                            wlist[slot] = ((unsigned long long)v << 32) |
                                          (unsigned)(~(unsigned)a);
                    } else if (v == sstar) {
                        int s2 = atomicAdd(&eqn, 1);
                        if (s2 < 64) eqlist[s2] = a;
                    }
                }
            }
        }
        __syncthreads();
        if (t == 0) {
            int n = eqn < 64 ? eqn : 64;     // same 64-cap as proven kernel
            for (int i2 = 1; i2 < n; ++i2) { // sort ties by anchor asc
                int v2 = eqlist[i2], j2 = i2 - 1;
                while (j2 >= 0 && eqlist[j2] > v2) { eqlist[j2 + 1] = eqlist[j2]; --j2; }
                eqlist[j2 + 1] = v2;
            }
            int tq = teq < n ? teq : n;
            int bse = nsel;
            for (int q2 = 0; q2 < tq; ++q2) {
                int slot = bse + q2;
                if (slot < 512)
                    wlist[slot] = ((unsigned long long)sstar << 32) |
                                  (unsigned)(~(unsigned)eqlist[q2]);
            }
            nsel = bse + tq;
        }
        __syncthreads();
    }
    int ns = nsel < 512 ? nsel : 512;
    if (t >= ns) wlist[t] = 0ull;
    __syncthreads();

    // ---- bitonic sort 512 desc, register-resident; shfl_xor for j<=32,
    // LDS exchange only for j>=64. Same network => identical permutation.
    {
        unsigned long long u = wlist[t];
        for (int k = 2; k <= 512; k <<= 1) {
            bool up = ((t & k) == 0);
            for (int j = k >> 1; j >= 64; j >>= 1) {
                __syncthreads();
                wlist[t] = u;
                __syncthreads();
                unsigned long long v = wlist[t ^ j];
                bool takeMax = (((t & j) == 0) == up);
                u = takeMax ? (u > v ? u : v) : (u < v ? u : v);
            }
            for (int j = ((k >> 1) < 64 ? (k >> 1) : 32); j > 0; j >>= 1) {
                unsigned long long v = __shfl_xor(u, j);
                bool takeMax = (((t & j) == 0) == up);
                u = takeMax ? (u > v ? u : v) : (u < v ? u : v);
            }
        }
        __syncthreads();
        wlist[t] = u;
        __syncthreads();
    }

    // ---- per-class NMS on the sorted top-400: on-demand ballot masks ----
    int m = ns < TOPK ? ns : TOPK;
    float offc = (float)(cm + 1) * 301.0f;
    if (t < m) {
        unsigned aidx = ~(unsigned)(wlist[t] & 0xFFFFFFFFull);
        const float* bp = boxes + ((size_t)b * A_N + aidx) * 4;
        float4 q;
        q.x = bp[0] + offc; q.y = bp[1] + offc;   // same exprs as proven code
        q.z = bp[2] + offc; q.w = bp[3] + offc;
        nbq[t] = q;
        sar[t] = (q.z - q.x) * (q.w - q.y);       // == bar[t] bits
    }
    if (t < 8) { fsup[t] = 0ull; ksv[t] = 0ull; }
    __syncthreads();

    int nch = (m + 63) >> 6;
    for (int g = 0; g < nch; ++g) {
        // wave 0: greedy scan of chunk g; masks of kept rows built on the
        // fly via ballot (lane = column within chunk). Decisions identical
        // to the proven serial scan.
        if (t < 64) {
            int bse = 64 * g;
            int jmax = m - bse; if (jmax > 64) jmax = 64;
            bool valid = t < jmax;
            float4 cb = valid ? nbq[bse + t] : make_float4(0.f, 0.f, 0.f, 0.f);
            float car = valid ? sar[bse + t] : 0.0f;
            unsigned long long sup = fsup[g], kv = 0ull;
            unsigned long long rem =
                ((jmax == 64) ? ~0ull : ((1ull << jmax) - 1ull)) & ~sup;
            while (rem) {
                int j = __builtin_ctzll(rem);    // next non-suppressed row
                float rx1 = __shfl(cb.x, j), ry1 = __shfl(cb.y, j);
                float rx2 = __shfl(cb.z, j), ry2 = __shfl(cb.w, j);
                float ra  = __shfl(car, j);
                bool p = false;
                if (valid && t > j) {            // strictly j<col, like j>i2
                    float lx = fmaxf(rx1, cb.x), ly = fmaxf(ry1, cb.y);
                    float rx = fminf(rx2, cb.z), ry = fminf(ry2, cb.w);
                    float ww = fmaxf(rx - lx, 0.0f), hh = fmaxf(ry - ly, 0.0f);
                    float inter = ww * hh;
                    float U = ra + car - inter + 1e-9f;   // row area first
                    p = ((double)inter > IOU_M * (double)U);
                }
                unsigned long long wj = __ballot(p);
                kv |= 1ull << j;
                sup |= wj;
                rem &= ~(sup | (1ull << j));
            }
            if (t == 0) { ksv[g] = kv; total_s += __popcll(kv); }
        }
        __syncthreads();
        if (total_s >= MAXDET) break;        // uniform; rows past the 200th
                                             // kept are never emitted anyway
        if (g + 1 < nch) {
            // waves 1..: future-word suppression = OR over kept rows of
            // chunk g (broadcast LDS reads; lane = column of word h).
            int w = t >> 6, l = t & 63;
            int h = g + 1 + w;
            if (h < nch) {
                unsigned long long kv = ksv[g];
                int jmax2 = m - 64 * h; if (jmax2 > 64) jmax2 = 64;
                bool v2 = l < jmax2;
                float4 cbl = v2 ? nbq[64 * h + l] : make_float4(0.f, 0.f, 0.f, 0.f);
                float cal = v2 ? sar[64 * h + l] : 0.0f;
                bool acc = false;
                unsigned long long rr = kv;
                while (rr) {
                    int r = __builtin_ctzll(rr); rr &= rr - 1;
                    float4 rq = nbq[64 * g + r];     // wave-uniform broadcast
                    float rar = sar[64 * g + r];
                    if (v2 && !acc) {
                        float lx = fmaxf(rq.x, cbl.x), ly = fmaxf(rq.y, cbl.y);
                        float rx = fminf(rq.z, cbl.z), ry = fminf(rq.w, cbl.w);
                        float ww = fmaxf(rx - lx, 0.0f), hh = fmaxf(ry - ly, 0.0f);
                        float inter = ww * hh;
                        float U = rar + cal - inter + 1e-9f;
                        acc = ((double)inter > IOU_M * (double)U);
                    }
                }
                unsigned long long wd = __ballot(acc);
                if (l == 0) fsup[h] |= wd;
            }
        }
        __syncthreads();
    }

    // rank-parallel emission (kept order == row order == serial order)
    if (t < 64) {
        int l = t, basek = 0;
        for (int g = 0; g < nch; ++g) {
            unsigned long long kv = ksv[g];
            int row = 64 * g + l;
            if ((kv >> l) & 1ull) {
                int rank = basek + __popcll(kv & ((1ull << l) - 1ull));
                if (rank < MAXDET) {
                    unsigned long long wv = wlist[row];
                    unsigned sbts = (unsigned)(wv >> 32);
                    unsigned aa2  = ~(unsigned)wv;        // anchor, <16384
                    int flat = cm * TOPK + row;
                    unsigned long long key =
                        ((unsigned long long)sbts << 31) |
                        ((unsigned long long)(131071 - flat) << 14) |
                        (unsigned long long)aa2;
                    kkey[(size_t)bc * MAXDET + rank] = key;
                }
            }
            basek += __popcll(kv);
        }
        if (l == 0) kcnt[bc] = total_s < MAXDET ? total_s : MAXDET;
    }
}

// ---------------------------------------------------------------- FALLBACK top-400 + NMS
// Verbatim proven kernel (used only if the workspace can't hold scT).
__global__ __launch_bounds__(NT) void k_topknms(const void* __restrict__ logits,
                                                const int* __restrict__ flag,
                                                const float* __restrict__ amax,
                                                const float* __restrict__ denom,
                                                const float* __restrict__ boxes,
                                                unsigned long long* __restrict__ kkey,
                                                int* __restrict__ kcnt) {
    __shared__ union {
        unsigned sbits[A_N];
        unsigned long long msk[TOPK * 7];
    } su;
    __shared__ unsigned long long wlist[512];
    __shared__ float bx1[TOPK], by1[TOPK], bx2[TOPK], by2[TOPK], bar[TOPK];
    __shared__ int wred[NT / 64];
    __shared__ unsigned bcast_p;
    __shared__ int bcast_rem;
    __shared__ int eqlist[64];
    __shared__ int eqn;
    __shared__ int bcast_athr;
    __shared__ int nsel;

    int bc = blockIdx.x;
    int b  = bc / CM1;
    int cm = bc % CM1;
    int bf = flag[0];
    int t  = threadIdx.x;

    for (int a = t; a < A_N; a += NT) {
        size_t base = (size_t)b * A_N + a;
        float e  = np_expf(ldin(logits, base * C_N + (cm + 1), bf) - amax[base]);
        float sc = e / denom[base];
        su.sbits[a] = (sc > 0.01f) ? __float_as_uint(sc) : 0u;
    }
    if (t == 0) { eqn = 0; nsel = 0; }
    __syncthreads();

    {
        int c0 = 0;
        for (int a = t; a < A_N; a += NT) c0 += (su.sbits[a] != 0u);
        for (int o = 32; o; o >>= 1) c0 += __shfl_down(c0, o);
        if ((t & 63) == 0) wred[t >> 6] = c0;
        __syncthreads();
        if (t == 0) {
            int tot = 0;
            for (int wv = 0; wv < NT / 64; ++wv) tot += wred[wv];
            bcast_rem = tot;
        }
        __syncthreads();
    }
    int nreal = bcast_rem;
    __syncthreads();

    unsigned sstar = 0u;
    int teq = 0;
    if (nreal >= TOPK) {
        unsigned p = 0x3C000000u;
        int rem = TOPK;
        for (int bit = 25; bit >= 0; --bit) {
            unsigned q = p | (1u << bit);
            int cnt = 0;
            for (int a = t; a < A_N; a += NT) cnt += ((su.sbits[a] >> bit) == (q >> bit));
            for (int o = 32; o; o >>= 1) cnt += __shfl_down(cnt, o);
            if ((t & 63) == 0) wred[t >> 6] = cnt;
            __syncthreads();
            if (t == 0) {
                int tot = 0;
                for (int wv = 0; wv < NT / 64; ++wv) tot += wred[wv];
                if (tot >= rem) { bcast_p = q; bcast_rem = rem; }
                else            { bcast_p = p; bcast_rem = rem - tot; }
            }
            __syncthreads();
            p = bcast_p; rem = bcast_rem;
            __syncthreads();
        }
        sstar = p;
        teq = rem;
        for (int a = t; a < A_N; a += NT) {
            if (su.sbits[a] == sstar) {
                int slot = atomicAdd(&eqn, 1);
                if (slot < 64) eqlist[slot] = a;
            }
        }
        __syncthreads();
        if (t == 0) {
            int n = eqn < 64 ? eqn : 64;
            for (int i = 1; i < n; ++i) {
                int v = eqlist[i], j = i - 1;
                while (j >= 0 && eqlist[j] > v) { eqlist[j + 1] = eqlist[j]; --j; }
                eqlist[j + 1] = v;
            }
            int tq = teq < n ? teq : n;
            bcast_athr = (tq > 0) ? eqlist[tq - 1] : -1;
        }
        __syncthreads();
    }
    int athr = (nreal >= TOPK) ? bcast_athr : -1;
    __syncthreads();

    for (int a = t; a < A_N; a += NT) {
        unsigned v = su.sbits[a];
        bool sel;
        if (nreal >= TOPK)
            sel = (v > sstar) || (v == sstar && a <= athr);
        else
            sel = (v != 0u);
        if (sel) {
            int slot = atomicAdd(&nsel, 1);
            if (slot < 512)
                wlist[slot] = ((unsigned long long)v << 32) | (unsigned)(~(unsigned)a);
        }
    }
    __syncthreads();
    int ns = nsel < 512 ? nsel : 512;
    if (t < 512 && t >= ns) wlist[t] = 0ull;
    __syncthreads();

    for (int k = 2; k <= 512; k <<= 1) {
        for (int j = k >> 1; j > 0; j >>= 1) {
            int ixj = t ^ j;
            if (ixj > t) {
                unsigned long long u = wlist[t], v = wlist[ixj];
                bool desc = ((t & k) == 0);
                if (desc ? (u < v) : (u > v)) { wlist[t] = v; wlist[ixj] = u; }
            }
            __syncthreads();
        }
    }

    int m = ns < TOPK ? ns : TOPK;
    float offc = (float)(cm + 1) * 301.0f;
    if (t < m) {
        unsigned aidx = ~(unsigned)(wlist[t] & 0xFFFFFFFFull);
        const float* bp = boxes + ((size_t)b * A_N + aidx) * 4;
        float x1 = bp[0] + offc, y1 = bp[1] + offc;
        float x2 = bp[2] + offc, y2 = bp[3] + offc;
        bx1[t] = x1; by1[t] = y1; bx2[t] = x2; by2[t] = y2;
        bar[t] = (x2 - x1) * (y2 - y1);
    }
    __syncthreads();

    if (t < m) {
        unsigned long long w[7] = {0, 0, 0, 0, 0, 0, 0};
        float x1 = bx1[t], y1 = by1[t], x2 = bx2[t], y2 = by2[t], a1 = bar[t];
        for (int j = t + 1; j < m; ++j) {
            float lx = fmaxf(x1, bx1[j]), ly = fmaxf(y1, by1[j]);
            float rx = fminf(x2, bx2[j]), ry = fminf(y2, by2[j]);
            float ww = fmaxf(rx - lx, 0.0f), hh = fmaxf(ry - ly, 0.0f);
            float inter = ww * hh;
            float iou = inter / (a1 + bar[j] - inter + 1e-9f);
            if (iou > 0.45f) w[j >> 6] |= 1ull << (j & 63);
        }
        for (int k2 = 0; k2 < 7; ++k2) su.msk[t * 7 + k2] = w[k2];
    }
    __syncthreads();

    if (t == 0) {
        unsigned long long sup[7] = {0, 0, 0, 0, 0, 0, 0};
        int cnt = 0;
        for (int i = 0; i < m; ++i) {
            if (!((sup[i >> 6] >> (i & 63)) & 1ull)) {
                unsigned long long wv = wlist[i];
                unsigned sb2 = (unsigned)(wv >> 32);
                unsigned a  = ~(unsigned)wv;
                int flat = cm * TOPK + i;
                unsigned long long key =
                    ((unsigned long long)sb2 << 31) |
                    ((unsigned long long)(131071 - flat) << 14) |
                    (unsigned long long)a;
                kkey[(size_t)bc * MAXDET + cnt] = key;
                cnt++;
                if (cnt == MAXDET) break;
                const unsigned long long* r = &su.msk[i * 7];
                for (int k2 = 0; k2 < 7; ++k2) sup[k2] |= r[k2];
            }
        }
        kcnt[bc] = cnt;
    }
}

// ---------------------------------------------------------------- parallel per-image top-200
// Keys are globally unique and each class list is sorted desc, so the merged
// output == the top-200 keys of the union in descending order. Radix select
// of the 200th largest, gather, bitonic sort 256 desc, emit. Bit-identical.
__global__ __launch_bounds__(256) void k_merge(const unsigned long long* __restrict__ kkey,
                                               const int* __restrict__ kcnt,
                                               const float* __restrict__ boxes,
                                               float* __restrict__ out) {
    __shared__ unsigned hist[1024];
    __shared__ unsigned long long wl[256];
    __shared__ int kc[CM1];
    __shared__ int tot_s;
    __shared__ unsigned selb_s;
    __shared__ int selrem_s;
    __shared__ int gcnt;

    int b = blockIdx.x;
    int t = threadIdx.x;
    const unsigned long long* keys = kkey + (size_t)b * (CM1 * MAXDET);
    const float* bx = boxes + (size_t)b * A_N * 4;
    float* ob = out + (size_t)b * MAXDET * 4;
    float* os = out + (size_t)B_N * MAXDET * 4 + (size_t)b * MAXDET;
    float* ol = out + (size_t)B_N * MAXDET * 5 + (size_t)b * MAXDET;

    if (t < CM1) kc[t] = kcnt[b * CM1 + t];
    if (t == 0) { tot_s = 0; gcnt = 0; }
    __syncthreads();

    {
        int c0 = 0;
        for (int idx = t; idx < CM1 * MAXDET; idx += 256) {
            int c = idx / MAXDET;
            if (idx - c * MAXDET < kc[c]) c0++;
        }
        for (int o = 32; o; o >>= 1) c0 += __shfl_down(c0, o);
        if ((t & 63) == 0) atomicAdd(&tot_s, c0);
    }
    __syncthreads();
    int total = tot_s;

    unsigned long long T = 0ull;
    if (total > MAXDET) {
        unsigned long long prefix = 0ull;
        if (t == 0) selrem_s = MAXDET;
        __syncthreads();
        const int sh[7] = {52, 42, 32, 22, 12, 2, 0};
        const int wd[7] = {10, 10, 10, 10, 10, 10, 2};
        for (int l = 0; l < 7; ++l) {
            int shift = sh[l], width = wd[l];
            int nb = 1 << width;
            for (int q = t; q < nb; q += 256) hist[q] = 0u;
            __syncthreads();
            for (int idx = t; idx < CM1 * MAXDET; idx += 256) {
                int c = idx / MAXDET;
                if (idx - c * MAXDET < kc[c]) {
                    unsigned long long key = keys[idx];
                    if ((key >> (shift + width)) == prefix)
                        atomicAdd(&hist[(unsigned)(key >> shift) & (unsigned)(nb - 1)], 1u);
                }
            }
            __syncthreads();
            if (nb >= 64) {
                if (t < 64) {
                    int rem = selrem_s;
                    int per = nb / 64;
                    unsigned s = 0;
                    for (int q = 0; q < per; ++q) s += hist[per * t + q];
                    unsigned suf = s;
                    for (int o = 1; o < 64; o <<= 1) {
                        unsigned vv = __shfl_down(suf, o);
                        if (t + o < 64) suf += vv;
                    }
                    unsigned cum = suf - s;
                    for (int q = per - 1; q >= 0; --q) {
                        unsigned h = hist[per * t + q];
                        if ((int)cum < rem && rem <= (int)(cum + h)) {
                            selb_s = (unsigned)(per * t + q);
                            selrem_s = rem - (int)cum;
                        }
                        cum += h;
                    }
                }
            } else if (t == 0) {
                int rem = selrem_s;
                unsigned cum = 0;
                for (int bq = nb - 1; bq >= 0; --bq) {
                    unsigned h = hist[bq];
                    if ((int)cum < rem && rem <= (int)(cum + h)) {
                        selb_s = (unsigned)bq;
                        selrem_s = rem - (int)cum;
                        break;
                    }
                    cum += h;
                }
            }
            __syncthreads();
            prefix = (prefix << width) | (unsigned long long)selb_s;
            __syncthreads();
        }
        T = prefix;
    }

    wl[t] = 0ull;
    __syncthreads();
    for (int idx = t; idx < CM1 * MAXDET; idx += 256) {
        int c = idx / MAXDET;
        if (idx - c * MAXDET < kc[c]) {
            unsigned long long key = keys[idx];
            if (key >= T) {
                int s = atomicAdd(&gcnt, 1);
                if (s < 256) wl[s] = key;
            }
        }
    }
    __syncthreads();

    for (int k = 2; k <= 256; k <<= 1) {
        for (int j = k >> 1; j > 0; j >>= 1) {
            int ixj = t ^ j;
            if (ixj > t) {
                unsigned long long u = wl[t], v = wl[ixj];
                bool desc = ((t & k) == 0);
                if (desc ? (u < v) : (u > v)) { wl[t] = v; wl[ixj] = u; }
            }
            __syncthreads();
        }
    }

    if (t < MAXDET) {
        unsigned long long key = wl[t];
        if (key == 0ull) {
            ob[t * 4 + 0] = 0.0f; ob[t * 4 + 1] = 0.0f;
            ob[t * 4 + 2] = 0.0f; ob[t * 4 + 3] = 0.0f;
            os[t] = 0.0f; ol[t] = 0.0f;
        } else {
            int a = (int)(key & 0x3FFFull);
            int flat = 131071 - (int)((key >> 14) & 0x1FFFFull);
            int cmv = flat / TOPK;
            const float* bp = bx + (size_t)a * 4;
            ob[t * 4 + 0] = bp[0]; ob[t * 4 + 1] = bp[1];
            ob[t * 4 + 2] = bp[2]; ob[t * 4 + 3] = bp[3];
            os[t] = __uint_as_float((unsigned)(key >> 31));
            ol[t] = (float)(cmv + 1);
        }
    }
}

// ---------------------------------------------------------------- host launcher
extern "C" void kernel_launch(void* const* d_in, const int* in_sizes, int n_in,
                              void* d_out, int out_size, void* d_ws, size_t ws_size,
                              hipStream_t stream) {
    const void* logits  = d_in[0];   // [32, 8732, 91] f32
    const void* rel     = d_in[1];   // [32, 8732, 4]
    const void* anchors = d_in[2];   // [8732, 4]
    float* out = (float*)d_out;      // boxes|scores|labels flat, f32

    char* ws = (char*)d_ws;
    size_t off = 0;
    auto alloc = [&](size_t bytes) -> void* {
        void* p = ws + off;
        off = (off + bytes + 255) & ~(size_t)255;
        return p;
    };
    float* boxes  = (float*)alloc((size_t)B_N * A_N * 4 * sizeof(float));
    float* amax   = (float*)alloc((size_t)B_N * A_N * sizeof(float));
    float* denom  = (float*)alloc((size_t)B_N * A_N * sizeof(float));
    int*   flag   = (int*)alloc(256);
    unsigned long long* kkey = (unsigned long long*)alloc((size_t)B_N * CM1 * MAXDET * sizeof(unsigned long long));
    int* kcnt     = (int*)alloc((size_t)B_N * CM1 * sizeof(int));

    // transposed raw-exp buffer: [B][90][A] u32 — ~96 MiB. Only used if the
    // workspace can hold it; else fall back to the proven path. (Read-only
    // in the consumer now — no in-place clobber.)
    size_t scT_bytes = (size_t)B_N * CM1 * A_N * sizeof(unsigned);
    unsigned* scT = nullptr;
    if (off + scT_bytes <= ws_size) scT = (unsigned*)alloc(scT_bytes);

    int gridBA = (B_N * A_N + 255) / 256;

    k_sniff<<<1, 256, 0, stream>>>((const unsigned*)logits, flag);
    k_stats<<<gridBA, 256, 0, stream>>>(logits, rel, anchors, flag, amax, denom, boxes, scT);
    if (scT)
        k_topknms_pre<<<B_N * CM1, NT, 0, stream>>>(scT, denom, boxes, kkey, kcnt);
    else
        k_topknms<<<B_N * CM1, NT, 0, stream>>>(logits, flag, amax, denom, boxes, kkey, kcnt);
    k_merge<<<B_N, 256, 0, stream>>>(kkey, kcnt, boxes, out);
}